// Round 3
// baseline (2463.228 us; speedup 1.0000x reference)
//
#include <hip/hip_runtime.h>
#include <math.h>

#define N_NODES 50000
#define N_EDGES 500000
#define N_GRAPHS 2048
#define HID 128
#define EDIM 12
#define NLAYERS 8
#define EPS_BN 1e-5f

// ---------------- CSR build ----------------
__global__ void zero_kernel(int* deg, int* cursor, float* stats) {
  int i = blockIdx.x * 256 + threadIdx.x;
  if (i < N_NODES) { deg[i] = 0; cursor[i] = 0; }
  if (i < NLAYERS * 256) stats[i] = 0.f;
}

__global__ void count_kernel(const int* __restrict__ dst, int* __restrict__ deg) {
  int e = blockIdx.x * 256 + threadIdx.x;
  if (e < N_EDGES) atomicAdd(&deg[dst[e]], 1);
}

__global__ void scan1_kernel(int* __restrict__ off, int* __restrict__ bsum) {
  __shared__ int s[256];
  int t = threadIdx.x; int n = blockIdx.x * 256 + t;
  int x = (n < N_NODES) ? off[n] : 0;
  s[t] = x; __syncthreads();
  for (int o = 1; o < 256; o <<= 1) {
    int v = (t >= o) ? s[t - o] : 0;
    __syncthreads(); s[t] += v; __syncthreads();
  }
  if (n < N_NODES) off[n] = s[t] - x;   // block-local exclusive
  if (t == 255) bsum[blockIdx.x] = s[255];
}

__global__ void scan2_kernel(int* __restrict__ bsum, int nb) {
  __shared__ int s[256];
  int t = threadIdx.x;
  int x = (t < nb) ? bsum[t] : 0;
  s[t] = x; __syncthreads();
  for (int o = 1; o < 256; o <<= 1) {
    int v = (t >= o) ? s[t - o] : 0;
    __syncthreads(); s[t] += v; __syncthreads();
  }
  if (t < nb) bsum[t] = s[t] - x;       // exclusive
}

__global__ void scan3_kernel(int* __restrict__ off, const int* __restrict__ bsum) {
  int t = threadIdx.x; int n = blockIdx.x * 256 + t;
  if (n < N_NODES) off[n] += bsum[blockIdx.x];
  if (n == 0 && blockIdx.x == 0) off[N_NODES] = N_EDGES;
}

__global__ void scatter_kernel(const int* __restrict__ src, const int* __restrict__ dst,
                               const int* __restrict__ off, int* __restrict__ cursor,
                               int2* __restrict__ elist2) {
  int e = blockIdx.x * 256 + threadIdx.x;
  if (e < N_EDGES) {
    int d = dst[e];
    int p = atomicAdd(&cursor[d], 1);
    elist2[off[d] + p] = make_int2(src[e], e);
  }
}

// ---------------- input projection ----------------
__global__ void inproj_kernel(const float* __restrict__ x, const float* __restrict__ Win,
                              const float* __restrict__ b_in, float* __restrict__ h) {
  __shared__ float xs[44];
  int t = threadIdx.x;
  int n0 = blockIdx.x * 2;
  if (t < 44) {
    int n = n0 + t / 22;
    xs[t] = (n < N_NODES) ? x[n0 * 22 + t] : 0.f;
  }
  __syncthreads();
  int c = t & 127, half = t >> 7;
  int n = n0 + half;
  if (n < N_NODES) {
    float acc = b_in[c];
#pragma unroll
    for (int k = 0; k < 22; k++) acc = fmaf(xs[half * 22 + k], Win[k * HID + c], acc);
    h[n * HID + c] = fmaxf(acc, 0.f);
  }
}

// ---------------- fused dual f32 GEMM: C1 = A@W1 (+b1), C2 = A@W2 (+b2) ----------------
template <int CO, bool BIAS>
__global__ __launch_bounds__(256) void gemm2_kernel(
    const float* __restrict__ A,
    const float* __restrict__ W1, const float* __restrict__ b1, float* __restrict__ C1,
    const float* __restrict__ W2, const float* __restrict__ b2, float* __restrict__ C2,
    int nrows) {
  __shared__ float As[32 * 128];
  constexpr int CW = CO / 32;
  int t = threadIdx.x;
  int brow = blockIdx.x * 32;
#pragma unroll
  for (int i = 0; i < 4; i++) {
    int f = t + i * 256;
    int r = f >> 5, cf = (f & 31) << 2;
    int g = brow + r;
    float4 v = (g < nrows) ? *(const float4*)&A[(size_t)g * 128 + cf] : make_float4(0.f, 0.f, 0.f, 0.f);
    *(float4*)&As[r * 128 + cf] = v;
  }
  __syncthreads();
  int cgrp = t & 31, rgrp = t >> 5;
  int c0 = cgrp * CW, r0 = rgrp * 4;
  float acc1[4][CW], acc2[4][CW];
#pragma unroll
  for (int r = 0; r < 4; r++)
#pragma unroll
    for (int c = 0; c < CW; c++) { acc1[r][c] = 0.f; acc2[r][c] = 0.f; }

  for (int k = 0; k < 128; k += 4) {
    float a[4][4];
#pragma unroll
    for (int r = 0; r < 4; r++) {
      float4 av = *(const float4*)&As[(r0 + r) * 128 + k];
      a[r][0] = av.x; a[r][1] = av.y; a[r][2] = av.z; a[r][3] = av.w;
    }
#pragma unroll
    for (int kk = 0; kk < 4; kk++) {
      float w1[CW], w2[CW];
      if constexpr (CW == 4) {
        float4 wv = *(const float4*)&W1[(k + kk) * CO + c0];
        w1[0] = wv.x; w1[1] = wv.y; w1[2] = wv.z; w1[3] = wv.w;
        float4 wu = *(const float4*)&W2[(k + kk) * CO + c0];
        w2[0] = wu.x; w2[1] = wu.y; w2[2] = wu.z; w2[3] = wu.w;
      } else {
        float2 wv = *(const float2*)&W1[(k + kk) * CO + c0];
        w1[0] = wv.x; w1[1] = wv.y;
        float2 wu = *(const float2*)&W2[(k + kk) * CO + c0];
        w2[0] = wu.x; w2[1] = wu.y;
      }
#pragma unroll
      for (int r = 0; r < 4; r++)
#pragma unroll
        for (int c = 0; c < CW; c++) {
          acc1[r][c] = fmaf(a[r][kk], w1[c], acc1[r][c]);
          acc2[r][c] = fmaf(a[r][kk], w2[c], acc2[r][c]);
        }
    }
  }
  float bb1[CW], bb2[CW];
#pragma unroll
  for (int c = 0; c < CW; c++) {
    bb1[c] = BIAS ? b1[c0 + c] : 0.f;
    bb2[c] = BIAS ? b2[c0 + c] : 0.f;
  }
#pragma unroll
  for (int r = 0; r < 4; r++) {
    int g = brow + r0 + r;
    if (g < nrows) {
      float o1[CW], o2[CW];
#pragma unroll
      for (int c = 0; c < CW; c++) { o1[c] = acc1[r][c] + bb1[c]; o2[c] = acc2[r][c] + bb2[c]; }
      if constexpr (CW == 4) {
        *(float4*)&C1[(size_t)g * CO + c0] = *(float4*)&o1[0];
        *(float4*)&C2[(size_t)g * CO + c0] = *(float4*)&o2[0];
      } else {
        *(float2*)&C1[(size_t)g * CO + c0] = *(float2*)&o1[0];
        *(float2*)&C2[(size_t)g * CO + c0] = *(float2*)&o2[0];
      }
    }
  }
}

// ---------------- GATv2 aggregation: 2 nodes per wave, interleaved chains ----------------
// Fuses BN partial-stat accumulation (sum, sumsq per channel) into the epilogue.
__global__ __launch_bounds__(256, 4) void gat_kernel(
    const float* __restrict__ xl, const float* __restrict__ xr,
    const float* __restrict__ edge_attr,
    const int2* __restrict__ elist2, const int* __restrict__ off,
    const float* __restrict__ Wel, const float* __restrict__ attl,
    const float* __restrict__ bol, float* __restrict__ out,
    float* __restrict__ stats) {
  __shared__ float lsum[4 * 128];
  __shared__ float lqsum[4 * 128];
  int lane = threadIdx.x & 63;
  int wid = threadIdx.x >> 6;
  int nodeA = blockIdx.x * 8 + wid * 2;
  int nodeB = nodeA + 1;
  int c0 = lane * 2;  // channels c0, c0+1 (same head = c0/32)
  bool vA = nodeA < N_NODES, vB = nodeB < N_NODES;

  float2 wk[12];
#pragma unroll
  for (int k = 0; k < 12; k++) wk[k] = *(const float2*)&Wel[k * HID + c0];
  float2 at = *(const float2*)&attl[c0];
  float2 xrA = vA ? *(const float2*)&xr[(size_t)nodeA * HID + c0] : make_float2(0.f, 0.f);
  float2 xrB = vB ? *(const float2*)&xr[(size_t)nodeB * HID + c0] : make_float2(0.f, 0.f);
  int isA = vA ? off[nodeA] : 0, ieA = vA ? off[nodeA + 1] : 0;
  int isB = vB ? off[nodeB] : 0, ieB = vB ? off[nodeB + 1] : 0;
  int degA = ieA - isA, degB = ieB - isB;
  int imax = max(degA, degB);

  float mA = -INFINITY, dA = 0.f, a0A = 0.f, a1A = 0.f;
  float mB = -INFINITY, dB = 0.f, a0B = 0.f, a1B = 0.f;

  int2 seA = elist2[(degA > 0) ? isA : 0];
  int2 seB = elist2[(degB > 0) ? isB : 0];

  for (int i = 0; i < imax; i++) {
    bool okA = i < degA, okB = i < degB;
    // prefetch next edge indices (one iteration ahead)
    int2 seAn = elist2[(i + 1 < degA) ? (isA + i + 1) : 0];
    int2 seBn = elist2[(i + 1 < degB) ? (isB + i + 1) : 0];
    // issue all data loads for both nodes before any compute
    const float* eapA = &edge_attr[(size_t)seA.y * EDIM];
    const float* eapB = &edge_attr[(size_t)seB.y * EDIM];
    float4 eA0 = *(const float4*)eapA;
    float4 eA1 = *(const float4*)(eapA + 4);
    float4 eA2 = *(const float4*)(eapA + 8);
    float4 eB0 = *(const float4*)eapB;
    float4 eB1 = *(const float4*)(eapB + 4);
    float4 eB2 = *(const float4*)(eapB + 8);
    float2 xlA = *(const float2*)&xl[(size_t)seA.x * HID + c0];
    float2 xlB = *(const float2*)&xl[(size_t)seB.x * HID + c0];

    float eavA[12] = {eA0.x, eA0.y, eA0.z, eA0.w, eA1.x, eA1.y, eA1.z, eA1.w,
                      eA2.x, eA2.y, eA2.z, eA2.w};
    float eavB[12] = {eB0.x, eB0.y, eB0.z, eB0.w, eB1.x, eB1.y, eB1.z, eB1.w,
                      eB2.x, eB2.y, eB2.z, eB2.w};
    float epA0 = 0.f, epA1 = 0.f, epB0 = 0.f, epB1 = 0.f;
#pragma unroll
    for (int k = 0; k < 12; k++) {
      epA0 = fmaf(eavA[k], wk[k].x, epA0);
      epA1 = fmaf(eavA[k], wk[k].y, epA1);
      epB0 = fmaf(eavB[k], wk[k].x, epB0);
      epB1 = fmaf(eavB[k], wk[k].y, epB1);
    }
    float sA0 = xlA.x + xrA.x + epA0; sA0 = (sA0 > 0.f) ? sA0 : 0.2f * sA0;
    float sA1 = xlA.y + xrA.y + epA1; sA1 = (sA1 > 0.f) ? sA1 : 0.2f * sA1;
    float sB0 = xlB.x + xrB.x + epB0; sB0 = (sB0 > 0.f) ? sB0 : 0.2f * sB0;
    float sB1 = xlB.y + xrB.y + epB1; sB1 = (sB1 > 0.f) ? sB1 : 0.2f * sB1;
    float vvA = fmaf(sA0, at.x, sA1 * at.y);
    float vvB = fmaf(sB0, at.x, sB1 * at.y);
    // reduce across the 16 lanes of each head; two independent chains interleave
#pragma unroll
    for (int o = 1; o <= 8; o <<= 1) {
      vvA += __shfl_xor(vvA, o);
      vvB += __shfl_xor(vvB, o);
    }
    vvA = okA ? vvA : -INFINITY;
    vvB = okB ? vvB : -INFINITY;
    // online softmax A
    float mnA = fmaxf(mA, vvA);
    float scA = (mA == -INFINITY) ? 0.f : __expf(mA - mnA);
    float pA = okA ? __expf(vvA - mnA) : 0.f;
    dA = fmaf(dA, scA, pA);
    a0A = fmaf(a0A, scA, pA * xlA.x);
    a1A = fmaf(a1A, scA, pA * xlA.y);
    mA = mnA;
    // online softmax B
    float mnB = fmaxf(mB, vvB);
    float scB = (mB == -INFINITY) ? 0.f : __expf(mB - mnB);
    float pB = okB ? __expf(vvB - mnB) : 0.f;
    dB = fmaf(dB, scB, pB);
    a0B = fmaf(a0B, scB, pB * xlB.x);
    a1B = fmaf(a1B, scB, pB * xlB.y);
    mB = mnB;

    seA = seAn; seB = seBn;
  }

  float invA = 1.f / (dA + 1e-16f);
  float invB = 1.f / (dB + 1e-16f);
  float2 bo2 = *(const float2*)&bol[c0];
  float2 oA, oB;
  oA.x = fmaf(a0A, invA, bo2.x); oA.y = fmaf(a1A, invA, bo2.y);
  oB.x = fmaf(a0B, invB, bo2.x); oB.y = fmaf(a1B, invB, bo2.y);
  if (vA) *(float2*)&out[(size_t)nodeA * HID + c0] = oA;
  if (vB) *(float2*)&out[(size_t)nodeB * HID + c0] = oB;

  // block-level BN partial stats
  float s0 = (vA ? oA.x : 0.f) + (vB ? oB.x : 0.f);
  float s1 = (vA ? oA.y : 0.f) + (vB ? oB.y : 0.f);
  float q0 = (vA ? oA.x * oA.x : 0.f) + (vB ? oB.x * oB.x : 0.f);
  float q1 = (vA ? oA.y * oA.y : 0.f) + (vB ? oB.y * oB.y : 0.f);
  *(float2*)&lsum[wid * 128 + c0] = make_float2(s0, s1);
  *(float2*)&lqsum[wid * 128 + c0] = make_float2(q0, q1);
  __syncthreads();
  int t = threadIdx.x;
  if (t < 128) {
    float s = lsum[t] + lsum[128 + t] + lsum[256 + t] + lsum[384 + t];
    atomicAdd(&stats[t], s);
  } else {
    int c = t - 128;
    float q = lqsum[c] + lqsum[128 + c] + lqsum[256 + c] + lqsum[384 + c];
    atomicAdd(&stats[128 + c], q);
  }
}

// ---------------- BatchNorm apply (+residual+relu) ----------------
__global__ void bnapply_kernel(const float* __restrict__ t, const float* __restrict__ res,
                               const float* __restrict__ sums, const float* __restrict__ gamma,
                               const float* __restrict__ beta, float* __restrict__ hout) {
  int i4 = blockIdx.x * 256 + threadIdx.x;
  if (i4 >= N_NODES * 32) return;
  int c0 = (i4 & 31) << 2;
  const float invN = 1.f / (float)N_NODES;
  float4 tv = *(const float4*)&t[(size_t)i4 * 4];
  float4 sm = *(const float4*)&sums[c0];
  float4 sq = *(const float4*)&sums[128 + c0];
  float4 gm = *(const float4*)&gamma[c0];
  float4 bt = *(const float4*)&beta[c0];
  float4 rv = make_float4(0.f, 0.f, 0.f, 0.f);
  if (res) rv = *(const float4*)&res[(size_t)i4 * 4];
  float4 o;
#define BN1(comp)                                                   \
  {                                                                 \
    float mu = sm.comp * invN;                                      \
    float var = sq.comp * invN - mu * mu;                           \
    float rs = rsqrtf(var + EPS_BN);                                \
    float v = (tv.comp - mu) * rs * gm.comp + bt.comp + rv.comp;    \
    o.comp = fmaxf(v, 0.f);                                         \
  }
  BN1(x) BN1(y) BN1(z) BN1(w)
#undef BN1
  *(float4*)&hout[(size_t)i4 * 4] = o;
}

// ---------------- policy head (one edge per 16 lanes) ----------------
__global__ __launch_bounds__(256) void policy_kernel(
    const float* __restrict__ Ps, const float* __restrict__ Pd,
    const int* __restrict__ src, const int* __restrict__ dst,
    const float* __restrict__ edge_attr, const float* __restrict__ Wp1e,
    const float* __restrict__ bp1, const float* __restrict__ Wp2,
    const float* __restrict__ bp2, float* __restrict__ outp) {
  int lane = threadIdx.x & 63;
  int j = lane & 15;  // lane within 16-lane group; channels 4j..4j+3
  int e = (blockIdx.x * 256 + threadIdx.x) >> 4;
  if (e >= N_EDGES) return;
  float4 we[12];
#pragma unroll
  for (int k = 0; k < 12; k++) we[k] = *(const float4*)&Wp1e[k * 64 + j * 4];
  float4 b4 = *(const float4*)&bp1[j * 4];
  float4 w2 = *(const float4*)&Wp2[j * 4];
  float bp2c = bp2[0];
  int s = src[e], d = dst[e];
  const float* eap = &edge_attr[(size_t)e * EDIM];
  float4 e0 = *(const float4*)eap;
  float4 e1 = *(const float4*)(eap + 4);
  float4 e2 = *(const float4*)(eap + 8);
  float4 ps = *(const float4*)&Ps[(size_t)s * 64 + j * 4];
  float4 pd = *(const float4*)&Pd[(size_t)d * 64 + j * 4];
  float eav[12] = {e0.x, e0.y, e0.z, e0.w, e1.x, e1.y, e1.z, e1.w, e2.x, e2.y, e2.z, e2.w};
  float hx = ps.x + pd.x + b4.x;
  float hy = ps.y + pd.y + b4.y;
  float hz = ps.z + pd.z + b4.z;
  float hw = ps.w + pd.w + b4.w;
#pragma unroll
  for (int k = 0; k < 12; k++) {
    hx = fmaf(eav[k], we[k].x, hx);
    hy = fmaf(eav[k], we[k].y, hy);
    hz = fmaf(eav[k], we[k].z, hz);
    hw = fmaf(eav[k], we[k].w, hw);
  }
  hx = fmaxf(hx, 0.f); hy = fmaxf(hy, 0.f); hz = fmaxf(hz, 0.f); hw = fmaxf(hw, 0.f);
  float v = fmaf(hx, w2.x, fmaf(hy, w2.y, fmaf(hz, w2.z, hw * w2.w)));
  v += __shfl_xor(v, 1);
  v += __shfl_xor(v, 2);
  v += __shfl_xor(v, 4);
  v += __shfl_xor(v, 8);
  if (j == 0) outp[e] = v + bp2c;
}

// ---------------- pooled mean + value head (one block per graph) ----------------
__device__ int lower_bound_dev(const int* a, int n, int key) {
  int lo = 0, hi = n;
  while (lo < hi) {
    int mid = (lo + hi) >> 1;
    if (a[mid] < key) lo = mid + 1; else hi = mid;
  }
  return lo;
}

__global__ void poolvalue_kernel(const float* __restrict__ h, const int* __restrict__ batch,
                                 const float* __restrict__ Wv1, const float* __restrict__ bv1,
                                 const float* __restrict__ Wv2, const float* __restrict__ bv2,
                                 float* __restrict__ outv) {
  __shared__ float pl[128];
  __shared__ float hd[64];
  __shared__ int range[2];
  int g = blockIdx.x, t = threadIdx.x;
  if (t == 0) {
    range[0] = lower_bound_dev(batch, N_NODES, g);
    range[1] = lower_bound_dev(batch, N_NODES, g + 1);
  }
  __syncthreads();
  int lo = range[0], hi = range[1];
  float s = 0.f;
  for (int n = lo; n < hi; n++) s += h[(size_t)n * HID + t];
  float cnt = (float)(hi - lo);
  pl[t] = s / fmaxf(cnt, 1.f);
  __syncthreads();
  if (t < 64) {
    float a = bv1[t];
    for (int c = 0; c < 128; c++) a = fmaf(pl[c], Wv1[c * 64 + t], a);
    hd[t] = fmaxf(a, 0.f);
  }
  __syncthreads();
  if (t < 3) {
    float a = bv2[t];
    for (int j = 0; j < 64; j++) a = fmaf(hd[j], Wv2[j * 3 + t], a);
    outv[g * 3 + t] = a;
  }
}

// ---------------- host ----------------
extern "C" void kernel_launch(void* const* d_in, const int* in_sizes, int n_in,
                              void* d_out, int out_size, void* d_ws, size_t ws_size,
                              hipStream_t stream) {
  (void)in_sizes; (void)n_in; (void)out_size; (void)ws_size;
  const float* x    = (const float*)d_in[0];
  const int*   src  = (const int*)d_in[1];
  const int*   dst  = (const int*)d_in[2];
  const int*   batch= (const int*)d_in[3];
  const float* ea   = (const float*)d_in[4];
  const float* Win  = (const float*)d_in[5];
  const float* b_in = (const float*)d_in[6];
  const float* Wl   = (const float*)d_in[7];
  const float* bl   = (const float*)d_in[8];
  const float* Wr   = (const float*)d_in[9];
  const float* br   = (const float*)d_in[10];
  const float* We   = (const float*)d_in[11];
  const float* att  = (const float*)d_in[12];
  const float* bo   = (const float*)d_in[13];
  const float* gamma= (const float*)d_in[14];
  const float* beta = (const float*)d_in[15];
  const float* Wv1  = (const float*)d_in[16];
  const float* bv1  = (const float*)d_in[17];
  const float* Wv2  = (const float*)d_in[18];
  const float* bv2  = (const float*)d_in[19];
  const float* Wp1  = (const float*)d_in[20];
  const float* bp1  = (const float*)d_in[21];
  const float* Wp2  = (const float*)d_in[22];
  const float* bp2  = (const float*)d_in[23];

  float* outv = (float*)d_out;                      // [G,3]
  float* outp = outv + (size_t)N_GRAPHS * 3;        // [E]

  float* hA    = (float*)d_ws;
  float* hB    = hA  + (size_t)N_NODES * HID;
  float* tmp   = hB  + (size_t)N_NODES * HID;
  float* xlb   = tmp + (size_t)N_NODES * HID;
  float* xrb   = xlb + (size_t)N_NODES * HID;
  float* stats = xrb + (size_t)N_NODES * HID;
  int* off    = (int*)(stats + NLAYERS * 256);
  int* cursor = off + (N_NODES + 1);
  int* bsum   = cursor + N_NODES;
  int2* elist2 = (int2*)(bsum + 256);

  const int NB = (N_NODES + 255) / 256;
  const int EB = (N_EDGES + 255) / 256;

  zero_kernel<<<NB, 256, 0, stream>>>(off, cursor, stats);
  count_kernel<<<EB, 256, 0, stream>>>(dst, off);
  scan1_kernel<<<NB, 256, 0, stream>>>(off, bsum);
  scan2_kernel<<<1, 256, 0, stream>>>(bsum, NB);
  scan3_kernel<<<NB, 256, 0, stream>>>(off, bsum);
  scatter_kernel<<<EB, 256, 0, stream>>>(src, dst, off, cursor, elist2);
  inproj_kernel<<<N_NODES / 2, 256, 0, stream>>>(x, Win, b_in, hA);

  const int GB = (N_NODES + 31) / 32;
  const int GATB = (N_NODES + 7) / 8;
  const int APB = (N_NODES * 32 + 255) / 256;

  for (int b2 = 0; b2 < 4; b2++) {
    int i = 2 * b2, j = i + 1;
    // layer i: hA -> hB
    gemm2_kernel<128, true><<<GB, 256, 0, stream>>>(hA,
        Wl + (size_t)i * HID * HID, bl + i * HID, xlb,
        Wr + (size_t)i * HID * HID, br + i * HID, xrb, N_NODES);
    gat_kernel<<<GATB, 256, 0, stream>>>(xlb, xrb, ea, elist2, off,
                                         We + (size_t)i * EDIM * HID, att + (size_t)i * HID,
                                         bo + (size_t)i * HID, tmp, stats + i * 256);
    bnapply_kernel<<<APB, 256, 0, stream>>>(tmp, nullptr, stats + i * 256, gamma + i * HID, beta + i * HID, hB);
    // layer j: hB -> hA (residual = hA)
    gemm2_kernel<128, true><<<GB, 256, 0, stream>>>(hB,
        Wl + (size_t)j * HID * HID, bl + j * HID, xlb,
        Wr + (size_t)j * HID * HID, br + j * HID, xrb, N_NODES);
    gat_kernel<<<GATB, 256, 0, stream>>>(xlb, xrb, ea, elist2, off,
                                         We + (size_t)j * EDIM * HID, att + (size_t)j * HID,
                                         bo + (size_t)j * HID, tmp, stats + j * 256);
    bnapply_kernel<<<APB, 256, 0, stream>>>(tmp, hA, stats + j * 256, gamma + j * HID, beta + j * HID, hA);
  }

  // policy head: Psrc/Pdst node projections reuse xlb
  float* Ps = xlb;
  float* Pd = xlb + (size_t)N_NODES * 64;
  gemm2_kernel<64, false><<<GB, 256, 0, stream>>>(hA,
      Wp1, nullptr, Ps, Wp1 + 128 * 64, nullptr, Pd, N_NODES);
  policy_kernel<<<(N_EDGES + 15) / 16, 256, 0, stream>>>(Ps, Pd, src, dst, ea,
                                                         Wp1 + 256 * 64, bp1, Wp2, bp2, outp);
  poolvalue_kernel<<<N_GRAPHS, 128, 0, stream>>>(hA, batch, Wv1, bv1, Wv2, bv2, outv);
}

// Round 4
// 2438.236 us; speedup vs baseline: 1.0103x; 1.0103x over previous
//
#include <hip/hip_runtime.h>
#include <math.h>

#define N_NODES 50000
#define N_EDGES 500000
#define N_GRAPHS 2048
#define HID 128
#define EDIM 12
#define NLAYERS 8
#define EPS_BN 1e-5f

// ---------------- CSR build ----------------
__global__ void zero_kernel(int* deg, int* cursor, float* stats) {
  int i = blockIdx.x * 256 + threadIdx.x;
  if (i < N_NODES) { deg[i] = 0; cursor[i] = 0; }
  if (i < NLAYERS * 256) stats[i] = 0.f;
}

__global__ void count_kernel(const int* __restrict__ dst, int* __restrict__ deg) {
  int e = blockIdx.x * 256 + threadIdx.x;
  if (e < N_EDGES) atomicAdd(&deg[dst[e]], 1);
}

__global__ void scan1_kernel(int* __restrict__ off, int* __restrict__ bsum) {
  __shared__ int s[256];
  int t = threadIdx.x; int n = blockIdx.x * 256 + t;
  int x = (n < N_NODES) ? off[n] : 0;
  s[t] = x; __syncthreads();
  for (int o = 1; o < 256; o <<= 1) {
    int v = (t >= o) ? s[t - o] : 0;
    __syncthreads(); s[t] += v; __syncthreads();
  }
  if (n < N_NODES) off[n] = s[t] - x;   // block-local exclusive
  if (t == 255) bsum[blockIdx.x] = s[255];
}

__global__ void scan2_kernel(int* __restrict__ bsum, int nb) {
  __shared__ int s[256];
  int t = threadIdx.x;
  int x = (t < nb) ? bsum[t] : 0;
  s[t] = x; __syncthreads();
  for (int o = 1; o < 256; o <<= 1) {
    int v = (t >= o) ? s[t - o] : 0;
    __syncthreads(); s[t] += v; __syncthreads();
  }
  if (t < nb) bsum[t] = s[t] - x;       // exclusive
}

__global__ void scan3_kernel(int* __restrict__ off, const int* __restrict__ bsum) {
  int t = threadIdx.x; int n = blockIdx.x * 256 + t;
  if (n < N_NODES) off[n] += bsum[blockIdx.x];
  if (n == 0 && blockIdx.x == 0) off[N_NODES] = N_EDGES;
}

__device__ inline unsigned pk_bf16(float a, float b) {
  unsigned ua = __float_as_uint(a), ub = __float_as_uint(b);
  ua = (ua + 0x7FFFu + ((ua >> 16) & 1u)) >> 16;   // RNE
  ub = (ub + 0x7FFFu + ((ub >> 16) & 1u)) >> 16;
  return ua | (ub << 16);
}

// builds: srcperm[pos] = src[e]; eaperm[pos] = bf16(edge_attr[e]) (8-dword stride)
__global__ void scatter_kernel(const int* __restrict__ src, const int* __restrict__ dst,
                               const float* __restrict__ ea,
                               const int* __restrict__ off, int* __restrict__ cursor,
                               int* __restrict__ srcperm, unsigned* __restrict__ eap32) {
  int e = blockIdx.x * 256 + threadIdx.x;
  if (e < N_EDGES) {
    int d = dst[e];
    int p = atomicAdd(&cursor[d], 1);
    int pos = off[d] + p;
    srcperm[pos] = src[e];
    const float* eap = &ea[(size_t)e * EDIM];
    float4 e0 = *(const float4*)eap;
    float4 e1 = *(const float4*)(eap + 4);
    float4 e2 = *(const float4*)(eap + 8);
    uint4 q;
    q.x = pk_bf16(e0.x, e0.y); q.y = pk_bf16(e0.z, e0.w);
    q.z = pk_bf16(e1.x, e1.y); q.w = pk_bf16(e1.z, e1.w);
    unsigned* o = &eap32[(size_t)pos * 8];
    *(uint4*)o = q;
    *(uint2*)(o + 4) = make_uint2(pk_bf16(e2.x, e2.y), pk_bf16(e2.z, e2.w));
  }
}

// ---------------- input projection ----------------
__global__ void inproj_kernel(const float* __restrict__ x, const float* __restrict__ Win,
                              const float* __restrict__ b_in, float* __restrict__ h) {
  __shared__ float xs[44];
  int t = threadIdx.x;
  int n0 = blockIdx.x * 2;
  if (t < 44) {
    int n = n0 + t / 22;
    xs[t] = (n < N_NODES) ? x[n0 * 22 + t] : 0.f;
  }
  __syncthreads();
  int c = t & 127, half = t >> 7;
  int n = n0 + half;
  if (n < N_NODES) {
    float acc = b_in[c];
#pragma unroll
    for (int k = 0; k < 22; k++) acc = fmaf(xs[half * 22 + k], Win[k * HID + c], acc);
    h[n * HID + c] = fmaxf(acc, 0.f);
  }
}

// ---------------- fused dual f32 GEMM: C1 = A@W1 (+b1), C2 = A@W2 (+b2) ----------------
template <int CO, bool BIAS>
__global__ __launch_bounds__(256) void gemm2_kernel(
    const float* __restrict__ A,
    const float* __restrict__ W1, const float* __restrict__ b1, float* __restrict__ C1,
    const float* __restrict__ W2, const float* __restrict__ b2, float* __restrict__ C2,
    int nrows) {
  __shared__ float As[32 * 128];
  constexpr int CW = CO / 32;
  int t = threadIdx.x;
  int brow = blockIdx.x * 32;
#pragma unroll
  for (int i = 0; i < 4; i++) {
    int f = t + i * 256;
    int r = f >> 5, cf = (f & 31) << 2;
    int g = brow + r;
    float4 v = (g < nrows) ? *(const float4*)&A[(size_t)g * 128 + cf] : make_float4(0.f, 0.f, 0.f, 0.f);
    *(float4*)&As[r * 128 + cf] = v;
  }
  __syncthreads();
  int cgrp = t & 31, rgrp = t >> 5;
  int c0 = cgrp * CW, r0 = rgrp * 4;
  float acc1[4][CW], acc2[4][CW];
#pragma unroll
  for (int r = 0; r < 4; r++)
#pragma unroll
    for (int c = 0; c < CW; c++) { acc1[r][c] = 0.f; acc2[r][c] = 0.f; }

  for (int k = 0; k < 128; k += 4) {
    float a[4][4];
#pragma unroll
    for (int r = 0; r < 4; r++) {
      float4 av = *(const float4*)&As[(r0 + r) * 128 + k];
      a[r][0] = av.x; a[r][1] = av.y; a[r][2] = av.z; a[r][3] = av.w;
    }
#pragma unroll
    for (int kk = 0; kk < 4; kk++) {
      float w1[CW], w2[CW];
      if constexpr (CW == 4) {
        float4 wv = *(const float4*)&W1[(k + kk) * CO + c0];
        w1[0] = wv.x; w1[1] = wv.y; w1[2] = wv.z; w1[3] = wv.w;
        float4 wu = *(const float4*)&W2[(k + kk) * CO + c0];
        w2[0] = wu.x; w2[1] = wu.y; w2[2] = wu.z; w2[3] = wu.w;
      } else {
        float2 wv = *(const float2*)&W1[(k + kk) * CO + c0];
        w1[0] = wv.x; w1[1] = wv.y;
        float2 wu = *(const float2*)&W2[(k + kk) * CO + c0];
        w2[0] = wu.x; w2[1] = wu.y;
      }
#pragma unroll
      for (int r = 0; r < 4; r++)
#pragma unroll
        for (int c = 0; c < CW; c++) {
          acc1[r][c] = fmaf(a[r][kk], w1[c], acc1[r][c]);
          acc2[r][c] = fmaf(a[r][kk], w2[c], acc2[r][c]);
        }
    }
  }
  float bb1[CW], bb2[CW];
#pragma unroll
  for (int c = 0; c < CW; c++) {
    bb1[c] = BIAS ? b1[c0 + c] : 0.f;
    bb2[c] = BIAS ? b2[c0 + c] : 0.f;
  }
#pragma unroll
  for (int r = 0; r < 4; r++) {
    int g = brow + r0 + r;
    if (g < nrows) {
      float o1[CW], o2[CW];
#pragma unroll
      for (int c = 0; c < CW; c++) { o1[c] = acc1[r][c] + bb1[c]; o2[c] = acc2[r][c] + bb2[c]; }
      if constexpr (CW == 4) {
        *(float4*)&C1[(size_t)g * CO + c0] = *(float4*)&o1[0];
        *(float4*)&C2[(size_t)g * CO + c0] = *(float4*)&o2[0];
      } else {
        *(float2*)&C1[(size_t)g * CO + c0] = *(float2*)&o1[0];
        *(float2*)&C2[(size_t)g * CO + c0] = *(float2*)&o2[0];
      }
    }
  }
}

// ---------------- GATv2 aggregation ----------------
// Half-node per wave: wave handles 64 channels (2 heads) of one node, 1 ch/lane.
// Two interleaved edge-chains per wave over the node's CSR range (merged at end).
// srcperm/eaperm are CSR-ordered -> streaming; only xl[] is a dependent gather.
__global__ __launch_bounds__(256, 8) void gat_kernel(
    const float* __restrict__ xl, const float* __restrict__ xr,
    const unsigned* __restrict__ eap32, const int* __restrict__ srcperm,
    const int* __restrict__ off,
    const float* __restrict__ Wel, const float* __restrict__ attl,
    const float* __restrict__ bol, float* __restrict__ out) {
  int lane = threadIdx.x & 63;
  int wid = threadIdx.x >> 6;            // 0..3
  int node = blockIdx.x * 2 + (wid >> 1);
  if (node >= N_NODES) return;
  int c = (wid & 1) * 64 + lane;         // channel 0..127 (head = c/32)

  float wk[12];
#pragma unroll
  for (int k = 0; k < 12; k++) wk[k] = Wel[k * HID + c];
  float at = attl[c];
  float xr1 = xr[(size_t)node * HID + c];
  int is = off[node], ie = off[node + 1];
  int deg = ie - is;
  int len1 = deg >> 1, len0 = deg - len1;  // len0 >= len1
  int base1 = is + len0;

  float m0 = -INFINITY, d0 = 0.f, a0 = 0.f;
  float m1 = -INFINITY, d1 = 0.f, a1 = 0.f;

  for (int i = 0; i < len0; i++) {
    bool ok1 = i < len1;
    int i0 = is + i;
    int i1 = ok1 ? base1 + i : is;
    // streaming loads (addresses independent of prior loads)
    int s0 = srcperm[i0];
    int s1 = srcperm[i1];
    const unsigned* p0 = &eap32[(size_t)i0 * 8];
    const unsigned* p1 = &eap32[(size_t)i1 * 8];
    uint4 qa0 = *(const uint4*)p0;
    uint2 qb0 = *(const uint2*)(p0 + 4);
    uint4 qa1 = *(const uint4*)p1;
    uint2 qb1 = *(const uint2*)(p1 + 4);
    // single dependent gather per chain
    float xl0 = xl[(size_t)s0 * HID + c];
    float xl1 = xl[(size_t)s1 * HID + c];

    unsigned q0[6] = {qa0.x, qa0.y, qa0.z, qa0.w, qb0.x, qb0.y};
    unsigned q1[6] = {qa1.x, qa1.y, qa1.z, qa1.w, qb1.x, qb1.y};
    float ep0 = 0.f, ep1 = 0.f;
#pragma unroll
    for (int k = 0; k < 6; k++) {
      ep0 = fmaf(__uint_as_float(q0[k] << 16), wk[2 * k], ep0);
      ep0 = fmaf(__uint_as_float(q0[k] & 0xFFFF0000u), wk[2 * k + 1], ep0);
      ep1 = fmaf(__uint_as_float(q1[k] << 16), wk[2 * k], ep1);
      ep1 = fmaf(__uint_as_float(q1[k] & 0xFFFF0000u), wk[2 * k + 1], ep1);
    }
    float t0 = xl0 + xr1 + ep0; t0 = (t0 > 0.f) ? t0 : 0.2f * t0;
    float t1 = xl1 + xr1 + ep1; t1 = (t1 > 0.f) ? t1 : 0.2f * t1;
    float v0 = t0 * at;
    float v1 = t1 * at;
    // per-head reduce over 32 lanes (xor 1..16 stays within 32-lane halves)
#pragma unroll
    for (int o = 1; o <= 16; o <<= 1) {
      v0 += __shfl_xor(v0, o);
      v1 += __shfl_xor(v1, o);
    }
    v1 = ok1 ? v1 : -INFINITY;
    // online softmax, chain 0 (v0 always valid)
    float mn0 = fmaxf(m0, v0);
    float sc0 = __expf(m0 - mn0);          // exp(-inf)=0 on first iter
    float pp0 = __expf(v0 - mn0);
    d0 = fmaf(d0, sc0, pp0);
    a0 = fmaf(a0, sc0, pp0 * xl0);
    m0 = mn0;
    // online softmax, chain 1 (may be empty/masked)
    float mn1 = fmaxf(m1, v1);
    float sc1 = (mn1 > -INFINITY) ? __expf(m1 - mn1) : 0.f;
    float pp1 = ok1 ? __expf(v1 - mn1) : 0.f;
    d1 = fmaf(d1, sc1, pp1);
    a1 = fmaf(a1, sc1, pp1 * xl1);
    m1 = mn1;
  }

  // merge the two chains
  float mn = fmaxf(m0, m1);
  float s0 = (m0 > -INFINITY) ? __expf(m0 - mn) : 0.f;
  float s1 = (m1 > -INFINITY) ? __expf(m1 - mn) : 0.f;
  float den = d0 * s0 + d1 * s1;
  float acc = a0 * s0 + a1 * s1;
  out[(size_t)node * HID + c] = acc / (den + 1e-16f) + bol[c];
}

// ---------------- BatchNorm stats ----------------
__global__ void bnstats_kernel(const float* __restrict__ t, float* __restrict__ sums) {
  int tid = threadIdx.x;
  int c = tid & 127, half = tid >> 7;
  float s = 0.f, q = 0.f;
  for (int n = blockIdx.x * 2 + half; n < N_NODES; n += 512) {
    float v = t[(size_t)n * HID + c];
    s += v; q = fmaf(v, v, q);
  }
  __shared__ float ls[256], lq[256];
  ls[tid] = s; lq[tid] = q;
  __syncthreads();
  if (tid < 128) {
    atomicAdd(&sums[c], ls[tid] + ls[tid + 128]);
    atomicAdd(&sums[128 + c], lq[tid] + lq[tid + 128]);
  }
}

__global__ void bnapply_kernel(const float* __restrict__ t, const float* __restrict__ res,
                               const float* __restrict__ sums, const float* __restrict__ gamma,
                               const float* __restrict__ beta, float* __restrict__ hout) {
  int i4 = blockIdx.x * 256 + threadIdx.x;
  if (i4 >= N_NODES * 32) return;
  int c0 = (i4 & 31) << 2;
  const float invN = 1.f / (float)N_NODES;
  float4 tv = *(const float4*)&t[(size_t)i4 * 4];
  float4 sm = *(const float4*)&sums[c0];
  float4 sq = *(const float4*)&sums[128 + c0];
  float4 gm = *(const float4*)&gamma[c0];
  float4 bt = *(const float4*)&beta[c0];
  float4 rv = make_float4(0.f, 0.f, 0.f, 0.f);
  if (res) rv = *(const float4*)&res[(size_t)i4 * 4];
  float4 o;
#define BN1(comp)                                                   \
  {                                                                 \
    float mu = sm.comp * invN;                                      \
    float var = sq.comp * invN - mu * mu;                           \
    float rs = rsqrtf(var + EPS_BN);                                \
    float v = (tv.comp - mu) * rs * gm.comp + bt.comp + rv.comp;    \
    o.comp = fmaxf(v, 0.f);                                         \
  }
  BN1(x) BN1(y) BN1(z) BN1(w)
#undef BN1
  *(float4*)&hout[(size_t)i4 * 4] = o;
}

// ---------------- policy head (one edge per 16 lanes) ----------------
__global__ __launch_bounds__(256) void policy_kernel(
    const float* __restrict__ Ps, const float* __restrict__ Pd,
    const int* __restrict__ src, const int* __restrict__ dst,
    const float* __restrict__ edge_attr, const float* __restrict__ Wp1e,
    const float* __restrict__ bp1, const float* __restrict__ Wp2,
    const float* __restrict__ bp2, float* __restrict__ outp) {
  int lane = threadIdx.x & 63;
  int j = lane & 15;  // channels 4j..4j+3
  int e = (blockIdx.x * 256 + threadIdx.x) >> 4;
  if (e >= N_EDGES) return;
  float4 we[12];
#pragma unroll
  for (int k = 0; k < 12; k++) we[k] = *(const float4*)&Wp1e[k * 64 + j * 4];
  float4 b4 = *(const float4*)&bp1[j * 4];
  float4 w2 = *(const float4*)&Wp2[j * 4];
  float bp2c = bp2[0];
  int s = src[e], d = dst[e];
  const float* eap = &edge_attr[(size_t)e * EDIM];
  float4 e0 = *(const float4*)eap;
  float4 e1 = *(const float4*)(eap + 4);
  float4 e2 = *(const float4*)(eap + 8);
  float4 ps = *(const float4*)&Ps[(size_t)s * 64 + j * 4];
  float4 pd = *(const float4*)&Pd[(size_t)d * 64 + j * 4];
  float eav[12] = {e0.x, e0.y, e0.z, e0.w, e1.x, e1.y, e1.z, e1.w, e2.x, e2.y, e2.z, e2.w};
  float hx = ps.x + pd.x + b4.x;
  float hy = ps.y + pd.y + b4.y;
  float hz = ps.z + pd.z + b4.z;
  float hw = ps.w + pd.w + b4.w;
#pragma unroll
  for (int k = 0; k < 12; k++) {
    hx = fmaf(eav[k], we[k].x, hx);
    hy = fmaf(eav[k], we[k].y, hy);
    hz = fmaf(eav[k], we[k].z, hz);
    hw = fmaf(eav[k], we[k].w, hw);
  }
  hx = fmaxf(hx, 0.f); hy = fmaxf(hy, 0.f); hz = fmaxf(hz, 0.f); hw = fmaxf(hw, 0.f);
  float v = fmaf(hx, w2.x, fmaf(hy, w2.y, fmaf(hz, w2.z, hw * w2.w)));
  v += __shfl_xor(v, 1);
  v += __shfl_xor(v, 2);
  v += __shfl_xor(v, 4);
  v += __shfl_xor(v, 8);
  if (j == 0) outp[e] = v + bp2c;
}

// ---------------- pooled mean + value head ----------------
__device__ int lower_bound_dev(const int* a, int n, int key) {
  int lo = 0, hi = n;
  while (lo < hi) {
    int mid = (lo + hi) >> 1;
    if (a[mid] < key) lo = mid + 1; else hi = mid;
  }
  return lo;
}

__global__ void poolvalue_kernel(const float* __restrict__ h, const int* __restrict__ batch,
                                 const float* __restrict__ Wv1, const float* __restrict__ bv1,
                                 const float* __restrict__ Wv2, const float* __restrict__ bv2,
                                 float* __restrict__ outv) {
  __shared__ float pl[128];
  __shared__ float hd[64];
  __shared__ int range[2];
  int g = blockIdx.x, t = threadIdx.x;
  if (t == 0) {
    range[0] = lower_bound_dev(batch, N_NODES, g);
    range[1] = lower_bound_dev(batch, N_NODES, g + 1);
  }
  __syncthreads();
  int lo = range[0], hi = range[1];
  float s = 0.f;
  for (int n = lo; n < hi; n++) s += h[(size_t)n * HID + t];
  float cnt = (float)(hi - lo);
  pl[t] = s / fmaxf(cnt, 1.f);
  __syncthreads();
  if (t < 64) {
    float a = bv1[t];
    for (int c = 0; c < 128; c++) a = fmaf(pl[c], Wv1[c * 64 + t], a);
    hd[t] = fmaxf(a, 0.f);
  }
  __syncthreads();
  if (t < 3) {
    float a = bv2[t];
    for (int j = 0; j < 64; j++) a = fmaf(hd[j], Wv2[j * 3 + t], a);
    outv[g * 3 + t] = a;
  }
}

// ---------------- host ----------------
extern "C" void kernel_launch(void* const* d_in, const int* in_sizes, int n_in,
                              void* d_out, int out_size, void* d_ws, size_t ws_size,
                              hipStream_t stream) {
  (void)in_sizes; (void)n_in; (void)out_size; (void)ws_size;
  const float* x    = (const float*)d_in[0];
  const int*   src  = (const int*)d_in[1];
  const int*   dst  = (const int*)d_in[2];
  const int*   batch= (const int*)d_in[3];
  const float* ea   = (const float*)d_in[4];
  const float* Win  = (const float*)d_in[5];
  const float* b_in = (const float*)d_in[6];
  const float* Wl   = (const float*)d_in[7];
  const float* bl   = (const float*)d_in[8];
  const float* Wr   = (const float*)d_in[9];
  const float* br   = (const float*)d_in[10];
  const float* We   = (const float*)d_in[11];
  const float* att  = (const float*)d_in[12];
  const float* bo   = (const float*)d_in[13];
  const float* gamma= (const float*)d_in[14];
  const float* beta = (const float*)d_in[15];
  const float* Wv1  = (const float*)d_in[16];
  const float* bv1  = (const float*)d_in[17];
  const float* Wv2  = (const float*)d_in[18];
  const float* bv2  = (const float*)d_in[19];
  const float* Wp1  = (const float*)d_in[20];
  const float* bp1  = (const float*)d_in[21];
  const float* Wp2  = (const float*)d_in[22];
  const float* bp2  = (const float*)d_in[23];

  float* outv = (float*)d_out;                      // [G,3]
  float* outp = outv + (size_t)N_GRAPHS * 3;        // [E]

  float* hA    = (float*)d_ws;
  float* hB    = hA  + (size_t)N_NODES * HID;
  float* tmp   = hB  + (size_t)N_NODES * HID;
  float* xlb   = tmp + (size_t)N_NODES * HID;
  float* xrb   = xlb + (size_t)N_NODES * HID;
  float* stats = xrb + (size_t)N_NODES * HID;
  int* off    = (int*)(stats + NLAYERS * 256);
  int* cursor = off + (N_NODES + 1);
  int* bsum   = cursor + N_NODES;
  int* srcperm = bsum + 256;
  unsigned* eap32 = (unsigned*)(((uintptr_t)(srcperm + N_EDGES) + 15) & ~(uintptr_t)15);

  const int NB = (N_NODES + 255) / 256;
  const int EB = (N_EDGES + 255) / 256;

  zero_kernel<<<NB, 256, 0, stream>>>(off, cursor, stats);
  count_kernel<<<EB, 256, 0, stream>>>(dst, off);
  scan1_kernel<<<NB, 256, 0, stream>>>(off, bsum);
  scan2_kernel<<<1, 256, 0, stream>>>(bsum, NB);
  scan3_kernel<<<NB, 256, 0, stream>>>(off, bsum);
  scatter_kernel<<<EB, 256, 0, stream>>>(src, dst, ea, off, cursor, srcperm, eap32);
  inproj_kernel<<<N_NODES / 2, 256, 0, stream>>>(x, Win, b_in, hA);

  const int GB = (N_NODES + 31) / 32;
  const int GATB = (N_NODES + 1) / 2;   // 2 nodes per block (4 waves)
  const int APB = (N_NODES * 32 + 255) / 256;

  for (int b2 = 0; b2 < 4; b2++) {
    int i = 2 * b2, j = i + 1;
    // layer i: hA -> hB
    gemm2_kernel<128, true><<<GB, 256, 0, stream>>>(hA,
        Wl + (size_t)i * HID * HID, bl + i * HID, xlb,
        Wr + (size_t)i * HID * HID, br + i * HID, xrb, N_NODES);
    gat_kernel<<<GATB, 256, 0, stream>>>(xlb, xrb, eap32, srcperm, off,
                                         We + (size_t)i * EDIM * HID, att + (size_t)i * HID,
                                         bo + (size_t)i * HID, tmp);
    bnstats_kernel<<<256, 256, 0, stream>>>(tmp, stats + i * 256);
    bnapply_kernel<<<APB, 256, 0, stream>>>(tmp, nullptr, stats + i * 256, gamma + i * HID, beta + i * HID, hB);
    // layer j: hB -> hA (residual = hA)
    gemm2_kernel<128, true><<<GB, 256, 0, stream>>>(hB,
        Wl + (size_t)j * HID * HID, bl + j * HID, xlb,
        Wr + (size_t)j * HID * HID, br + j * HID, xrb, N_NODES);
    gat_kernel<<<GATB, 256, 0, stream>>>(xlb, xrb, eap32, srcperm, off,
                                         We + (size_t)j * EDIM * HID, att + (size_t)j * HID,
                                         bo + (size_t)j * HID, tmp);
    bnstats_kernel<<<256, 256, 0, stream>>>(tmp, stats + j * 256);
    bnapply_kernel<<<APB, 256, 0, stream>>>(tmp, hA, stats + j * 256, gamma + j * HID, beta + j * HID, hA);
  }

  // policy head
  float* Ps = xlb;
  float* Pd = xlb + (size_t)N_NODES * 64;
  gemm2_kernel<64, false><<<GB, 256, 0, stream>>>(hA,
      Wp1, nullptr, Ps, Wp1 + 128 * 64, nullptr, Pd, N_NODES);
  policy_kernel<<<(N_EDGES + 15) / 16, 256, 0, stream>>>(Ps, Pd, src, dst, ea,
                                                         Wp1 + 256 * 64, bp1, Wp2, bp2, outp);
  poolvalue_kernel<<<N_GRAPHS, 128, 0, stream>>>(hA, batch, Wv1, bv1, Wv2, bv2, outv);
}

// Round 6
// 1564.500 us; speedup vs baseline: 1.5744x; 1.5585x over previous
//
#include <hip/hip_runtime.h>
#include <math.h>

#define N_NODES 50000
#define N_EDGES 500000
#define N_GRAPHS 2048
#define HID 128
#define EDIM 12
#define NLAYERS 8
#define EPS_BN 1e-5f

typedef __attribute__((ext_vector_type(8))) short short8;
typedef __attribute__((ext_vector_type(4))) float f32x4;
typedef unsigned int uint;
typedef unsigned short ushort;

__device__ inline ushort f2bf(float x) {
  unsigned u = __float_as_uint(x);
  u = (u + 0x7FFFu + ((u >> 16) & 1u)) >> 16;  // RNE
  return (ushort)u;
}
__device__ inline unsigned pk_bf16(float a, float b) {
  return (unsigned)f2bf(a) | ((unsigned)f2bf(b) << 16);
}
__device__ inline float bflo(uint q) { return __uint_as_float(q << 16); }
__device__ inline float bfhi(uint q) { return __uint_as_float(q & 0xFFFF0000u); }

// ---------------- CSR build ----------------
__global__ void zero_kernel(int* deg, int* cursor, float* stats) {
  int i = blockIdx.x * 256 + threadIdx.x;
  if (i < N_NODES) { deg[i] = 0; cursor[i] = 0; }
  if (i < NLAYERS * 256) stats[i] = 0.f;
}

__global__ void count_kernel(const int* __restrict__ dst, int* __restrict__ deg) {
  int e = blockIdx.x * 256 + threadIdx.x;
  if (e < N_EDGES) atomicAdd(&deg[dst[e]], 1);
}

__global__ void scan1_kernel(int* __restrict__ off, int* __restrict__ bsum) {
  __shared__ int s[256];
  int t = threadIdx.x; int n = blockIdx.x * 256 + t;
  int x = (n < N_NODES) ? off[n] : 0;
  s[t] = x; __syncthreads();
  for (int o = 1; o < 256; o <<= 1) {
    int v = (t >= o) ? s[t - o] : 0;
    __syncthreads(); s[t] += v; __syncthreads();
  }
  if (n < N_NODES) off[n] = s[t] - x;
  if (t == 255) bsum[blockIdx.x] = s[255];
}

__global__ void scan2_kernel(int* __restrict__ bsum, int nb) {
  __shared__ int s[256];
  int t = threadIdx.x;
  int x = (t < nb) ? bsum[t] : 0;
  s[t] = x; __syncthreads();
  for (int o = 1; o < 256; o <<= 1) {
    int v = (t >= o) ? s[t - o] : 0;
    __syncthreads(); s[t] += v; __syncthreads();
  }
  if (t < nb) bsum[t] = s[t] - x;
}

__global__ void scan3_kernel(int* __restrict__ off, const int* __restrict__ bsum) {
  int t = threadIdx.x; int n = blockIdx.x * 256 + t;
  if (n < N_NODES) off[n] += bsum[blockIdx.x];
  if (n == 0 && blockIdx.x == 0) off[N_NODES] = N_EDGES;
}

// srcperm[pos]=src[e]; eap32[pos]=bf16(edge_attr[e]) packed, stride 8 dwords
__global__ void scatter_kernel(const int* __restrict__ src, const int* __restrict__ dst,
                               const float* __restrict__ ea,
                               const int* __restrict__ off, int* __restrict__ cursor,
                               int* __restrict__ srcperm, unsigned* __restrict__ eap32) {
  int e = blockIdx.x * 256 + threadIdx.x;
  if (e < N_EDGES) {
    int d = dst[e];
    int p = atomicAdd(&cursor[d], 1);
    int pos = off[d] + p;
    srcperm[pos] = src[e];
    const float* eap = &ea[(size_t)e * EDIM];
    float4 e0 = *(const float4*)eap;
    float4 e1 = *(const float4*)(eap + 4);
    float4 e2 = *(const float4*)(eap + 8);
    uint4 q;
    q.x = pk_bf16(e0.x, e0.y); q.y = pk_bf16(e0.z, e0.w);
    q.z = pk_bf16(e1.x, e1.y); q.w = pk_bf16(e1.z, e1.w);
    unsigned* o = &eap32[(size_t)pos * 8];
    *(uint4*)o = q;
    *(uint2*)(o + 4) = make_uint2(pk_bf16(e2.x, e2.y), pk_bf16(e2.z, e2.w));
  }
}

// ---------------- weight packing for MFMA fragments ----------------
// wpk[layer][(kb*256+cc)*32+kk] = bf16( cc<128 ? Wl[layer][kb*32+kk][cc] : Wr[layer][kb*32+kk][cc-128] )
__global__ void wprep_kernel(const float* __restrict__ Wl, const float* __restrict__ Wr,
                             ushort* __restrict__ wpk) {
  int idx = blockIdx.x * 256 + threadIdx.x;
  if (idx >= NLAYERS * 4 * 256 * 32) return;
  int kk = idx & 31;
  int cc = (idx >> 5) & 255;
  int kb = (idx >> 13) & 3;
  int layer = idx >> 15;
  int k = kb * 32 + kk;
  float v = (cc < 128) ? Wl[((size_t)layer * 128 + k) * 128 + cc]
                       : Wr[((size_t)layer * 128 + k) * 128 + (cc - 128)];
  wpk[idx] = f2bf(v);
}

// wppk[(kb*128+cc)*32+kk] = bf16( cc<64 ? Wp1[kb*32+kk][cc] : Wp1[128+kb*32+kk][cc-64] )
__global__ void wprep_pol_kernel(const float* __restrict__ Wp1, ushort* __restrict__ wppk) {
  int idx = blockIdx.x * 256 + threadIdx.x;
  if (idx >= 4 * 128 * 32) return;
  int kk = idx & 31;
  int cc = (idx >> 5) & 127;
  int kb = idx >> 12;
  int k = kb * 32 + kk;
  float v = (cc < 64) ? Wp1[(size_t)k * 64 + cc] : Wp1[(size_t)(128 + k) * 64 + (cc - 64)];
  wppk[idx] = f2bf(v);
}

// ---------------- input projection (writes f32 h + bf16 shadow) ----------------
__global__ void inproj_kernel(const float* __restrict__ x, const float* __restrict__ Win,
                              const float* __restrict__ b_in, float* __restrict__ h,
                              ushort* __restrict__ h16) {
  __shared__ float xs[44];
  int t = threadIdx.x;
  int n0 = blockIdx.x * 2;
  if (t < 44) xs[t] = x[n0 * 22 + t];
  __syncthreads();
  int c = t & 127, half = t >> 7;
  int n = n0 + half;
  if (n < N_NODES) {
    float acc = b_in[c];
#pragma unroll
    for (int k = 0; k < 22; k++) acc = fmaf(xs[half * 22 + k], Win[k * HID + c], acc);
    float v = fmaxf(acc, 0.f);
    h[(size_t)n * HID + c] = v;
    h16[(size_t)n * HID + c] = f2bf(v);
  }
}

// ---------------- MFMA GEMM: [C1|C2] = A16 @ Wpk (+bias), 64x NOUT tile ----------------
// A16: [nrows][128] bf16. Wpk: fragment-packed [4][NOUT][32] bf16.
// Output split at SPLIT: C1 cols [0,SPLIT), C2 cols [SPLIT,NOUT); row stride = SPLIT.
template <int NOUT, int SPLIT, bool BIAS, bool OUTBF16>
__global__ __launch_bounds__(256) void gemm_mfma_kernel(
    const ushort* __restrict__ A16, const ushort* __restrict__ Wpk,
    const float* __restrict__ b1, const float* __restrict__ b2,
    void* __restrict__ C1v, void* __restrict__ C2v, int nrows) {
  __shared__ ushort As[64][136];  // +8 pad breaks bank aliasing
  int t = threadIdx.x;
  int brow = blockIdx.x * 64;
  // 64 rows x 128 cols bf16 = 1024 x 16B chunks: 16 chunks/row
#pragma unroll
  for (int i = 0; i < 4; i++) {
    int f = t + i * 256;          // 0..1023
    int r = f >> 4;               // 0..63   (FIXED: was f>>3)
    int cg = (f & 15) * 8;        // 0..120  (FIXED: was (f&7)*8)
    int g = brow + r;
    uint4 v = make_uint4(0, 0, 0, 0);
    if (g < nrows) v = *(const uint4*)&A16[(size_t)g * HID + cg];
    *(uint4*)&As[r][cg] = v;
  }
  __syncthreads();
  int lane = t & 63, wave = t >> 6;
  int arow = wave * 16 + (lane & 15);
  int k8 = (lane >> 4) * 8;
  constexpr int NT = NOUT / 16;
  f32x4 acc[NT];
#pragma unroll
  for (int n = 0; n < NT; n++) acc[n] = (f32x4){0.f, 0.f, 0.f, 0.f};
#pragma unroll
  for (int kb = 0; kb < 4; kb++) {
    short8 a = *(const short8*)&As[arow][kb * 32 + k8];
#pragma unroll
    for (int n = 0; n < NT; n++) {
      int col = n * 16 + (lane & 15);
      short8 b = *(const short8*)&Wpk[((size_t)(kb * NOUT + col)) * 32 + k8];
      acc[n] = __builtin_amdgcn_mfma_f32_16x16x32_bf16(a, b, acc[n], 0, 0, 0);
    }
  }
  // C/D layout (m89-verified): col = lane&15, row = (lane>>4)*4 + j
  int rbase = brow + wave * 16 + (lane >> 4) * 4;
  int ccol = lane & 15;
#pragma unroll
  for (int n = 0; n < NT; n++) {
    int col = n * 16 + ccol;
    float bias = 0.f;
    if (BIAS) bias = (col < SPLIT) ? b1[col] : b2[col - SPLIT];
    int colw = (col < SPLIT) ? col : col - SPLIT;
#pragma unroll
    for (int j = 0; j < 4; j++) {
      int row = rbase + j;
      if (row < nrows) {
        float v = acc[n][j] + bias;
        if (OUTBF16) {
          ushort* dstp = (ushort*)((col < SPLIT) ? C1v : C2v);
          dstp[(size_t)row * SPLIT + colw] = f2bf(v);
        } else {
          float* dstp = (float*)((col < SPLIT) ? C1v : C2v);
          dstp[(size_t)row * SPLIT + colw] = v;
        }
      }
    }
  }
}

// ---------------- GATv2 aggregation ----------------
// 1 node/wave, 2 ch/lane. Two edge-chains (halves of CSR range) + 2-stage pipeline:
// iter i computes edge i, gathers xl[i+1], streams src/ea[i+2].
__global__ __launch_bounds__(256, 4) void gat_kernel(
    const ushort* __restrict__ xl16, const ushort* __restrict__ xr16,
    const uint* __restrict__ eap32, const int* __restrict__ srcperm,
    const int* __restrict__ off,
    const float* __restrict__ Wel, const float* __restrict__ attl,
    const float* __restrict__ bol, float* __restrict__ out) {
  int lane = threadIdx.x & 63;
  int node = blockIdx.x * 4 + (threadIdx.x >> 6);
  if (node >= N_NODES) return;
  int c0 = lane * 2;  // channels c0, c0+1 (head = c0/32)

  float2 wk[12];
#pragma unroll
  for (int k = 0; k < 12; k++) wk[k] = *(const float2*)&Wel[k * HID + c0];
  float2 at = *(const float2*)&attl[c0];
  uint xrd = *(const uint*)&xr16[(size_t)node * HID + c0];
  float xrl = bflo(xrd), xrh = bfhi(xrd);

  int is = off[node], deg = off[node + 1] - is;
  int lenB = deg >> 1, lenA = deg - lenB;
  int bA = is, bB = is + lenA;

  float mA = -INFINITY, dA = 0.f, aA0 = 0.f, aA1 = 0.f;
  float mB = -INFINITY, dB = 0.f, aB0 = 0.f, aB1 = 0.f;

  if (deg > 0) {
    int iB0 = (lenB > 0) ? bB : bA;
    int iA1 = (1 < lenA) ? bA + 1 : bA;
    int iB1 = (1 < lenB) ? bB + 1 : iB0;
    int sA = srcperm[bA];
    int sB = srcperm[iB0];
    uint4 qAa = *(const uint4*)&eap32[(size_t)bA * 8];
    uint2 qAb = *(const uint2*)&eap32[(size_t)bA * 8 + 4];
    uint4 qBa = *(const uint4*)&eap32[(size_t)iB0 * 8];
    uint2 qBb = *(const uint2*)&eap32[(size_t)iB0 * 8 + 4];
    uint xlA = *(const uint*)&xl16[(size_t)sA * HID + c0];
    uint xlB = *(const uint*)&xl16[(size_t)sB * HID + c0];
    int sAn = srcperm[iA1];
    int sBn = srcperm[iB1];
    uint4 qAan = *(const uint4*)&eap32[(size_t)iA1 * 8];
    uint2 qAbn = *(const uint2*)&eap32[(size_t)iA1 * 8 + 4];
    uint4 qBan = *(const uint4*)&eap32[(size_t)iB1 * 8];
    uint2 qBbn = *(const uint2*)&eap32[(size_t)iB1 * 8 + 4];

    for (int i = 0; i < lenA; i++) {
      // stage: gather next xl (independent of current compute)
      uint xlAn = *(const uint*)&xl16[(size_t)sAn * HID + c0];
      uint xlBn = *(const uint*)&xl16[(size_t)sBn * HID + c0];
      // stage: stream i+2 indices/attrs
      int iA2 = (i + 2 < lenA) ? bA + i + 2 : bA;
      int iB2 = (i + 2 < lenB) ? bB + i + 2 : bA;
      int sA2 = srcperm[iA2];
      int sB2 = srcperm[iB2];
      uint4 qAa2 = *(const uint4*)&eap32[(size_t)iA2 * 8];
      uint2 qAb2 = *(const uint2*)&eap32[(size_t)iA2 * 8 + 4];
      uint4 qBa2 = *(const uint4*)&eap32[(size_t)iB2 * 8];
      uint2 qBb2 = *(const uint2*)&eap32[(size_t)iB2 * 8 + 4];

      // compute edge i for both chains
      float xA0 = bflo(xlA), xA1 = bfhi(xlA);
      float xB0 = bflo(xlB), xB1 = bfhi(xlB);
      uint qa[6] = {qAa.x, qAa.y, qAa.z, qAa.w, qAb.x, qAb.y};
      uint qb[6] = {qBa.x, qBa.y, qBa.z, qBa.w, qBb.x, qBb.y};
      float epA0 = 0.f, epA1 = 0.f, epB0 = 0.f, epB1 = 0.f;
#pragma unroll
      for (int k = 0; k < 6; k++) {
        float ea0 = bflo(qa[k]), ea1 = bfhi(qa[k]);
        epA0 = fmaf(ea0, wk[2 * k].x, epA0); epA0 = fmaf(ea1, wk[2 * k + 1].x, epA0);
        epA1 = fmaf(ea0, wk[2 * k].y, epA1); epA1 = fmaf(ea1, wk[2 * k + 1].y, epA1);
        float eb0 = bflo(qb[k]), eb1 = bfhi(qb[k]);
        epB0 = fmaf(eb0, wk[2 * k].x, epB0); epB0 = fmaf(eb1, wk[2 * k + 1].x, epB0);
        epB1 = fmaf(eb0, wk[2 * k].y, epB1); epB1 = fmaf(eb1, wk[2 * k + 1].y, epB1);
      }
      float tA0 = xA0 + xrl + epA0; tA0 = (tA0 > 0.f) ? tA0 : 0.2f * tA0;
      float tA1 = xA1 + xrh + epA1; tA1 = (tA1 > 0.f) ? tA1 : 0.2f * tA1;
      float tB0 = xB0 + xrl + epB0; tB0 = (tB0 > 0.f) ? tB0 : 0.2f * tB0;
      float tB1 = xB1 + xrh + epB1; tB1 = (tB1 > 0.f) ? tB1 : 0.2f * tB1;
      float vA = fmaf(tA0, at.x, tA1 * at.y);
      float vB = fmaf(tB0, at.x, tB1 * at.y);
#pragma unroll
      for (int o = 1; o <= 8; o <<= 1) {
        vA += __shfl_xor(vA, o);
        vB += __shfl_xor(vB, o);
      }
      // online softmax A (always valid)
      float mnA = fmaxf(mA, vA);
      float scA = __expf(mA - mnA);
      float pA = __expf(vA - mnA);
      dA = fmaf(dA, scA, pA);
      aA0 = fmaf(aA0, scA, pA * xA0);
      aA1 = fmaf(aA1, scA, pA * xA1);
      mA = mnA;
      // online softmax B (wave-uniform validity)
      if (i < lenB) {
        float mnB = fmaxf(mB, vB);
        float scB = __expf(mB - mnB);
        float pB = __expf(vB - mnB);
        dB = fmaf(dB, scB, pB);
        aB0 = fmaf(aB0, scB, pB * xB0);
        aB1 = fmaf(aB1, scB, pB * xB1);
        mB = mnB;
      }
      // rotate pipeline registers
      xlA = xlAn; xlB = xlBn;
      qAa = qAan; qAb = qAbn; qBa = qBan; qBb = qBbn;
      sAn = sA2; sBn = sB2;
      qAan = qAa2; qAbn = qAb2; qBan = qBa2; qBbn = qBb2;
    }
  }
  // merge chains
  float mn = fmaxf(mA, mB);
  float wA = (mA > -INFINITY) ? __expf(mA - mn) : 0.f;
  float wB = (mB > -INFINITY) ? __expf(mB - mn) : 0.f;
  float den = dA * wA + dB * wB;
  float acc0 = aA0 * wA + aB0 * wB;
  float acc1 = aA1 * wA + aB1 * wB;
  float inv = 1.f / (den + 1e-16f);
  float2 bo2 = *(const float2*)&bol[c0];
  float2 o;
  o.x = fmaf(acc0, inv, bo2.x);
  o.y = fmaf(acc1, inv, bo2.y);
  *(float2*)&out[(size_t)node * HID + c0] = o;
}

// ---------------- BatchNorm ----------------
__global__ void bnstats_kernel(const float* __restrict__ t, float* __restrict__ sums) {
  int tid = threadIdx.x;
  int c = tid & 127, half = tid >> 7;
  float s = 0.f, q = 0.f;
  for (int n = blockIdx.x * 2 + half; n < N_NODES; n += 512) {
    float v = t[(size_t)n * HID + c];
    s += v; q = fmaf(v, v, q);
  }
  __shared__ float ls[256], lq[256];
  ls[tid] = s; lq[tid] = q;
  __syncthreads();
  if (tid < 128) {
    atomicAdd(&sums[c], ls[tid] + ls[tid + 128]);
    atomicAdd(&sums[128 + c], lq[tid] + lq[tid + 128]);
  }
}

__global__ void bnapply_kernel(const float* __restrict__ t, const float* __restrict__ res,
                               const float* __restrict__ sums, const float* __restrict__ gamma,
                               const float* __restrict__ beta, float* __restrict__ hout,
                               ushort* __restrict__ h16) {
  int i4 = blockIdx.x * 256 + threadIdx.x;
  if (i4 >= N_NODES * 32) return;
  int c0 = (i4 & 31) << 2;
  const float invN = 1.f / (float)N_NODES;
  float4 tv = *(const float4*)&t[(size_t)i4 * 4];
  float4 sm = *(const float4*)&sums[c0];
  float4 sq = *(const float4*)&sums[128 + c0];
  float4 gm = *(const float4*)&gamma[c0];
  float4 bt = *(const float4*)&beta[c0];
  float4 rv = make_float4(0.f, 0.f, 0.f, 0.f);
  if (res) rv = *(const float4*)&res[(size_t)i4 * 4];
  float4 o;
#define BN1(comp)                                                   \
  {                                                                 \
    float mu = sm.comp * invN;                                      \
    float var = sq.comp * invN - mu * mu;                           \
    float rs = rsqrtf(var + EPS_BN);                                \
    float v = (tv.comp - mu) * rs * gm.comp + bt.comp + rv.comp;    \
    o.comp = fmaxf(v, 0.f);                                         \
  }
  BN1(x) BN1(y) BN1(z) BN1(w)
#undef BN1
  *(float4*)&hout[(size_t)i4 * 4] = o;
  *(uint2*)&h16[(size_t)i4 * 4] = make_uint2(pk_bf16(o.x, o.y), pk_bf16(o.z, o.w));
}

// ---------------- policy head (one edge per 16 lanes) ----------------
__global__ __launch_bounds__(256) void policy_kernel(
    const float* __restrict__ Ps, const float* __restrict__ Pd,
    const int* __restrict__ src, const int* __restrict__ dst,
    const float* __restrict__ edge_attr, const float* __restrict__ Wp1e,
    const float* __restrict__ bp1, const float* __restrict__ Wp2,
    const float* __restrict__ bp2, float* __restrict__ outp) {
  int lane = threadIdx.x & 63;
  int j = lane & 15;  // channels 4j..4j+3
  int e = (blockIdx.x * 256 + threadIdx.x) >> 4;
  if (e >= N_EDGES) return;
  float4 we[12];
#pragma unroll
  for (int k = 0; k < 12; k++) we[k] = *(const float4*)&Wp1e[k * 64 + j * 4];
  float4 b4 = *(const float4*)&bp1[j * 4];
  float4 w2 = *(const float4*)&Wp2[j * 4];
  float bp2c = bp2[0];
  int s = src[e], d = dst[e];
  const float* eap = &edge_attr[(size_t)e * EDIM];
  float4 e0 = *(const float4*)eap;
  float4 e1 = *(const float4*)(eap + 4);
  float4 e2 = *(const float4*)(eap + 8);
  float4 ps = *(const float4*)&Ps[(size_t)s * 64 + j * 4];
  float4 pd = *(const float4*)&Pd[(size_t)d * 64 + j * 4];
  float eav[12] = {e0.x, e0.y, e0.z, e0.w, e1.x, e1.y, e1.z, e1.w, e2.x, e2.y, e2.z, e2.w};
  float hx = ps.x + pd.x + b4.x;
  float hy = ps.y + pd.y + b4.y;
  float hz = ps.z + pd.z + b4.z;
  float hw = ps.w + pd.w + b4.w;
#pragma unroll
  for (int k = 0; k < 12; k++) {
    hx = fmaf(eav[k], we[k].x, hx);
    hy = fmaf(eav[k], we[k].y, hy);
    hz = fmaf(eav[k], we[k].z, hz);
    hw = fmaf(eav[k], we[k].w, hw);
  }
  hx = fmaxf(hx, 0.f); hy = fmaxf(hy, 0.f); hz = fmaxf(hz, 0.f); hw = fmaxf(hw, 0.f);
  float v = fmaf(hx, w2.x, fmaf(hy, w2.y, fmaf(hz, w2.z, hw * w2.w)));
  v += __shfl_xor(v, 1);
  v += __shfl_xor(v, 2);
  v += __shfl_xor(v, 4);
  v += __shfl_xor(v, 8);
  if (j == 0) outp[e] = v + bp2c;
}

// ---------------- pooled mean + value head ----------------
__device__ int lower_bound_dev(const int* a, int n, int key) {
  int lo = 0, hi = n;
  while (lo < hi) {
    int mid = (lo + hi) >> 1;
    if (a[mid] < key) lo = mid + 1; else hi = mid;
  }
  return lo;
}

__global__ void poolvalue_kernel(const float* __restrict__ h, const int* __restrict__ batch,
                                 const float* __restrict__ Wv1, const float* __restrict__ bv1,
                                 const float* __restrict__ Wv2, const float* __restrict__ bv2,
                                 float* __restrict__ outv) {
  __shared__ float pl[128];
  __shared__ float hd[64];
  __shared__ int range[2];
  int g = blockIdx.x, t = threadIdx.x;
  if (t == 0) {
    range[0] = lower_bound_dev(batch, N_NODES, g);
    range[1] = lower_bound_dev(batch, N_NODES, g + 1);
  }
  __syncthreads();
  int lo = range[0], hi = range[1];
  float s = 0.f;
  for (int n = lo; n < hi; n++) s += h[(size_t)n * HID + t];
  float cnt = (float)(hi - lo);
  pl[t] = s / fmaxf(cnt, 1.f);
  __syncthreads();
  if (t < 64) {
    float a = bv1[t];
    for (int c = 0; c < 128; c++) a = fmaf(pl[c], Wv1[c * 64 + t], a);
    hd[t] = fmaxf(a, 0.f);
  }
  __syncthreads();
  if (t < 3) {
    float a = bv2[t];
    for (int j = 0; j < 64; j++) a = fmaf(hd[j], Wv2[j * 3 + t], a);
    outv[g * 3 + t] = a;
  }
}

// ---------------- host ----------------
extern "C" void kernel_launch(void* const* d_in, const int* in_sizes, int n_in,
                              void* d_out, int out_size, void* d_ws, size_t ws_size,
                              hipStream_t stream) {
  (void)in_sizes; (void)n_in; (void)out_size; (void)ws_size;
  const float* x    = (const float*)d_in[0];
  const int*   src  = (const int*)d_in[1];
  const int*   dst  = (const int*)d_in[2];
  const int*   batch= (const int*)d_in[3];
  const float* ea   = (const float*)d_in[4];
  const float* Win  = (const float*)d_in[5];
  const float* b_in = (const float*)d_in[6];
  const float* Wl   = (const float*)d_in[7];
  const float* bl   = (const float*)d_in[8];
  const float* Wr   = (const float*)d_in[9];
  const float* br   = (const float*)d_in[10];
  const float* We   = (const float*)d_in[11];
  const float* att  = (const float*)d_in[12];
  const float* bo   = (const float*)d_in[13];
  const float* gamma= (const float*)d_in[14];
  const float* beta = (const float*)d_in[15];
  const float* Wv1  = (const float*)d_in[16];
  const float* bv1  = (const float*)d_in[17];
  const float* Wv2  = (const float*)d_in[18];
  const float* bv2  = (const float*)d_in[19];
  const float* Wp1  = (const float*)d_in[20];
  const float* bp1  = (const float*)d_in[21];
  const float* Wp2  = (const float*)d_in[22];
  const float* bp2  = (const float*)d_in[23];

  float* outv = (float*)d_out;                      // [G,3]
  float* outp = outv + (size_t)N_GRAPHS * 3;        // [E]

  float* hA    = (float*)d_ws;
  float* hB    = hA  + (size_t)N_NODES * HID;
  float* tmp   = hB  + (size_t)N_NODES * HID;
  ushort* xl16 = (ushort*)(tmp + (size_t)N_NODES * HID);
  ushort* xr16 = xl16 + (size_t)N_NODES * HID;
  ushort* h16  = xr16 + (size_t)N_NODES * HID;
  float* stats = (float*)(h16 + (size_t)N_NODES * HID);
  ushort* wpk  = (ushort*)(stats + NLAYERS * 256);
  ushort* wppk = wpk + (size_t)NLAYERS * 4 * 256 * 32;
  int* off    = (int*)(wppk + 4 * 128 * 32);
  int* cursor = off + (N_NODES + 1);
  int* bsum   = cursor + N_NODES;
  int* srcperm = bsum + 256;
  uint* eap32 = (uint*)(((uintptr_t)(srcperm + N_EDGES) + 15) & ~(uintptr_t)15);

  const int NB = (N_NODES + 255) / 256;
  const int EB = (N_EDGES + 255) / 256;

  zero_kernel<<<NB, 256, 0, stream>>>(off, cursor, stats);
  count_kernel<<<EB, 256, 0, stream>>>(dst, off);
  scan1_kernel<<<NB, 256, 0, stream>>>(off, bsum);
  scan2_kernel<<<1, 256, 0, stream>>>(bsum, NB);
  scan3_kernel<<<NB, 256, 0, stream>>>(off, bsum);
  scatter_kernel<<<EB, 256, 0, stream>>>(src, dst, ea, off, cursor, srcperm, eap32);
  wprep_kernel<<<(NLAYERS * 4 * 256 * 32 + 255) / 256, 256, 0, stream>>>(Wl, Wr, wpk);
  wprep_pol_kernel<<<(4 * 128 * 32 + 255) / 256, 256, 0, stream>>>(Wp1, wppk);
  inproj_kernel<<<N_NODES / 2, 256, 0, stream>>>(x, Win, b_in, hA, h16);

  const int MB = (N_NODES + 63) / 64;           // MFMA gemm blocks
  const int GATB = (N_NODES + 3) / 4;           // 1 node/wave, 4 waves/block
  const int APB = (N_NODES * 32 + 255) / 256;

  for (int b2 = 0; b2 < 4; b2++) {
    int i = 2 * b2, j = i + 1;
    // layer i: h16 -> xl16,xr16 ; gat -> tmp ; BN -> hB (+h16)
    gemm_mfma_kernel<256, 128, true, true><<<MB, 256, 0, stream>>>(
        h16, wpk + (size_t)i * 32768, bl + i * HID, br + i * HID, xl16, xr16, N_NODES);
    gat_kernel<<<GATB, 256, 0, stream>>>(xl16, xr16, eap32, srcperm, off,
                                         We + (size_t)i * EDIM * HID, att + (size_t)i * HID,
                                         bo + (size_t)i * HID, tmp);
    bnstats_kernel<<<256, 256, 0, stream>>>(tmp, stats + i * 256);
    bnapply_kernel<<<APB, 256, 0, stream>>>(tmp, nullptr, stats + i * 256,
                                            gamma + i * HID, beta + i * HID, hB, h16);
    // layer j: residual = hA ; BN -> hA (+h16)
    gemm_mfma_kernel<256, 128, true, true><<<MB, 256, 0, stream>>>(
        h16, wpk + (size_t)j * 32768, bl + j * HID, br + j * HID, xl16, xr16, N_NODES);
    gat_kernel<<<GATB, 256, 0, stream>>>(xl16, xr16, eap32, srcperm, off,
                                         We + (size_t)j * EDIM * HID, att + (size_t)j * HID,
                                         bo + (size_t)j * HID, tmp);
    bnstats_kernel<<<256, 256, 0, stream>>>(tmp, stats + j * 256);
    bnapply_kernel<<<APB, 256, 0, stream>>>(tmp, hA, stats + j * 256,
                                            gamma + j * HID, beta + j * HID, hA, h16);
  }

  // policy head: Ps/Pd via MFMA (f32 out), aliased onto hB/tmp (free now)
  float* Ps = hB;
  float* Pd = tmp;
  gemm_mfma_kernel<128, 64, false, false><<<MB, 256, 0, stream>>>(
      h16, wppk, nullptr, nullptr, Ps, Pd, N_NODES);
  policy_kernel<<<(N_EDGES + 15) / 16, 256, 0, stream>>>(Ps, Pd, src, dst, ea,
                                                         Wp1 + 256 * 64, bp1, Wp2, bp2, outp);
  poolvalue_kernel<<<N_GRAPHS, 128, 0, stream>>>(hA, batch, Wv1, bv1, Wv2, bv2, outv);
}

// Round 8
// 1456.181 us; speedup vs baseline: 1.6916x; 1.0744x over previous
//
#include <hip/hip_runtime.h>
#include <math.h>

#define N_NODES 50000
#define N_EDGES 500000
#define N_GRAPHS 2048
#define HID 128
#define EDIM 12
#define NLAYERS 8
#define EPS_BN 1e-5f

typedef __attribute__((ext_vector_type(8))) short short8;
typedef __attribute__((ext_vector_type(4))) float f32x4;
typedef __attribute__((ext_vector_type(2))) float f32x2;
typedef unsigned int uint;
typedef unsigned short ushort;

__device__ inline ushort f2bf(float x) {
  unsigned u = __float_as_uint(x);
  u = (u + 0x7FFFu + ((u >> 16) & 1u)) >> 16;  // RNE
  return (ushort)u;
}
__device__ inline unsigned pk_bf16(float a, float b) {
  return (unsigned)f2bf(a) | ((unsigned)f2bf(b) << 16);
}
__device__ inline float bflo(uint q) { return __uint_as_float(q << 16); }
__device__ inline float bfhi(uint q) { return __uint_as_float(q & 0xFFFF0000u); }
__device__ inline f32x2 pfma(f32x2 a, f32x2 b, f32x2 c) {
  return __builtin_elementwise_fma(a, b, c);
}
// butterfly add over 16-lane groups, pure-VALU DPP (ctrl must be a literal)
template <int CTRL>
__device__ inline float dpp_add(float v) {
  int s = __builtin_amdgcn_update_dpp(0, __float_as_int(v), CTRL, 0xF, 0xF, true);
  return v + __int_as_float(s);
}
#define RED16(v)              \
  v = dpp_add<0xB1>(v);       \
  v = dpp_add<0x4E>(v);       \
  v = dpp_add<0x141>(v);      \
  v = dpp_add<0x140>(v);

// ---------------- CSR build ----------------
__global__ void zero_kernel(int* deg, int* cursor, float* stats) {
  int i = blockIdx.x * 256 + threadIdx.x;
  if (i < N_NODES) { deg[i] = 0; cursor[i] = 0; }
  if (i < NLAYERS * 256) stats[i] = 0.f;
}

__global__ void count_kernel(const int* __restrict__ dst, int* __restrict__ deg) {
  int e = blockIdx.x * 256 + threadIdx.x;
  if (e < N_EDGES) atomicAdd(&deg[dst[e]], 1);
}

__global__ void scan1_kernel(int* __restrict__ off, int* __restrict__ bsum) {
  __shared__ int s[256];
  int t = threadIdx.x; int n = blockIdx.x * 256 + t;
  int x = (n < N_NODES) ? off[n] : 0;
  s[t] = x; __syncthreads();
  for (int o = 1; o < 256; o <<= 1) {
    int v = (t >= o) ? s[t - o] : 0;
    __syncthreads(); s[t] += v; __syncthreads();
  }
  if (n < N_NODES) off[n] = s[t] - x;
  if (t == 255) bsum[blockIdx.x] = s[255];
}

__global__ void scan2_kernel(int* __restrict__ bsum, int nb) {
  __shared__ int s[256];
  int t = threadIdx.x;
  int x = (t < nb) ? bsum[t] : 0;
  s[t] = x; __syncthreads();
  for (int o = 1; o < 256; o <<= 1) {
    int v = (t >= o) ? s[t - o] : 0;
    __syncthreads(); s[t] += v; __syncthreads();
  }
  if (t < nb) bsum[t] = s[t] - x;
}

__global__ void scan3_kernel(int* __restrict__ off, const int* __restrict__ bsum) {
  int t = threadIdx.x; int n = blockIdx.x * 256 + t;
  if (n < N_NODES) off[n] += bsum[blockIdx.x];
  if (n == 0 && blockIdx.x == 0) off[N_NODES] = N_EDGES;
}

// erec[pos] = {src, pad, ea_bf16 x6} (8 dwords, 32B)
__global__ void scatter_kernel(const int* __restrict__ src, const int* __restrict__ dst,
                               const float* __restrict__ ea,
                               const int* __restrict__ off, int* __restrict__ cursor,
                               uint* __restrict__ erec) {
  int e = blockIdx.x * 256 + threadIdx.x;
  if (e < N_EDGES) {
    int d = dst[e];
    int p = atomicAdd(&cursor[d], 1);
    int pos = off[d] + p;
    const float* eap = &ea[(size_t)e * EDIM];
    float4 e0 = *(const float4*)eap;
    float4 e1 = *(const float4*)(eap + 4);
    float4 e2 = *(const float4*)(eap + 8);
    uint4 q0, q1;
    q0.x = (uint)src[e]; q0.y = 0u;
    q0.z = pk_bf16(e0.x, e0.y); q0.w = pk_bf16(e0.z, e0.w);
    q1.x = pk_bf16(e1.x, e1.y); q1.y = pk_bf16(e1.z, e1.w);
    q1.z = pk_bf16(e2.x, e2.y); q1.w = pk_bf16(e2.z, e2.w);
    uint* o = &erec[(size_t)pos * 8];
    *(uint4*)o = q0;
    *(uint4*)(o + 4) = q1;
  }
}

// ---------------- weight packing for MFMA fragments ----------------
__global__ void wprep_kernel(const float* __restrict__ Wl, const float* __restrict__ Wr,
                             ushort* __restrict__ wpk) {
  int idx = blockIdx.x * 256 + threadIdx.x;
  if (idx >= NLAYERS * 4 * 256 * 32) return;
  int kk = idx & 31;
  int cc = (idx >> 5) & 255;
  int kb = (idx >> 13) & 3;
  int layer = idx >> 15;
  int k = kb * 32 + kk;
  float v = (cc < 128) ? Wl[((size_t)layer * 128 + k) * 128 + cc]
                       : Wr[((size_t)layer * 128 + k) * 128 + (cc - 128)];
  wpk[idx] = f2bf(v);
}

__global__ void wprep_pol_kernel(const float* __restrict__ Wp1, ushort* __restrict__ wppk) {
  int idx = blockIdx.x * 256 + threadIdx.x;
  if (idx >= 4 * 128 * 32) return;
  int kk = idx & 31;
  int cc = (idx >> 5) & 127;
  int kb = idx >> 12;
  int k = kb * 32 + kk;
  float v = (cc < 64) ? Wp1[(size_t)k * 64 + cc] : Wp1[(size_t)(128 + k) * 64 + (cc - 64)];
  wppk[idx] = f2bf(v);
}

// ---------------- input projection (writes f32 hres + bf16 h16) ----------------
__global__ void inproj_kernel(const float* __restrict__ x, const float* __restrict__ Win,
                              const float* __restrict__ b_in, float* __restrict__ h,
                              ushort* __restrict__ h16) {
  __shared__ float xs[44];
  int t = threadIdx.x;
  int n0 = blockIdx.x * 2;
  if (t < 44) xs[t] = x[n0 * 22 + t];
  __syncthreads();
  int c = t & 127, half = t >> 7;
  int n = n0 + half;
  if (n < N_NODES) {
    float acc = b_in[c];
#pragma unroll
    for (int k = 0; k < 22; k++) acc = fmaf(xs[half * 22 + k], Win[k * HID + c], acc);
    float v = fmaxf(acc, 0.f);
    h[(size_t)n * HID + c] = v;
    h16[(size_t)n * HID + c] = f2bf(v);
  }
}

// ---------------- MFMA GEMM (optionally BN+residual+relu fused on input) --------
// !BNFUSE: A = A16 (bf16). BNFUSE: A = relu(bn(T; stats,gamma,beta) [+res]);
//   if WRITEH also writes the normalized f32 h to hout.
// Output [C1|C2] split at SPLIT; bias b1/b2 when BIAS; f32 or bf16 out.
template <int NOUT, int SPLIT, bool BIAS, bool OUTBF16, bool BNFUSE, bool RESID, bool WRITEH>
__global__ __launch_bounds__(256) void gemm_mfma_kernel(
    const ushort* __restrict__ A16, const float* __restrict__ T,
    const float* __restrict__ stats, const float* __restrict__ gamma,
    const float* __restrict__ beta, const float* __restrict__ res,
    float* __restrict__ hout,
    const ushort* __restrict__ Wpk, const float* __restrict__ b1,
    const float* __restrict__ b2, void* __restrict__ C1v, void* __restrict__ C2v,
    int nrows) {
  __shared__ ushort As[64][136];  // +8 pad
  int t = threadIdx.x;
  int brow = blockIdx.x * 64;
  if constexpr (!BNFUSE) {
    // 64 rows x 128 bf16 = 1024 16B-chunks (16/row)
#pragma unroll
    for (int i = 0; i < 4; i++) {
      int f = t + i * 256;
      int r = f >> 4, cg = (f & 15) * 8;
      int g = brow + r;
      uint4 v = make_uint4(0, 0, 0, 0);
      if (g < nrows) v = *(const uint4*)&A16[(size_t)g * HID + cg];
      *(uint4*)&As[r][cg] = v;
    }
  } else {
    int cg = (t & 31) * 4;   // fixed col group per thread
    int r0 = t >> 5;         // 8 rows per thread, stride 8
    const float invN = 1.f / (float)N_NODES;
    float4 sm = *(const float4*)&stats[cg];
    float4 sq = *(const float4*)&stats[128 + cg];
    float4 gm = *(const float4*)&gamma[cg];
    float4 bt = *(const float4*)&beta[cg];
    float s4[4] = {sm.x, sm.y, sm.z, sm.w};
    float q4[4] = {sq.x, sq.y, sq.z, sq.w};
    float g4[4] = {gm.x, gm.y, gm.z, gm.w};
    float bb4[4] = {bt.x, bt.y, bt.z, bt.w};
    float scl[4], shf[4];
#pragma unroll
    for (int k = 0; k < 4; k++) {
      float mu = s4[k] * invN;
      float var = q4[k] * invN - mu * mu;
      float rs = rsqrtf(var + EPS_BN);
      scl[k] = g4[k] * rs;
      shf[k] = bb4[k] - mu * scl[k];
    }
#pragma unroll
    for (int rr = 0; rr < 8; rr++) {
      int r = r0 + rr * 8;
      int g = brow + r;
      float4 tv = make_float4(0.f, 0.f, 0.f, 0.f);
      if (g < nrows) tv = *(const float4*)&T[(size_t)g * HID + cg];
      float o0 = fmaf(tv.x, scl[0], shf[0]);
      float o1 = fmaf(tv.y, scl[1], shf[1]);
      float o2 = fmaf(tv.z, scl[2], shf[2]);
      float o3 = fmaf(tv.w, scl[3], shf[3]);
      if constexpr (RESID) {
        if (g < nrows) {
          float4 rv = *(const float4*)&res[(size_t)g * HID + cg];
          o0 += rv.x; o1 += rv.y; o2 += rv.z; o3 += rv.w;
        }
      }
      o0 = fmaxf(o0, 0.f); o1 = fmaxf(o1, 0.f);
      o2 = fmaxf(o2, 0.f); o3 = fmaxf(o3, 0.f);
      if constexpr (WRITEH) {
        if (g < nrows) {
          float4 ov = make_float4(o0, o1, o2, o3);
          *(float4*)&hout[(size_t)g * HID + cg] = ov;
        }
      }
      *(uint2*)&As[r][cg] = make_uint2(pk_bf16(o0, o1), pk_bf16(o2, o3));
    }
  }
  __syncthreads();
  int lane = t & 63, wave = t >> 6;
  int arow = wave * 16 + (lane & 15);
  int k8 = (lane >> 4) * 8;
  constexpr int NT = NOUT / 16;
  f32x4 acc[NT];
#pragma unroll
  for (int n = 0; n < NT; n++) acc[n] = (f32x4){0.f, 0.f, 0.f, 0.f};
#pragma unroll
  for (int kb = 0; kb < 4; kb++) {
    short8 a = *(const short8*)&As[arow][kb * 32 + k8];
#pragma unroll
    for (int n = 0; n < NT; n++) {
      int col = n * 16 + (lane & 15);
      short8 b = *(const short8*)&Wpk[((size_t)(kb * NOUT + col)) * 32 + k8];
      acc[n] = __builtin_amdgcn_mfma_f32_16x16x32_bf16(a, b, acc[n], 0, 0, 0);
    }
  }
  // C/D: col = lane&15, row = (lane>>4)*4 + j
  int rbase = brow + wave * 16 + (lane >> 4) * 4;
  int ccol = lane & 15;
#pragma unroll
  for (int n = 0; n < NT; n++) {
    int col = n * 16 + ccol;
    float bias = 0.f;
    if (BIAS) bias = (col < SPLIT) ? b1[col] : b2[col - SPLIT];
    int colw = (col < SPLIT) ? col : col - SPLIT;
#pragma unroll
    for (int j = 0; j < 4; j++) {
      int row = rbase + j;
      if (row < nrows) {
        float v = acc[n][j] + bias;
        if (OUTBF16) {
          ushort* dstp = (ushort*)((col < SPLIT) ? C1v : C2v);
          dstp[(size_t)row * SPLIT + colw] = f2bf(v);
        } else {
          float* dstp = (float*)((col < SPLIT) ? C1v : C2v);
          dstp[(size_t)row * SPLIT + colw] = v;
        }
      }
    }
  }
}

// ---------------- GATv2 aggregation ----------------
// 1 node/wave, 2 ch/lane; two edge-chains + 2-deep pipeline.
// DPP butterfly reduce, packed f32 math, single-exp online softmax.
__global__ __launch_bounds__(256, 4) void gat_kernel(
    const ushort* __restrict__ xl16, const ushort* __restrict__ xr16,
    const uint* __restrict__ erec, const int* __restrict__ off,
    const float* __restrict__ Wel, const float* __restrict__ attl,
    const float* __restrict__ bol, float* __restrict__ out) {
  int lane = threadIdx.x & 63;
  int node = blockIdx.x * 4 + (threadIdx.x >> 6);
  if (node >= N_NODES) return;
  int c0 = lane * 2;

  f32x2 wk[12];
#pragma unroll
  for (int k = 0; k < 12; k++) {
    float2 w = *(const float2*)&Wel[k * HID + c0];
    wk[k] = (f32x2){w.x, w.y};
  }
  float2 at = *(const float2*)&attl[c0];
  uint xrd = *(const uint*)&xr16[(size_t)node * HID + c0];
  f32x2 xrv = (f32x2){bflo(xrd), bfhi(xrd)};

  int is = off[node], deg = off[node + 1] - is;
  int lenB = deg >> 1, lenA = deg - lenB;
  int bB = is + lenA;

  float mA = -INFINITY, dA = 0.f;
  float mB = -INFINITY, dB = 0.f;
  f32x2 accA = (f32x2){0.f, 0.f};
  f32x2 accB = (f32x2){0.f, 0.f};

  if (deg > 0) {
    int iB0 = (lenB > 0) ? bB : is;
    uint4 eAa = *(const uint4*)&erec[(size_t)is * 8];
    uint4 eAb = *(const uint4*)&erec[(size_t)is * 8 + 4];
    uint4 eBa = *(const uint4*)&erec[(size_t)iB0 * 8];
    uint4 eBb = *(const uint4*)&erec[(size_t)iB0 * 8 + 4];
    uint xlA = *(const uint*)&xl16[(size_t)(int)eAa.x * HID + c0];
    uint xlB = *(const uint*)&xl16[(size_t)(int)eBa.x * HID + c0];
    int iA1 = (1 < lenA) ? is + 1 : is;
    int iB1 = (1 < lenB) ? bB + 1 : iB0;
    uint4 eAan = *(const uint4*)&erec[(size_t)iA1 * 8];
    uint4 eAbn = *(const uint4*)&erec[(size_t)iA1 * 8 + 4];
    uint4 eBan = *(const uint4*)&erec[(size_t)iB1 * 8];
    uint4 eBbn = *(const uint4*)&erec[(size_t)iB1 * 8 + 4];

    for (int i = 0; i < lenA; i++) {
      // prefetch xl for edge i+1 (uses already-loaded next records)
      uint xlAn = *(const uint*)&xl16[(size_t)(int)eAan.x * HID + c0];
      uint xlBn = *(const uint*)&xl16[(size_t)(int)eBan.x * HID + c0];
      // stream records for edge i+2
      int iA2 = (i + 2 < lenA) ? is + i + 2 : is;
      int iB2 = (i + 2 < lenB) ? bB + i + 2 : is;
      uint4 eAa2 = *(const uint4*)&erec[(size_t)iA2 * 8];
      uint4 eAb2 = *(const uint4*)&erec[(size_t)iA2 * 8 + 4];
      uint4 eBa2 = *(const uint4*)&erec[(size_t)iB2 * 8];
      uint4 eBb2 = *(const uint4*)&erec[(size_t)iB2 * 8 + 4];

      // ---- compute edge i, chain A ----
      {
        f32x2 xa = (f32x2){bflo(xlA), bfhi(xlA)};
        uint qa[6] = {eAa.z, eAa.w, eAb.x, eAb.y, eAb.z, eAb.w};
        f32x2 ep = (f32x2){0.f, 0.f};
#pragma unroll
        for (int k = 0; k < 6; k++) {
          float lo = bflo(qa[k]), hi = bfhi(qa[k]);
          ep = pfma((f32x2){lo, lo}, wk[2 * k], ep);
          ep = pfma((f32x2){hi, hi}, wk[2 * k + 1], ep);
        }
        f32x2 tv = xa + xrv + ep;
        f32x2 tp = __builtin_elementwise_max(tv, (f32x2){0.f, 0.f});
        f32x2 tn = __builtin_elementwise_min(tv, (f32x2){0.f, 0.f});
        tv = pfma(tn, (f32x2){0.2f, 0.2f}, tp);
        float v = fmaf(tv.y, at.y, tv.x * at.x);
        RED16(v)
        float dm = v - mA;
        float e = __expf(fminf(dm, -dm));
        bool big = dm > 0.f;
        float sc = big ? e : 1.f;
        float p = big ? 1.f : e;
        mA = fmaxf(mA, v);
        dA = fmaf(dA, sc, p);
        accA = pfma(accA, (f32x2){sc, sc}, (f32x2){p, p} * xa);
      }
      // ---- compute edge i, chain B (masked; i/lenB wave-uniform) ----
      if (i < lenB) {
        f32x2 xb = (f32x2){bflo(xlB), bfhi(xlB)};
        uint qb[6] = {eBa.z, eBa.w, eBb.x, eBb.y, eBb.z, eBb.w};
        f32x2 ep = (f32x2){0.f, 0.f};
#pragma unroll
        for (int k = 0; k < 6; k++) {
          float lo = bflo(qb[k]), hi = bfhi(qb[k]);
          ep = pfma((f32x2){lo, lo}, wk[2 * k], ep);
          ep = pfma((f32x2){hi, hi}, wk[2 * k + 1], ep);
        }
        f32x2 tv = xb + xrv + ep;
        f32x2 tp = __builtin_elementwise_max(tv, (f32x2){0.f, 0.f});
        f32x2 tn = __builtin_elementwise_min(tv, (f32x2){0.f, 0.f});
        tv = pfma(tn, (f32x2){0.2f, 0.2f}, tp);
        float v = fmaf(tv.y, at.y, tv.x * at.x);
        RED16(v)
        float dm = v - mB;
        float e = __expf(fminf(dm, -dm));
        bool big = dm > 0.f;
        float sc = big ? e : 1.f;
        float p = big ? 1.f : e;
        mB = fmaxf(mB, v);
        dB = fmaf(dB, sc, p);
        accB = pfma(accB, (f32x2){sc, sc}, (f32x2){p, p} * xb);
      }
      // rotate pipeline
      eAa = eAan; eAb = eAbn; eBa = eBan; eBb = eBbn;
      xlA = xlAn; xlB = xlBn;
      eAan = eAa2; eAbn = eAb2; eBan = eBa2; eBbn = eBb2;
    }
  }
  // merge chains
  float mn = fmaxf(mA, mB);
  float wA = (mA > -INFINITY) ? __expf(mA - mn) : 0.f;
  float wB = (mB > -INFINITY) ? __expf(mB - mn) : 0.f;
  float den = dA * wA + dB * wB;
  f32x2 acc = accA * (f32x2){wA, wA} + accB * (f32x2){wB, wB};
  float inv = 1.f / (den + 1e-16f);
  float2 bo2 = *(const float2*)&bol[c0];
  float2 o;
  o.x = fmaf(acc.x, inv, bo2.x);
  o.y = fmaf(acc.y, inv, bo2.y);
  *(float2*)&out[(size_t)node * HID + c0] = o;
}

// ---------------- BatchNorm stats ----------------
__global__ void bnstats_kernel(const float* __restrict__ t, float* __restrict__ sums) {
  int tid = threadIdx.x;
  int c = tid & 127, half = tid >> 7;
  float s = 0.f, q = 0.f;
  for (int n = blockIdx.x * 2 + half; n < N_NODES; n += 512) {
    float v = t[(size_t)n * HID + c];
    s += v; q = fmaf(v, v, q);
  }
  __shared__ float ls[256], lq[256];
  ls[tid] = s; lq[tid] = q;
  __syncthreads();
  if (tid < 128) {
    atomicAdd(&sums[c], ls[tid] + ls[tid + 128]);
    atomicAdd(&sums[128 + c], lq[tid] + lq[tid + 128]);
  }
}

// ---------------- policy head (one edge per 16 lanes) ----------------
__global__ __launch_bounds__(256) void policy_kernel(
    const float* __restrict__ Ps, const float* __restrict__ Pd,
    const int* __restrict__ src, const int* __restrict__ dst,
    const float* __restrict__ edge_attr, const float* __restrict__ Wp1e,
    const float* __restrict__ bp1, const float* __restrict__ Wp2,
    const float* __restrict__ bp2, float* __restrict__ outp) {
  int lane = threadIdx.x & 63;
  int j = lane & 15;
  int e = (blockIdx.x * 256 + threadIdx.x) >> 4;
  if (e >= N_EDGES) return;
  float4 we[12];
#pragma unroll
  for (int k = 0; k < 12; k++) we[k] = *(const float4*)&Wp1e[k * 64 + j * 4];
  float4 b4 = *(const float4*)&bp1[j * 4];
  float4 w2 = *(const float4*)&Wp2[j * 4];
  float bp2c = bp2[0];
  int s = src[e], d = dst[e];
  const float* eap = &edge_attr[(size_t)e * EDIM];
  float4 e0 = *(const float4*)eap;
  float4 e1 = *(const float4*)(eap + 4);
  float4 e2 = *(const float4*)(eap + 8);
  float4 ps = *(const float4*)&Ps[(size_t)s * 64 + j * 4];
  float4 pd = *(const float4*)&Pd[(size_t)d * 64 + j * 4];
  float eav[12] = {e0.x, e0.y, e0.z, e0.w, e1.x, e1.y, e1.z, e1.w, e2.x, e2.y, e2.z, e2.w};
  float hx = ps.x + pd.x + b4.x;
  float hy = ps.y + pd.y + b4.y;
  float hz = ps.z + pd.z + b4.z;
  float hw = ps.w + pd.w + b4.w;
#pragma unroll
  for (int k = 0; k < 12; k++) {
    hx = fmaf(eav[k], we[k].x, hx);
    hy = fmaf(eav[k], we[k].y, hy);
    hz = fmaf(eav[k], we[k].z, hz);
    hw = fmaf(eav[k], we[k].w, hw);
  }
  hx = fmaxf(hx, 0.f); hy = fmaxf(hy, 0.f); hz = fmaxf(hz, 0.f); hw = fmaxf(hw, 0.f);
  float v = fmaf(hx, w2.x, fmaf(hy, w2.y, fmaf(hz, w2.z, hw * w2.w)));
  v += __shfl_xor(v, 1);
  v += __shfl_xor(v, 2);
  v += __shfl_xor(v, 4);
  v += __shfl_xor(v, 8);
  if (j == 0) outp[e] = v + bp2c;
}

// ---------------- pooled mean + value head ----------------
__device__ int lower_bound_dev(const int* a, int n, int key) {
  int lo = 0, hi = n;
  while (lo < hi) {
    int mid = (lo + hi) >> 1;
    if (a[mid] < key) lo = mid + 1; else hi = mid;
  }
  return lo;
}

__global__ void poolvalue_kernel(const float* __restrict__ h, const int* __restrict__ batch,
                                 const float* __restrict__ Wv1, const float* __restrict__ bv1,
                                 const float* __restrict__ Wv2, const float* __restrict__ bv2,
                                 float* __restrict__ outv) {
  __shared__ float pl[128];
  __shared__ float hd[64];
  __shared__ int range[2];
  int g = blockIdx.x, t = threadIdx.x;
  if (t == 0) {
    range[0] = lower_bound_dev(batch, N_NODES, g);
    range[1] = lower_bound_dev(batch, N_NODES, g + 1);
  }
  __syncthreads();
  int lo = range[0], hi = range[1];
  float s = 0.f;
  for (int n = lo; n < hi; n++) s += h[(size_t)n * HID + t];
  float cnt = (float)(hi - lo);
  pl[t] = s / fmaxf(cnt, 1.f);
  __syncthreads();
  if (t < 64) {
    float a = bv1[t];
    for (int c = 0; c < 128; c++) a = fmaf(pl[c], Wv1[c * 64 + t], a);
    hd[t] = fmaxf(a, 0.f);
  }
  __syncthreads();
  if (t < 3) {
    float a = bv2[t];
    for (int j = 0; j < 64; j++) a = fmaf(hd[j], Wv2[j * 3 + t], a);
    outv[g * 3 + t] = a;
  }
}

// ---------------- host ----------------
extern "C" void kernel_launch(void* const* d_in, const int* in_sizes, int n_in,
                              void* d_out, int out_size, void* d_ws, size_t ws_size,
                              hipStream_t stream) {
  (void)in_sizes; (void)n_in; (void)out_size; (void)ws_size;
  const float* x    = (const float*)d_in[0];
  const int*   src  = (const int*)d_in[1];
  const int*   dst  = (const int*)d_in[2];
  const int*   batch= (const int*)d_in[3];
  const float* ea   = (const float*)d_in[4];
  const float* Win  = (const float*)d_in[5];
  const float* b_in = (const float*)d_in[6];
  const float* Wl   = (const float*)d_in[7];
  const float* bl   = (const float*)d_in[8];
  const float* Wr   = (const float*)d_in[9];
  const float* br   = (const float*)d_in[10];
  const float* We   = (const float*)d_in[11];
  const float* att  = (const float*)d_in[12];
  const float* bo   = (const float*)d_in[13];
  const float* gamma= (const float*)d_in[14];
  const float* beta = (const float*)d_in[15];
  const float* Wv1  = (const float*)d_in[16];
  const float* bv1  = (const float*)d_in[17];
  const float* Wv2  = (const float*)d_in[18];
  const float* bv2  = (const float*)d_in[19];
  const float* Wp1  = (const float*)d_in[20];
  const float* bp1  = (const float*)d_in[21];
  const float* Wp2  = (const float*)d_in[22];
  const float* bp2  = (const float*)d_in[23];

  float* outv = (float*)d_out;                      // [G,3]
  float* outp = outv + (size_t)N_GRAPHS * 3;        // [E]

  float* hres  = (float*)d_ws;                           // residual / final h (f32)
  float* tmp   = hres + (size_t)N_NODES * HID;           // gat output (f32)
  ushort* h16  = (ushort*)(tmp + (size_t)N_NODES * HID); // inproj bf16 (layer-0 gemm input)
  ushort* xl16 = h16 + (size_t)N_NODES * HID;
  ushort* xr16 = xl16 + (size_t)N_NODES * HID;
  float* stats = (float*)(xr16 + (size_t)N_NODES * HID);
  ushort* wpk  = (ushort*)(stats + NLAYERS * 256);
  ushort* wppk = wpk + (size_t)NLAYERS * 4 * 256 * 32;
  int* off    = (int*)(wppk + 4 * 128 * 32);
  int* cursor = off + (N_NODES + 1);
  int* bsum   = cursor + N_NODES;
  uint* erec  = (uint*)(((uintptr_t)(bsum + 256) + 15) & ~(uintptr_t)15);

  const int NB = (N_NODES + 255) / 256;
  const int EB = (N_EDGES + 255) / 256;

  zero_kernel<<<NB, 256, 0, stream>>>(off, cursor, stats);
  count_kernel<<<EB, 256, 0, stream>>>(dst, off);
  scan1_kernel<<<NB, 256, 0, stream>>>(off, bsum);
  scan2_kernel<<<1, 256, 0, stream>>>(bsum, NB);
  scan3_kernel<<<NB, 256, 0, stream>>>(off, bsum);
  scatter_kernel<<<EB, 256, 0, stream>>>(src, dst, ea, off, cursor, erec);
  wprep_kernel<<<(NLAYERS * 4 * 256 * 32 + 255) / 256, 256, 0, stream>>>(Wl, Wr, wpk);
  wprep_pol_kernel<<<(4 * 128 * 32 + 255) / 256, 256, 0, stream>>>(Wp1, wppk);
  inproj_kernel<<<N_NODES / 2, 256, 0, stream>>>(x, Win, b_in, hres, h16);

  const int MB = (N_NODES + 63) / 64;
  const int GATB = (N_NODES + 3) / 4;

  for (int l = 0; l < NLAYERS; l++) {
    // GEMM producing xl16/xr16 for layer l (with BN of layer l-1 fused on input)
    if (l == 0) {
      gemm_mfma_kernel<256, 128, true, true, false, false, false><<<MB, 256, 0, stream>>>(
          h16, nullptr, nullptr, nullptr, nullptr, nullptr, nullptr,
          wpk, bl, br, xl16, xr16, N_NODES);
    } else if (l & 1) {
      // consumes BN of even layer l-1 (no residual)
      int p = l - 1;
      gemm_mfma_kernel<256, 128, true, true, true, false, false><<<MB, 256, 0, stream>>>(
          nullptr, tmp, stats + p * 256, gamma + p * HID, beta + p * HID, nullptr, nullptr,
          wpk + (size_t)l * 32768, bl + l * HID, br + l * HID, xl16, xr16, N_NODES);
    } else {
      // consumes BN of odd layer l-1 (+residual, updates hres)
      int p = l - 1;
      gemm_mfma_kernel<256, 128, true, true, true, true, true><<<MB, 256, 0, stream>>>(
          nullptr, tmp, stats + p * 256, gamma + p * HID, beta + p * HID, hres, hres,
          wpk + (size_t)l * 32768, bl + l * HID, br + l * HID, xl16, xr16, N_NODES);
    }
    gat_kernel<<<GATB, 256, 0, stream>>>(xl16, xr16, erec, off,
                                         We + (size_t)l * EDIM * HID, att + (size_t)l * HID,
                                         bo + (size_t)l * HID, tmp);
    bnstats_kernel<<<256, 256, 0, stream>>>(tmp, stats + l * 256);
  }

  // policy projections with BN of layer 7 fused (+residual, writes final h to hres)
  float* Ps = (float*)xl16;   // N*64 f32 fits the N*128 bf16 region exactly
  float* Pd = (float*)xr16;
  gemm_mfma_kernel<128, 64, false, false, true, true, true><<<MB, 256, 0, stream>>>(
      nullptr, tmp, stats + 7 * 256, gamma + 7 * HID, beta + 7 * HID, hres, hres,
      wppk, nullptr, nullptr, Ps, Pd, N_NODES);
  policy_kernel<<<(N_EDGES + 15) / 16, 256, 0, stream>>>(Ps, Pd, src, dst, ea,
                                                         Wp1 + 256 * 64, bp1, Wp2, bp2, outp);
  poolvalue_kernel<<<N_GRAPHS, 128, 0, stream>>>(hres, batch, Wv1, bv1, Wv2, bv2, outv);
}

// Round 9
// 1392.883 us; speedup vs baseline: 1.7684x; 1.0454x over previous
//
#include <hip/hip_runtime.h>
#include <math.h>

#define N_NODES 50000
#define N_EDGES 500000
#define N_GRAPHS 2048
#define HID 128
#define EDIM 12
#define NLAYERS 8
#define EPS_BN 1e-5f

typedef __attribute__((ext_vector_type(8))) short short8;
typedef __attribute__((ext_vector_type(4))) float f32x4;
typedef __attribute__((ext_vector_type(2))) float f32x2;
typedef unsigned int uint;
typedef unsigned short ushort;

__device__ inline ushort f2bf(float x) {
  unsigned u = __float_as_uint(x);
  u = (u + 0x7FFFu + ((u >> 16) & 1u)) >> 16;  // RNE
  return (ushort)u;
}
__device__ inline unsigned pk_bf16(float a, float b) {
  return (unsigned)f2bf(a) | ((unsigned)f2bf(b) << 16);
}
__device__ inline float bflo(uint q) { return __uint_as_float(q << 16); }
__device__ inline float bfhi(uint q) { return __uint_as_float(q & 0xFFFF0000u); }
__device__ inline f32x2 pfma(f32x2 a, f32x2 b, f32x2 c) {
  return __builtin_elementwise_fma(a, b, c);
}
// butterfly add over 16-lane groups, pure-VALU DPP (ctrl must be a literal)
template <int CTRL>
__device__ inline float dpp_add(float v) {
  int s = __builtin_amdgcn_update_dpp(0, __float_as_int(v), CTRL, 0xF, 0xF, true);
  return v + __int_as_float(s);
}
#define RED16(v)              \
  v = dpp_add<0xB1>(v);       \
  v = dpp_add<0x4E>(v);       \
  v = dpp_add<0x141>(v);      \
  v = dpp_add<0x140>(v);

// ---------------- CSR build ----------------
__global__ void zero_kernel(int* deg, int* cursor, float* stats, uint* erec) {
  int i = blockIdx.x * 256 + threadIdx.x;
  if (i < N_NODES) { deg[i] = 0; cursor[i] = 0; }
  if (i < NLAYERS * 256) stats[i] = 0.f;
  if (i < 32) erec[(size_t)N_EDGES * 8 + i] = 0u;  // 4 pad records (src=0)
}

__global__ void count_kernel(const int* __restrict__ dst, int* __restrict__ deg) {
  int e = blockIdx.x * 256 + threadIdx.x;
  if (e < N_EDGES) atomicAdd(&deg[dst[e]], 1);
}

__global__ void scan1_kernel(int* __restrict__ off, int* __restrict__ bsum) {
  __shared__ int s[256];
  int t = threadIdx.x; int n = blockIdx.x * 256 + t;
  int x = (n < N_NODES) ? off[n] : 0;
  s[t] = x; __syncthreads();
  for (int o = 1; o < 256; o <<= 1) {
    int v = (t >= o) ? s[t - o] : 0;
    __syncthreads(); s[t] += v; __syncthreads();
  }
  if (n < N_NODES) off[n] = s[t] - x;
  if (t == 255) bsum[blockIdx.x] = s[255];
}

__global__ void scan2_kernel(int* __restrict__ bsum, int nb) {
  __shared__ int s[256];
  int t = threadIdx.x;
  int x = (t < nb) ? bsum[t] : 0;
  s[t] = x; __syncthreads();
  for (int o = 1; o < 256; o <<= 1) {
    int v = (t >= o) ? s[t - o] : 0;
    __syncthreads(); s[t] += v; __syncthreads();
  }
  if (t < nb) bsum[t] = s[t] - x;
}

__global__ void scan3_kernel(int* __restrict__ off, const int* __restrict__ bsum) {
  int t = threadIdx.x; int n = blockIdx.x * 256 + t;
  if (n < N_NODES) off[n] += bsum[blockIdx.x];
  if (n == 0 && blockIdx.x == 0) off[N_NODES] = N_EDGES;
}

// erec[pos] = {src, pad, ea_bf16 x6} (8 dwords, 32B)
__global__ void scatter_kernel(const int* __restrict__ src, const int* __restrict__ dst,
                               const float* __restrict__ ea,
                               const int* __restrict__ off, int* __restrict__ cursor,
                               uint* __restrict__ erec) {
  int e = blockIdx.x * 256 + threadIdx.x;
  if (e < N_EDGES) {
    int d = dst[e];
    int p = atomicAdd(&cursor[d], 1);
    int pos = off[d] + p;
    const float* eap = &ea[(size_t)e * EDIM];
    float4 e0 = *(const float4*)eap;
    float4 e1 = *(const float4*)(eap + 4);
    float4 e2 = *(const float4*)(eap + 8);
    uint4 q0, q1;
    q0.x = (uint)src[e]; q0.y = 0u;
    q0.z = pk_bf16(e0.x, e0.y); q0.w = pk_bf16(e0.z, e0.w);
    q1.x = pk_bf16(e1.x, e1.y); q1.y = pk_bf16(e1.z, e1.w);
    q1.z = pk_bf16(e2.x, e2.y); q1.w = pk_bf16(e2.z, e2.w);
    uint* o = &erec[(size_t)pos * 8];
    *(uint4*)o = q0;
    *(uint4*)(o + 4) = q1;
  }
}

// ---------------- weight packing for MFMA fragments ----------------
__global__ void wprep_kernel(const float* __restrict__ Wl, const float* __restrict__ Wr,
                             ushort* __restrict__ wpk) {
  int idx = blockIdx.x * 256 + threadIdx.x;
  if (idx >= NLAYERS * 4 * 256 * 32) return;
  int kk = idx & 31;
  int cc = (idx >> 5) & 255;
  int kb = (idx >> 13) & 3;
  int layer = idx >> 15;
  int k = kb * 32 + kk;
  float v = (cc < 128) ? Wl[((size_t)layer * 128 + k) * 128 + cc]
                       : Wr[((size_t)layer * 128 + k) * 128 + (cc - 128)];
  wpk[idx] = f2bf(v);
}

__global__ void wprep_pol_kernel(const float* __restrict__ Wp1, ushort* __restrict__ wppk) {
  int idx = blockIdx.x * 256 + threadIdx.x;
  if (idx >= 4 * 128 * 32) return;
  int kk = idx & 31;
  int cc = (idx >> 5) & 127;
  int kb = idx >> 12;
  int k = kb * 32 + kk;
  float v = (cc < 64) ? Wp1[(size_t)k * 64 + cc] : Wp1[(size_t)(128 + k) * 64 + (cc - 64)];
  wppk[idx] = f2bf(v);
}

// ---------------- input projection (writes f32 hres + bf16 h16) ----------------
__global__ void inproj_kernel(const float* __restrict__ x, const float* __restrict__ Win,
                              const float* __restrict__ b_in, float* __restrict__ h,
                              ushort* __restrict__ h16) {
  __shared__ float xs[44];
  int t = threadIdx.x;
  int n0 = blockIdx.x * 2;
  if (t < 44) xs[t] = x[n0 * 22 + t];
  __syncthreads();
  int c = t & 127, half = t >> 7;
  int n = n0 + half;
  if (n < N_NODES) {
    float acc = b_in[c];
#pragma unroll
    for (int k = 0; k < 22; k++) acc = fmaf(xs[half * 22 + k], Win[k * HID + c], acc);
    float v = fmaxf(acc, 0.f);
    h[(size_t)n * HID + c] = v;
    h16[(size_t)n * HID + c] = f2bf(v);
  }
}

// ---------------- MFMA GEMM (optionally BN+residual+relu fused on input) --------
template <int NOUT, int SPLIT, bool BIAS, bool OUTBF16, bool BNFUSE, bool RESID, bool WRITEH>
__global__ __launch_bounds__(256) void gemm_mfma_kernel(
    const ushort* __restrict__ A16, const float* __restrict__ T,
    const float* __restrict__ stats, const float* __restrict__ gamma,
    const float* __restrict__ beta, const float* __restrict__ res,
    float* __restrict__ hout,
    const ushort* __restrict__ Wpk, const float* __restrict__ b1,
    const float* __restrict__ b2, void* __restrict__ C1v, void* __restrict__ C2v,
    int nrows) {
  __shared__ ushort As[64][136];  // +8 pad
  int t = threadIdx.x;
  int brow = blockIdx.x * 64;
  if constexpr (!BNFUSE) {
#pragma unroll
    for (int i = 0; i < 4; i++) {
      int f = t + i * 256;
      int r = f >> 4, cg = (f & 15) * 8;
      int g = brow + r;
      uint4 v = make_uint4(0, 0, 0, 0);
      if (g < nrows) v = *(const uint4*)&A16[(size_t)g * HID + cg];
      *(uint4*)&As[r][cg] = v;
    }
  } else {
    int cg = (t & 31) * 4;
    int r0 = t >> 5;
    const float invN = 1.f / (float)N_NODES;
    float4 sm = *(const float4*)&stats[cg];
    float4 sq = *(const float4*)&stats[128 + cg];
    float4 gm = *(const float4*)&gamma[cg];
    float4 bt = *(const float4*)&beta[cg];
    float s4[4] = {sm.x, sm.y, sm.z, sm.w};
    float q4[4] = {sq.x, sq.y, sq.z, sq.w};
    float g4[4] = {gm.x, gm.y, gm.z, gm.w};
    float bb4[4] = {bt.x, bt.y, bt.z, bt.w};
    float scl[4], shf[4];
#pragma unroll
    for (int k = 0; k < 4; k++) {
      float mu = s4[k] * invN;
      float var = q4[k] * invN - mu * mu;
      float rs = rsqrtf(var + EPS_BN);
      scl[k] = g4[k] * rs;
      shf[k] = bb4[k] - mu * scl[k];
    }
#pragma unroll
    for (int rr = 0; rr < 8; rr++) {
      int r = r0 + rr * 8;
      int g = brow + r;
      float4 tv = make_float4(0.f, 0.f, 0.f, 0.f);
      if (g < nrows) tv = *(const float4*)&T[(size_t)g * HID + cg];
      float o0 = fmaf(tv.x, scl[0], shf[0]);
      float o1 = fmaf(tv.y, scl[1], shf[1]);
      float o2 = fmaf(tv.z, scl[2], shf[2]);
      float o3 = fmaf(tv.w, scl[3], shf[3]);
      if constexpr (RESID) {
        if (g < nrows) {
          float4 rv = *(const float4*)&res[(size_t)g * HID + cg];
          o0 += rv.x; o1 += rv.y; o2 += rv.z; o3 += rv.w;
        }
      }
      o0 = fmaxf(o0, 0.f); o1 = fmaxf(o1, 0.f);
      o2 = fmaxf(o2, 0.f); o3 = fmaxf(o3, 0.f);
      if constexpr (WRITEH) {
        if (g < nrows) {
          float4 ov = make_float4(o0, o1, o2, o3);
          *(float4*)&hout[(size_t)g * HID + cg] = ov;
        }
      }
      *(uint2*)&As[r][cg] = make_uint2(pk_bf16(o0, o1), pk_bf16(o2, o3));
    }
  }
  __syncthreads();
  int lane = t & 63, wave = t >> 6;
  int arow = wave * 16 + (lane & 15);
  int k8 = (lane >> 4) * 8;
  constexpr int NT = NOUT / 16;
  f32x4 acc[NT];
#pragma unroll
  for (int n = 0; n < NT; n++) acc[n] = (f32x4){0.f, 0.f, 0.f, 0.f};
#pragma unroll
  for (int kb = 0; kb < 4; kb++) {
    short8 a = *(const short8*)&As[arow][kb * 32 + k8];
#pragma unroll
    for (int n = 0; n < NT; n++) {
      int col = n * 16 + (lane & 15);
      short8 b = *(const short8*)&Wpk[((size_t)(kb * NOUT + col)) * 32 + k8];
      acc[n] = __builtin_amdgcn_mfma_f32_16x16x32_bf16(a, b, acc[n], 0, 0, 0);
    }
  }
  // C/D: col = lane&15, row = (lane>>4)*4 + j
  int rbase = brow + wave * 16 + (lane >> 4) * 4;
  int ccol = lane & 15;
#pragma unroll
  for (int n = 0; n < NT; n++) {
    int col = n * 16 + ccol;
    float bias = 0.f;
    if (BIAS) bias = (col < SPLIT) ? b1[col] : b2[col - SPLIT];
    int colw = (col < SPLIT) ? col : col - SPLIT;
#pragma unroll
    for (int j = 0; j < 4; j++) {
      int row = rbase + j;
      if (row < nrows) {
        float v = acc[n][j] + bias;
        if (OUTBF16) {
          ushort* dstp = (ushort*)((col < SPLIT) ? C1v : C2v);
          dstp[(size_t)row * SPLIT + colw] = f2bf(v);
        } else {
          float* dstp = (float*)((col < SPLIT) ? C1v : C2v);
          dstp[(size_t)row * SPLIT + colw] = v;
        }
      }
    }
  }
}

// ---------------- GATv2 aggregation ----------------
// 1 node/wave, 2 ch/lane; two edge-chains; unroll-by-2 ping-pong pipeline with
// unconditional pointer-advance prefetch (erec has 4 zeroed pad records).
// Per-edge: packed ep FMAs, max(x,0.2x) leaky, DPP reduce, single-exp softmax.
#define GAT_EDGE(ra, rb, xlw, m, d, acc)                                    \
  {                                                                         \
    f32x2 xa = (f32x2){bflo(xlw), bfhi(xlw)};                               \
    f32x2 ep = xa + xrv;                                                    \
    uint q;                                                                 \
    q = ra.z;                                                               \
    ep = pfma((f32x2){bflo(q), bflo(q)}, wk[0], ep);                        \
    ep = pfma((f32x2){bfhi(q), bfhi(q)}, wk[1], ep);                        \
    q = ra.w;                                                               \
    ep = pfma((f32x2){bflo(q), bflo(q)}, wk[2], ep);                        \
    ep = pfma((f32x2){bfhi(q), bfhi(q)}, wk[3], ep);                        \
    q = rb.x;                                                               \
    ep = pfma((f32x2){bflo(q), bflo(q)}, wk[4], ep);                        \
    ep = pfma((f32x2){bfhi(q), bfhi(q)}, wk[5], ep);                        \
    q = rb.y;                                                               \
    ep = pfma((f32x2){bflo(q), bflo(q)}, wk[6], ep);                        \
    ep = pfma((f32x2){bfhi(q), bfhi(q)}, wk[7], ep);                        \
    q = rb.z;                                                               \
    ep = pfma((f32x2){bflo(q), bflo(q)}, wk[8], ep);                        \
    ep = pfma((f32x2){bfhi(q), bfhi(q)}, wk[9], ep);                        \
    q = rb.w;                                                               \
    ep = pfma((f32x2){bflo(q), bflo(q)}, wk[10], ep);                       \
    ep = pfma((f32x2){bfhi(q), bfhi(q)}, wk[11], ep);                       \
    f32x2 sv = __builtin_elementwise_max(ep, ep * (f32x2){0.2f, 0.2f});     \
    float v = fmaf(sv.y, at.y, sv.x * at.x);                                \
    RED16(v)                                                                \
    float dm = v - m;                                                       \
    float e = __expf(-fabsf(dm));                                           \
    bool big = dm > 0.f;                                                    \
    float sc = big ? e : 1.f;                                               \
    float p = big ? 1.f : e;                                                \
    m = fmaxf(m, v);                                                        \
    d = fmaf(d, sc, p);                                                     \
    acc = pfma(acc, (f32x2){sc, sc}, (f32x2){p, p} * xa);                   \
  }

__global__ __launch_bounds__(256, 4) void gat_kernel(
    const ushort* __restrict__ xl16, const ushort* __restrict__ xr16,
    const uint* __restrict__ erec, const int* __restrict__ off,
    const float* __restrict__ Wel, const float* __restrict__ attl,
    const float* __restrict__ bol, float* __restrict__ out) {
  int lane = threadIdx.x & 63;
  int node = blockIdx.x * 4 + (threadIdx.x >> 6);
  if (node >= N_NODES) return;
  int c0 = lane * 2;

  f32x2 wk[12];
#pragma unroll
  for (int k = 0; k < 12; k++) {
    float2 w = *(const float2*)&Wel[k * HID + c0];
    wk[k] = (f32x2){w.x, w.y};
  }
  float2 at = *(const float2*)&attl[c0];
  uint xrd = *(const uint*)&xr16[(size_t)node * HID + c0];
  f32x2 xrv = (f32x2){bflo(xrd), bfhi(xrd)};

  int is = off[node], deg = off[node + 1] - is;
  int lenB = deg >> 1, lenA = deg - lenB;
  const uint* pA = erec + (size_t)is * 8;
  const uint* pB = pA + (size_t)lenA * 8;

  float mA = -INFINITY, dA = 0.f;
  float mB = -INFINITY, dB = 0.f;
  f32x2 accA = (f32x2){0.f, 0.f};
  f32x2 accB = (f32x2){0.f, 0.f};

  if (deg > 0) {
    // prologue: records 0,1 of both chains (pad makes all reads safe)
    uint4 A0a = *(const uint4*)pA,        A0b = *(const uint4*)(pA + 4);
    uint4 B0a = *(const uint4*)pB,        B0b = *(const uint4*)(pB + 4);
    uint4 A1a = *(const uint4*)(pA + 8),  A1b = *(const uint4*)(pA + 12);
    uint4 B1a = *(const uint4*)(pB + 8),  B1b = *(const uint4*)(pB + 12);
    uint xA0 = *(const uint*)&xl16[(size_t)(int)A0a.x * HID + c0];
    uint xB0 = *(const uint*)&xl16[(size_t)(int)B0a.x * HID + c0];
    int i = 0;
    for (; i + 2 <= lenA; i += 2) {
      // gathers for edge pair's second slot
      uint xA1 = *(const uint*)&xl16[(size_t)(int)A1a.x * HID + c0];
      uint xB1 = *(const uint*)&xl16[(size_t)(int)B1a.x * HID + c0];
      // stream records i+2 (unconditional)
      const uint* qA2 = pA + (size_t)(i + 2) * 8;
      const uint* qB2 = pB + (size_t)(i + 2) * 8;
      uint4 nA0a = *(const uint4*)qA2, nA0b = *(const uint4*)(qA2 + 4);
      uint4 nB0a = *(const uint4*)qB2, nB0b = *(const uint4*)(qB2 + 4);
      GAT_EDGE(A0a, A0b, xA0, mA, dA, accA)
      if (i < lenB) GAT_EDGE(B0a, B0b, xB0, mB, dB, accB)
      // stream records i+3 (unconditional)
      const uint* qA3 = pA + (size_t)(i + 3) * 8;
      const uint* qB3 = pB + (size_t)(i + 3) * 8;
      uint4 nA1a = *(const uint4*)qA3, nA1b = *(const uint4*)(qA3 + 4);
      uint4 nB1a = *(const uint4*)qB3, nB1b = *(const uint4*)(qB3 + 4);
      uint nxA0 = *(const uint*)&xl16[(size_t)(int)nA0a.x * HID + c0];
      uint nxB0 = *(const uint*)&xl16[(size_t)(int)nB0a.x * HID + c0];
      GAT_EDGE(A1a, A1b, xA1, mA, dA, accA)
      if (i + 1 < lenB) GAT_EDGE(B1a, B1b, xB1, mB, dB, accB)
      A0a = nA0a; A0b = nA0b; B0a = nB0a; B0b = nB0b;
      A1a = nA1a; A1b = nA1b; B1a = nB1a; B1b = nB1b;
      xA0 = nxA0; xB0 = nxB0;
    }
    if (i < lenA) {  // one leftover edge (lenA odd)
      GAT_EDGE(A0a, A0b, xA0, mA, dA, accA)
      if (i < lenB) GAT_EDGE(B0a, B0b, xB0, mB, dB, accB)
    }
  }
  // merge chains
  float mn = fmaxf(mA, mB);
  float wA = (mA > -INFINITY) ? __expf(mA - mn) : 0.f;
  float wB = (mB > -INFINITY) ? __expf(mB - mn) : 0.f;
  float den = dA * wA + dB * wB;
  f32x2 acc = accA * (f32x2){wA, wA} + accB * (f32x2){wB, wB};
  float inv = 1.f / (den + 1e-16f);
  float2 bo2 = *(const float2*)&bol[c0];
  float2 o;
  o.x = fmaf(acc.x, inv, bo2.x);
  o.y = fmaf(acc.y, inv, bo2.y);
  *(float2*)&out[(size_t)node * HID + c0] = o;
}

// ---------------- BatchNorm stats ----------------
__global__ void bnstats_kernel(const float* __restrict__ t, float* __restrict__ sums) {
  int tid = threadIdx.x;
  int c = tid & 127, half = tid >> 7;
  float s = 0.f, q = 0.f;
  for (int n = blockIdx.x * 2 + half; n < N_NODES; n += 512) {
    float v = t[(size_t)n * HID + c];
    s += v; q = fmaf(v, v, q);
  }
  __shared__ float ls[256], lq[256];
  ls[tid] = s; lq[tid] = q;
  __syncthreads();
  if (tid < 128) {
    atomicAdd(&sums[c], ls[tid] + ls[tid + 128]);
    atomicAdd(&sums[128 + c], lq[tid] + lq[tid + 128]);
  }
}

// ---------------- policy head (one edge per 16 lanes, bf16 Ps/Pd) ----------------
__global__ __launch_bounds__(256) void policy_kernel(
    const ushort* __restrict__ Ps, const ushort* __restrict__ Pd,
    const int* __restrict__ src, const int* __restrict__ dst,
    const float* __restrict__ edge_attr, const float* __restrict__ Wp1e,
    const float* __restrict__ bp1, const float* __restrict__ Wp2,
    const float* __restrict__ bp2, float* __restrict__ outp) {
  int lane = threadIdx.x & 63;
  int j = lane & 15;
  int e = (blockIdx.x * 256 + threadIdx.x) >> 4;
  if (e >= N_EDGES) return;
  float4 we[12];
#pragma unroll
  for (int k = 0; k < 12; k++) we[k] = *(const float4*)&Wp1e[k * 64 + j * 4];
  float4 b4 = *(const float4*)&bp1[j * 4];
  float4 w2 = *(const float4*)&Wp2[j * 4];
  float bp2c = bp2[0];
  int s = src[e], d = dst[e];
  const float* eap = &edge_attr[(size_t)e * EDIM];
  float4 e0 = *(const float4*)eap;
  float4 e1 = *(const float4*)(eap + 4);
  float4 e2 = *(const float4*)(eap + 8);
  uint2 psu = *(const uint2*)&Ps[(size_t)s * 64 + j * 4];
  uint2 pdu = *(const uint2*)&Pd[(size_t)d * 64 + j * 4];
  float eav[12] = {e0.x, e0.y, e0.z, e0.w, e1.x, e1.y, e1.z, e1.w, e2.x, e2.y, e2.z, e2.w};
  float hx = bflo(psu.x) + bflo(pdu.x) + b4.x;
  float hy = bfhi(psu.x) + bfhi(pdu.x) + b4.y;
  float hz = bflo(psu.y) + bflo(pdu.y) + b4.z;
  float hw = bfhi(psu.y) + bfhi(pdu.y) + b4.w;
#pragma unroll
  for (int k = 0; k < 12; k++) {
    hx = fmaf(eav[k], we[k].x, hx);
    hy = fmaf(eav[k], we[k].y, hy);
    hz = fmaf(eav[k], we[k].z, hz);
    hw = fmaf(eav[k], we[k].w, hw);
  }
  hx = fmaxf(hx, 0.f); hy = fmaxf(hy, 0.f); hz = fmaxf(hz, 0.f); hw = fmaxf(hw, 0.f);
  float v = fmaf(hx, w2.x, fmaf(hy, w2.y, fmaf(hz, w2.z, hw * w2.w)));
  v += __shfl_xor(v, 1);
  v += __shfl_xor(v, 2);
  v += __shfl_xor(v, 4);
  v += __shfl_xor(v, 8);
  if (j == 0) outp[e] = v + bp2c;
}

// ---------------- pooled mean + value head ----------------
__device__ int lower_bound_dev(const int* a, int n, int key) {
  int lo = 0, hi = n;
  while (lo < hi) {
    int mid = (lo + hi) >> 1;
    if (a[mid] < key) lo = mid + 1; else hi = mid;
  }
  return lo;
}

__global__ void poolvalue_kernel(const float* __restrict__ h, const int* __restrict__ batch,
                                 const float* __restrict__ Wv1, const float* __restrict__ bv1,
                                 const float* __restrict__ Wv2, const float* __restrict__ bv2,
                                 float* __restrict__ outv) {
  __shared__ float pl[128];
  __shared__ float hd[64];
  __shared__ int range[2];
  int g = blockIdx.x, t = threadIdx.x;
  if (t == 0) {
    range[0] = lower_bound_dev(batch, N_NODES, g);
    range[1] = lower_bound_dev(batch, N_NODES, g + 1);
  }
  __syncthreads();
  int lo = range[0], hi = range[1];
  float s = 0.f;
  for (int n = lo; n < hi; n++) s += h[(size_t)n * HID + t];
  float cnt = (float)(hi - lo);
  pl[t] = s / fmaxf(cnt, 1.f);
  __syncthreads();
  if (t < 64) {
    float a = bv1[t];
    for (int c = 0; c < 128; c++) a = fmaf(pl[c], Wv1[c * 64 + t], a);
    hd[t] = fmaxf(a, 0.f);
  }
  __syncthreads();
  if (t < 3) {
    float a = bv2[t];
    for (int j = 0; j < 64; j++) a = fmaf(hd[j], Wv2[j * 3 + t], a);
    outv[g * 3 + t] = a;
  }
}

// ---------------- host ----------------
extern "C" void kernel_launch(void* const* d_in, const int* in_sizes, int n_in,
                              void* d_out, int out_size, void* d_ws, size_t ws_size,
                              hipStream_t stream) {
  (void)in_sizes; (void)n_in; (void)out_size; (void)ws_size;
  const float* x    = (const float*)d_in[0];
  const int*   src  = (const int*)d_in[1];
  const int*   dst  = (const int*)d_in[2];
  const int*   batch= (const int*)d_in[3];
  const float* ea   = (const float*)d_in[4];
  const float* Win  = (const float*)d_in[5];
  const float* b_in = (const float*)d_in[6];
  const float* Wl   = (const float*)d_in[7];
  const float* bl   = (const float*)d_in[8];
  const float* Wr   = (const float*)d_in[9];
  const float* br   = (const float*)d_in[10];
  const float* We   = (const float*)d_in[11];
  const float* att  = (const float*)d_in[12];
  const float* bo   = (const float*)d_in[13];
  const float* gamma= (const float*)d_in[14];
  const float* beta = (const float*)d_in[15];
  const float* Wv1  = (const float*)d_in[16];
  const float* bv1  = (const float*)d_in[17];
  const float* Wv2  = (const float*)d_in[18];
  const float* bv2  = (const float*)d_in[19];
  const float* Wp1  = (const float*)d_in[20];
  const float* bp1  = (const float*)d_in[21];
  const float* Wp2  = (const float*)d_in[22];
  const float* bp2  = (const float*)d_in[23];

  float* outv = (float*)d_out;                      // [G,3]
  float* outp = outv + (size_t)N_GRAPHS * 3;        // [E]

  float* hres  = (float*)d_ws;                           // residual / final h (f32)
  float* tmp   = hres + (size_t)N_NODES * HID;           // gat output (f32)
  ushort* h16  = (ushort*)(tmp + (size_t)N_NODES * HID); // inproj bf16
  ushort* xl16 = h16 + (size_t)N_NODES * HID;
  ushort* xr16 = xl16 + (size_t)N_NODES * HID;
  float* stats = (float*)(xr16 + (size_t)N_NODES * HID);
  ushort* wpk  = (ushort*)(stats + NLAYERS * 256);
  ushort* wppk = wpk + (size_t)NLAYERS * 4 * 256 * 32;
  int* off    = (int*)(wppk + 4 * 128 * 32);
  int* cursor = off + (N_NODES + 1);
  int* bsum   = cursor + N_NODES;
  uint* erec  = (uint*)(((uintptr_t)(bsum + 256) + 15) & ~(uintptr_t)15);

  const int NB = (N_NODES + 255) / 256;
  const int EB = (N_EDGES + 255) / 256;

  zero_kernel<<<NB, 256, 0, stream>>>(off, cursor, stats, erec);
  count_kernel<<<EB, 256, 0, stream>>>(dst, off);
  scan1_kernel<<<NB, 256, 0, stream>>>(off, bsum);
  scan2_kernel<<<1, 256, 0, stream>>>(bsum, NB);
  scan3_kernel<<<NB, 256, 0, stream>>>(off, bsum);
  scatter_kernel<<<EB, 256, 0, stream>>>(src, dst, ea, off, cursor, erec);
  wprep_kernel<<<(NLAYERS * 4 * 256 * 32 + 255) / 256, 256, 0, stream>>>(Wl, Wr, wpk);
  wprep_pol_kernel<<<(4 * 128 * 32 + 255) / 256, 256, 0, stream>>>(Wp1, wppk);
  inproj_kernel<<<N_NODES / 2, 256, 0, stream>>>(x, Win, b_in, hres, h16);

  const int MB = (N_NODES + 63) / 64;
  const int GATB = (N_NODES + 3) / 4;

  for (int l = 0; l < NLAYERS; l++) {
    if (l == 0) {
      gemm_mfma_kernel<256, 128, true, true, false, false, false><<<MB, 256, 0, stream>>>(
          h16, nullptr, nullptr, nullptr, nullptr, nullptr, nullptr,
          wpk, bl, br, xl16, xr16, N_NODES);
    } else if (l & 1) {
      int p = l - 1;
      gemm_mfma_kernel<256, 128, true, true, true, false, false><<<MB, 256, 0, stream>>>(
          nullptr, tmp, stats + p * 256, gamma + p * HID, beta + p * HID, nullptr, nullptr,
          wpk + (size_t)l * 32768, bl + l * HID, br + l * HID, xl16, xr16, N_NODES);
    } else {
      int p = l - 1;
      gemm_mfma_kernel<256, 128, true, true, true, true, true><<<MB, 256, 0, stream>>>(
          nullptr, tmp, stats + p * 256, gamma + p * HID, beta + p * HID, hres, hres,
          wpk + (size_t)l * 32768, bl + l * HID, br + l * HID, xl16, xr16, N_NODES);
    }
    gat_kernel<<<GATB, 256, 0, stream>>>(xl16, xr16, erec, off,
                                         We + (size_t)l * EDIM * HID, att + (size_t)l * HID,
                                         bo + (size_t)l * HID, tmp);
    bnstats_kernel<<<256, 256, 0, stream>>>(tmp, stats + l * 256);
  }

  // policy projections: BN of layer 7 fused (+residual, final h -> hres), bf16 out
  ushort* Ps = xl16;
  ushort* Pd = xr16;
  gemm_mfma_kernel<128, 64, false, true, true, true, true><<<MB, 256, 0, stream>>>(
      nullptr, tmp, stats + 7 * 256, gamma + 7 * HID, beta + 7 * HID, hres, hres,
      wppk, nullptr, nullptr, Ps, Pd, N_NODES);
  policy_kernel<<<(N_EDGES + 15) / 16, 256, 0, stream>>>(Ps, Pd, src, dst, ea,
                                                         Wp1 + 256 * 64, bp1, Wp2, bp2, outp);
  poolvalue_kernel<<<N_GRAPHS, 128, 0, stream>>>(hres, batch, Wv1, bv1, Wv2, bv2, outv);
}

// Round 10
// 1295.698 us; speedup vs baseline: 1.9011x; 1.0750x over previous
//
#include <hip/hip_runtime.h>
#include <math.h>

#define N_NODES 50000
#define N_EDGES 500000
#define N_GRAPHS 2048
#define HID 128
#define EDIM 12
#define NLAYERS 8
#define EPS_BN 1e-5f
#define LOG2E 1.44269504088896340736f

typedef __attribute__((ext_vector_type(8))) short short8;
typedef __attribute__((ext_vector_type(4))) float f32x4;
typedef __attribute__((ext_vector_type(2))) float f32x2;
typedef unsigned int uint;
typedef unsigned short ushort;

__device__ inline ushort f2bf(float x) {
  unsigned u = __float_as_uint(x);
  u = (u + 0x7FFFu + ((u >> 16) & 1u)) >> 16;  // RNE
  return (ushort)u;
}
__device__ inline unsigned pk_bf16(float a, float b) {
  return (unsigned)f2bf(a) | ((unsigned)f2bf(b) << 16);
}
__device__ inline float bflo(uint q) { return __uint_as_float(q << 16); }
__device__ inline float bfhi(uint q) { return __uint_as_float(q & 0xFFFF0000u); }
__device__ inline f32x2 pfma(f32x2 a, f32x2 b, f32x2 c) {
  return __builtin_elementwise_fma(a, b, c);
}
// butterfly add over 16-lane groups, pure-VALU DPP (ctrl must be a literal)
template <int CTRL>
__device__ inline float dpp_add(float v) {
  int s = __builtin_amdgcn_update_dpp(0, __float_as_int(v), CTRL, 0xF, 0xF, true);
  return v + __int_as_float(s);
}
#define RED16(v)              \
  v = dpp_add<0xB1>(v);       \
  v = dpp_add<0x4E>(v);       \
  v = dpp_add<0x141>(v);      \
  v = dpp_add<0x140>(v);

// ---------------- CSR build ----------------
__global__ void zero_kernel(int* deg, int* cursor, float* stats, uint* erec) {
  int i = blockIdx.x * 256 + threadIdx.x;
  if (i < N_NODES) { deg[i] = 0; cursor[i] = 0; }
  if (i < NLAYERS * 256) stats[i] = 0.f;
  if (i < 32) erec[(size_t)N_EDGES * 8 + i] = 0u;  // 4 pad records (src=0)
}

__global__ void count_kernel(const int* __restrict__ dst, int* __restrict__ deg) {
  int e = blockIdx.x * 256 + threadIdx.x;
  if (e < N_EDGES) atomicAdd(&deg[dst[e]], 1);
}

__global__ void scan1_kernel(int* __restrict__ off, int* __restrict__ bsum) {
  __shared__ int s[256];
  int t = threadIdx.x; int n = blockIdx.x * 256 + t;
  int x = (n < N_NODES) ? off[n] : 0;
  s[t] = x; __syncthreads();
  for (int o = 1; o < 256; o <<= 1) {
    int v = (t >= o) ? s[t - o] : 0;
    __syncthreads(); s[t] += v; __syncthreads();
  }
  if (n < N_NODES) off[n] = s[t] - x;
  if (t == 255) bsum[blockIdx.x] = s[255];
}

__global__ void scan2_kernel(int* __restrict__ bsum, int nb) {
  __shared__ int s[256];
  int t = threadIdx.x;
  int x = (t < nb) ? bsum[t] : 0;
  s[t] = x; __syncthreads();
  for (int o = 1; o < 256; o <<= 1) {
    int v = (t >= o) ? s[t - o] : 0;
    __syncthreads(); s[t] += v; __syncthreads();
  }
  if (t < nb) bsum[t] = s[t] - x;
}

__global__ void scan3_kernel(int* __restrict__ off, const int* __restrict__ bsum) {
  int t = threadIdx.x; int n = blockIdx.x * 256 + t;
  if (n < N_NODES) off[n] += bsum[blockIdx.x];
  if (n == 0 && blockIdx.x == 0) off[N_NODES] = N_EDGES;
}

// erec[pos] = {src, pad, ea_bf16 x6} (8 dwords, 32B)
__global__ void scatter_kernel(const int* __restrict__ src, const int* __restrict__ dst,
                               const float* __restrict__ ea,
                               const int* __restrict__ off, int* __restrict__ cursor,
                               uint* __restrict__ erec) {
  int e = blockIdx.x * 256 + threadIdx.x;
  if (e < N_EDGES) {
    int d = dst[e];
    int p = atomicAdd(&cursor[d], 1);
    int pos = off[d] + p;
    const float* eap = &ea[(size_t)e * EDIM];
    float4 e0 = *(const float4*)eap;
    float4 e1 = *(const float4*)(eap + 4);
    float4 e2 = *(const float4*)(eap + 8);
    uint4 q0, q1;
    q0.x = (uint)src[e]; q0.y = 0u;
    q0.z = pk_bf16(e0.x, e0.y); q0.w = pk_bf16(e0.z, e0.w);
    q1.x = pk_bf16(e1.x, e1.y); q1.y = pk_bf16(e1.z, e1.w);
    q1.z = pk_bf16(e2.x, e2.y); q1.w = pk_bf16(e2.z, e2.w);
    uint* o = &erec[(size_t)pos * 8];
    *(uint4*)o = q0;
    *(uint4*)(o + 4) = q1;
  }
}

// ---------------- weight packing for MFMA fragments ----------------
__global__ void wprep_kernel(const float* __restrict__ Wl, const float* __restrict__ Wr,
                             ushort* __restrict__ wpk) {
  int idx = blockIdx.x * 256 + threadIdx.x;
  if (idx >= NLAYERS * 4 * 256 * 32) return;
  int kk = idx & 31;
  int cc = (idx >> 5) & 255;
  int kb = (idx >> 13) & 3;
  int layer = idx >> 15;
  int k = kb * 32 + kk;
  float v = (cc < 128) ? Wl[((size_t)layer * 128 + k) * 128 + cc]
                       : Wr[((size_t)layer * 128 + k) * 128 + (cc - 128)];
  wpk[idx] = f2bf(v);
}

__global__ void wprep_pol_kernel(const float* __restrict__ Wp1, ushort* __restrict__ wppk) {
  int idx = blockIdx.x * 256 + threadIdx.x;
  if (idx >= 4 * 128 * 32) return;
  int kk = idx & 31;
  int cc = (idx >> 5) & 127;
  int kb = idx >> 12;
  int k = kb * 32 + kk;
  float v = (cc < 64) ? Wp1[(size_t)k * 64 + cc] : Wp1[(size_t)(128 + k) * 64 + (cc - 64)];
  wppk[idx] = f2bf(v);
}

// ---------------- input projection (writes f32 hres + bf16 h16) ----------------
__global__ void inproj_kernel(const float* __restrict__ x, const float* __restrict__ Win,
                              const float* __restrict__ b_in, float* __restrict__ h,
                              ushort* __restrict__ h16) {
  __shared__ float xs[44];
  int t = threadIdx.x;
  int n0 = blockIdx.x * 2;
  if (t < 44) xs[t] = x[n0 * 22 + t];
  __syncthreads();
  int c = t & 127, half = t >> 7;
  int n = n0 + half;
  if (n < N_NODES) {
    float acc = b_in[c];
#pragma unroll
    for (int k = 0; k < 22; k++) acc = fmaf(xs[half * 22 + k], Win[k * HID + c], acc);
    float v = fmaxf(acc, 0.f);
    h[(size_t)n * HID + c] = v;
    h16[(size_t)n * HID + c] = f2bf(v);
  }
}

// ---------------- MFMA GEMM (optionally BN+residual+relu fused on input) --------
// BNFUSE reads bf16 T16 (gat output), normalizes with stats, +res, relu, -> LDS bf16.
template <int NOUT, int SPLIT, bool BIAS, bool OUTBF16, bool BNFUSE, bool RESID, bool WRITEH>
__global__ __launch_bounds__(256) void gemm_mfma_kernel(
    const ushort* __restrict__ A16, const ushort* __restrict__ T16,
    const float* __restrict__ stats, const float* __restrict__ gamma,
    const float* __restrict__ beta, const float* __restrict__ res,
    float* __restrict__ hout,
    const ushort* __restrict__ Wpk, const float* __restrict__ b1,
    const float* __restrict__ b2, void* __restrict__ C1v, void* __restrict__ C2v,
    int nrows) {
  __shared__ ushort As[64][136];  // +8 pad
  int t = threadIdx.x;
  int brow = blockIdx.x * 64;
  if constexpr (!BNFUSE) {
#pragma unroll
    for (int i = 0; i < 4; i++) {
      int f = t + i * 256;
      int r = f >> 4, cg = (f & 15) * 8;
      int g = brow + r;
      uint4 v = make_uint4(0, 0, 0, 0);
      if (g < nrows) v = *(const uint4*)&A16[(size_t)g * HID + cg];
      *(uint4*)&As[r][cg] = v;
    }
  } else {
    int cg = (t & 31) * 4;
    int r0 = t >> 5;
    const float invN = 1.f / (float)N_NODES;
    float4 sm = *(const float4*)&stats[cg];
    float4 sq = *(const float4*)&stats[128 + cg];
    float4 gm = *(const float4*)&gamma[cg];
    float4 bt = *(const float4*)&beta[cg];
    float s4[4] = {sm.x, sm.y, sm.z, sm.w};
    float q4[4] = {sq.x, sq.y, sq.z, sq.w};
    float g4[4] = {gm.x, gm.y, gm.z, gm.w};
    float bb4[4] = {bt.x, bt.y, bt.z, bt.w};
    float scl[4], shf[4];
#pragma unroll
    for (int k = 0; k < 4; k++) {
      float mu = s4[k] * invN;
      float var = q4[k] * invN - mu * mu;
      float rs = rsqrtf(var + EPS_BN);
      scl[k] = g4[k] * rs;
      shf[k] = bb4[k] - mu * scl[k];
    }
#pragma unroll
    for (int rr = 0; rr < 8; rr++) {
      int r = r0 + rr * 8;
      int g = brow + r;
      uint2 tvu = make_uint2(0u, 0u);
      if (g < nrows) tvu = *(const uint2*)&T16[(size_t)g * HID + cg];
      float o0 = fmaf(bflo(tvu.x), scl[0], shf[0]);
      float o1 = fmaf(bfhi(tvu.x), scl[1], shf[1]);
      float o2 = fmaf(bflo(tvu.y), scl[2], shf[2]);
      float o3 = fmaf(bfhi(tvu.y), scl[3], shf[3]);
      if constexpr (RESID) {
        if (g < nrows) {
          float4 rv = *(const float4*)&res[(size_t)g * HID + cg];
          o0 += rv.x; o1 += rv.y; o2 += rv.z; o3 += rv.w;
        }
      }
      o0 = fmaxf(o0, 0.f); o1 = fmaxf(o1, 0.f);
      o2 = fmaxf(o2, 0.f); o3 = fmaxf(o3, 0.f);
      if constexpr (WRITEH) {
        if (g < nrows) {
          float4 ov = make_float4(o0, o1, o2, o3);
          *(float4*)&hout[(size_t)g * HID + cg] = ov;
        }
      }
      *(uint2*)&As[r][cg] = make_uint2(pk_bf16(o0, o1), pk_bf16(o2, o3));
    }
  }
  __syncthreads();
  int lane = t & 63, wave = t >> 6;
  int arow = wave * 16 + (lane & 15);
  int k8 = (lane >> 4) * 8;
  constexpr int NT = NOUT / 16;
  f32x4 acc[NT];
#pragma unroll
  for (int n = 0; n < NT; n++) acc[n] = (f32x4){0.f, 0.f, 0.f, 0.f};
#pragma unroll
  for (int kb = 0; kb < 4; kb++) {
    short8 a = *(const short8*)&As[arow][kb * 32 + k8];
#pragma unroll
    for (int n = 0; n < NT; n++) {
      int col = n * 16 + (lane & 15);
      short8 b = *(const short8*)&Wpk[((size_t)(kb * NOUT + col)) * 32 + k8];
      acc[n] = __builtin_amdgcn_mfma_f32_16x16x32_bf16(a, b, acc[n], 0, 0, 0);
    }
  }
  // C/D: col = lane&15, row = (lane>>4)*4 + j
  int rbase = brow + wave * 16 + (lane >> 4) * 4;
  int ccol = lane & 15;
#pragma unroll
  for (int n = 0; n < NT; n++) {
    int col = n * 16 + ccol;
    float bias = 0.f;
    if (BIAS) bias = (col < SPLIT) ? b1[col] : b2[col - SPLIT];
    int colw = (col < SPLIT) ? col : col - SPLIT;
#pragma unroll
    for (int j = 0; j < 4; j++) {
      int row = rbase + j;
      if (row < nrows) {
        float v = acc[n][j] + bias;
        if (OUTBF16) {
          ushort* dstp = (ushort*)((col < SPLIT) ? C1v : C2v);
          dstp[(size_t)row * SPLIT + colw] = f2bf(v);
        } else {
          float* dstp = (float*)((col < SPLIT) ? C1v : C2v);
          dstp[(size_t)row * SPLIT + colw] = v;
        }
      }
    }
  }
}

// ---------------- GATv2 aggregation ----------------
// 1 node/wave, 2 ch/lane. SINGLE edge stream (no chain split); records prefetched
// 2-3 edges ahead via pad-safe unconditional loads; even edges -> state0, odd ->
// state1 (independent online-softmax chains, merged at end). exp2-domain softmax.
#define GAT_EDGE(ra, rb, xlw, m, d, acc)                                    \
  {                                                                         \
    f32x2 xa = (f32x2){bflo(xlw), bfhi(xlw)};                               \
    f32x2 ep = xa + xrv;                                                    \
    uint q;                                                                 \
    q = ra.z;                                                               \
    ep = pfma((f32x2){bflo(q), bflo(q)}, wk[0], ep);                        \
    ep = pfma((f32x2){bfhi(q), bfhi(q)}, wk[1], ep);                        \
    q = ra.w;                                                               \
    ep = pfma((f32x2){bflo(q), bflo(q)}, wk[2], ep);                        \
    ep = pfma((f32x2){bfhi(q), bfhi(q)}, wk[3], ep);                        \
    q = rb.x;                                                               \
    ep = pfma((f32x2){bflo(q), bflo(q)}, wk[4], ep);                        \
    ep = pfma((f32x2){bfhi(q), bfhi(q)}, wk[5], ep);                        \
    q = rb.y;                                                               \
    ep = pfma((f32x2){bflo(q), bflo(q)}, wk[6], ep);                        \
    ep = pfma((f32x2){bfhi(q), bfhi(q)}, wk[7], ep);                        \
    q = rb.z;                                                               \
    ep = pfma((f32x2){bflo(q), bflo(q)}, wk[8], ep);                        \
    ep = pfma((f32x2){bfhi(q), bfhi(q)}, wk[9], ep);                        \
    q = rb.w;                                                               \
    ep = pfma((f32x2){bflo(q), bflo(q)}, wk[10], ep);                       \
    ep = pfma((f32x2){bfhi(q), bfhi(q)}, wk[11], ep);                       \
    f32x2 sv = __builtin_elementwise_max(ep, ep * (f32x2){0.2f, 0.2f});     \
    float v = fmaf(sv.y, at.y, sv.x * at.x);                                \
    RED16(v)                                                                \
    float dm = v - m;                                                       \
    float e = __builtin_amdgcn_exp2f(-fabsf(dm));                           \
    bool big = dm > 0.f;                                                    \
    float sc = big ? e : 1.f;                                               \
    float p = big ? 1.f : e;                                                \
    m = fmaxf(m, v);                                                        \
    d = fmaf(d, sc, p);                                                     \
    acc = pfma(acc, (f32x2){sc, sc}, (f32x2){p, p} * xa);                   \
  }

__global__ __launch_bounds__(256, 4) void gat_kernel(
    const ushort* __restrict__ xl16, const ushort* __restrict__ xr16,
    const uint* __restrict__ erec, const int* __restrict__ off,
    const float* __restrict__ Wel, const float* __restrict__ attl,
    const float* __restrict__ bol, ushort* __restrict__ out16) {
  int lane = threadIdx.x & 63;
  int node = blockIdx.x * 4 + (threadIdx.x >> 6);
  if (node >= N_NODES) return;
  int c0 = lane * 2;

  f32x2 wk[12];
#pragma unroll
  for (int k = 0; k < 12; k++) {
    float2 w = *(const float2*)&Wel[k * HID + c0];
    wk[k] = (f32x2){w.x, w.y};
  }
  float2 at = *(const float2*)&attl[c0];
  at.x *= LOG2E; at.y *= LOG2E;  // exp2-domain scores (softmax ratio invariant)
  uint xrd = *(const uint*)&xr16[((uint)node << 7) + c0];
  f32x2 xrv = (f32x2){bflo(xrd), bfhi(xrd)};

  int is = off[node], deg = off[node + 1] - is;
  const uint* p = erec + (size_t)is * 8;

  float m0 = -INFINITY, d0 = 0.f;
  float m1 = -INFINITY, d1 = 0.f;
  f32x2 acc0 = (f32x2){0.f, 0.f};
  f32x2 acc1 = (f32x2){0.f, 0.f};

  if (deg > 0) {
    // prologue (pad records make all reads safe)
    uint4 Aa = *(const uint4*)p,        Ab = *(const uint4*)(p + 4);
    uint4 Ba = *(const uint4*)(p + 8),  Bb = *(const uint4*)(p + 12);
    uint xA = *(const uint*)&xl16[(Aa.x << 7) + c0];
    int i = 0;
    for (; i + 2 <= deg; i += 2) {
      uint xB = *(const uint*)&xl16[(Ba.x << 7) + c0];
      const uint* q2 = p + (size_t)(i + 2) * 8;           // records i+2, i+3
      uint4 Ca = *(const uint4*)q2,        Cb = *(const uint4*)(q2 + 4);
      uint4 Da = *(const uint4*)(q2 + 8),  Db = *(const uint4*)(q2 + 12);
      GAT_EDGE(Aa, Ab, xA, m0, d0, acc0)
      uint xC = *(const uint*)&xl16[(Ca.x << 7) + c0];    // xl for edge i+2
      GAT_EDGE(Ba, Bb, xB, m1, d1, acc1)
      Aa = Ca; Ab = Cb; Ba = Da; Bb = Db; xA = xC;
    }
    if (i < deg) GAT_EDGE(Aa, Ab, xA, m0, d0, acc0)
  }
  // merge even/odd states (log2 domain)
  float mn = fmaxf(m0, m1);
  float w0 = (m0 > -INFINITY) ? __builtin_amdgcn_exp2f(m0 - mn) : 0.f;
  float w1 = (m1 > -INFINITY) ? __builtin_amdgcn_exp2f(m1 - mn) : 0.f;
  float den = d0 * w0 + d1 * w1;
  f32x2 acc = acc0 * (f32x2){w0, w0} + acc1 * (f32x2){w1, w1};
  float inv = 1.f / (den + 1e-16f);
  float2 bo2 = *(const float2*)&bol[c0];
  out16[((uint)node << 7) + c0 + 0] = f2bf(fmaf(acc.x, inv, bo2.x));
  out16[((uint)node << 7) + c0 + 1] = f2bf(fmaf(acc.y, inv, bo2.y));
}

// ---------------- BatchNorm stats (bf16 input) ----------------
__global__ void bnstats_kernel(const ushort* __restrict__ t16, float* __restrict__ sums) {
  int tid = threadIdx.x;
  int c2 = (tid & 63) * 2;     // channel pair
  int grp = tid >> 6;          // 0..3 row groups
  float s0 = 0.f, s1 = 0.f, q0 = 0.f, q1 = 0.f;
  for (int n = blockIdx.x * 4 + grp; n < N_NODES; n += 1024) {
    uint v = *(const uint*)&t16[((uint)n << 7) + c2];
    float a = bflo(v), b = bfhi(v);
    s0 += a; q0 = fmaf(a, a, q0);
    s1 += b; q1 = fmaf(b, b, q1);
  }
  __shared__ float ls[4][128], lq[4][128];
  *(float2*)&ls[grp][c2] = make_float2(s0, s1);
  *(float2*)&lq[grp][c2] = make_float2(q0, q1);
  __syncthreads();
  if (tid < 128) {
    float s = ls[0][tid] + ls[1][tid] + ls[2][tid] + ls[3][tid];
    atomicAdd(&sums[tid], s);
    float q = lq[0][tid] + lq[1][tid] + lq[2][tid] + lq[3][tid];
    atomicAdd(&sums[128 + tid], q);
  }
}

// ---------------- policy head (one edge per 16 lanes, bf16 Ps/Pd) ----------------
__global__ __launch_bounds__(256) void policy_kernel(
    const ushort* __restrict__ Ps, const ushort* __restrict__ Pd,
    const int* __restrict__ src, const int* __restrict__ dst,
    const float* __restrict__ edge_attr, const float* __restrict__ Wp1e,
    const float* __restrict__ bp1, const float* __restrict__ Wp2,
    const float* __restrict__ bp2, float* __restrict__ outp) {
  int lane = threadIdx.x & 63;
  int j = lane & 15;
  int e = (blockIdx.x * 256 + threadIdx.x) >> 4;
  if (e >= N_EDGES) return;
  float4 we[12];
#pragma unroll
  for (int k = 0; k < 12; k++) we[k] = *(const float4*)&Wp1e[k * 64 + j * 4];
  float4 b4 = *(const float4*)&bp1[j * 4];
  float4 w2 = *(const float4*)&Wp2[j * 4];
  float bp2c = bp2[0];
  int s = src[e], d = dst[e];
  const float* eap = &edge_attr[(size_t)e * EDIM];
  float4 e0 = *(const float4*)eap;
  float4 e1 = *(const float4*)(eap + 4);
  float4 e2 = *(const float4*)(eap + 8);
  uint2 psu = *(const uint2*)&Ps[(size_t)s * 64 + j * 4];
  uint2 pdu = *(const uint2*)&Pd[(size_t)d * 64 + j * 4];
  float eav[12] = {e0.x, e0.y, e0.z, e0.w, e1.x, e1.y, e1.z, e1.w, e2.x, e2.y, e2.z, e2.w};
  float hx = bflo(psu.x) + bflo(pdu.x) + b4.x;
  float hy = bfhi(psu.x) + bfhi(pdu.x) + b4.y;
  float hz = bflo(psu.y) + bflo(pdu.y) + b4.z;
  float hw = bfhi(psu.y) + bfhi(pdu.y) + b4.w;
#pragma unroll
  for (int k = 0; k < 12; k++) {
    hx = fmaf(eav[k], we[k].x, hx);
    hy = fmaf(eav[k], we[k].y, hy);
    hz = fmaf(eav[k], we[k].z, hz);
    hw = fmaf(eav[k], we[k].w, hw);
  }
  hx = fmaxf(hx, 0.f); hy = fmaxf(hy, 0.f); hz = fmaxf(hz, 0.f); hw = fmaxf(hw, 0.f);
  float v = fmaf(hx, w2.x, fmaf(hy, w2.y, fmaf(hz, w2.z, hw * w2.w)));
  v += __shfl_xor(v, 1);
  v += __shfl_xor(v, 2);
  v += __shfl_xor(v, 4);
  v += __shfl_xor(v, 8);
  if (j == 0) outp[e] = v + bp2c;
}

// ---------------- pooled mean + value head ----------------
__device__ int lower_bound_dev(const int* a, int n, int key) {
  int lo = 0, hi = n;
  while (lo < hi) {
    int mid = (lo + hi) >> 1;
    if (a[mid] < key) lo = mid + 1; else hi = mid;
  }
  return lo;
}

__global__ void poolvalue_kernel(const float* __restrict__ h, const int* __restrict__ batch,
                                 const float* __restrict__ Wv1, const float* __restrict__ bv1,
                                 const float* __restrict__ Wv2, const float* __restrict__ bv2,
                                 float* __restrict__ outv) {
  __shared__ float pl[128];
  __shared__ float hd[64];
  __shared__ int range[2];
  int g = blockIdx.x, t = threadIdx.x;
  if (t == 0) {
    range[0] = lower_bound_dev(batch, N_NODES, g);
    range[1] = lower_bound_dev(batch, N_NODES, g + 1);
  }
  __syncthreads();
  int lo = range[0], hi = range[1];
  float s = 0.f;
  for (int n = lo; n < hi; n++) s += h[(size_t)n * HID + t];
  float cnt = (float)(hi - lo);
  pl[t] = s / fmaxf(cnt, 1.f);
  __syncthreads();
  if (t < 64) {
    float a = bv1[t];
    for (int c = 0; c < 128; c++) a = fmaf(pl[c], Wv1[c * 64 + t], a);
    hd[t] = fmaxf(a, 0.f);
  }
  __syncthreads();
  if (t < 3) {
    float a = bv2[t];
    for (int j = 0; j < 64; j++) a = fmaf(hd[j], Wv2[j * 3 + t], a);
    outv[g * 3 + t] = a;
  }
}

// ---------------- host ----------------
extern "C" void kernel_launch(void* const* d_in, const int* in_sizes, int n_in,
                              void* d_out, int out_size, void* d_ws, size_t ws_size,
                              hipStream_t stream) {
  (void)in_sizes; (void)n_in; (void)out_size; (void)ws_size;
  const float* x    = (const float*)d_in[0];
  const int*   src  = (const int*)d_in[1];
  const int*   dst  = (const int*)d_in[2];
  const int*   batch= (const int*)d_in[3];
  const float* ea   = (const float*)d_in[4];
  const float* Win  = (const float*)d_in[5];
  const float* b_in = (const float*)d_in[6];
  const float* Wl   = (const float*)d_in[7];
  const float* bl   = (const float*)d_in[8];
  const float* Wr   = (const float*)d_in[9];
  const float* br   = (const float*)d_in[10];
  const float* We   = (const float*)d_in[11];
  const float* att  = (const float*)d_in[12];
  const float* bo   = (const float*)d_in[13];
  const float* gamma= (const float*)d_in[14];
  const float* beta = (const float*)d_in[15];
  const float* Wv1  = (const float*)d_in[16];
  const float* bv1  = (const float*)d_in[17];
  const float* Wv2  = (const float*)d_in[18];
  const float* bv2  = (const float*)d_in[19];
  const float* Wp1  = (const float*)d_in[20];
  const float* bp1  = (const float*)d_in[21];
  const float* Wp2  = (const float*)d_in[22];
  const float* bp2  = (const float*)d_in[23];

  float* outv = (float*)d_out;                      // [G,3]
  float* outp = outv + (size_t)N_GRAPHS * 3;        // [E]

  float* hres   = (float*)d_ws;                           // residual / final h (f32)
  ushort* tmp16 = (ushort*)(hres + (size_t)N_NODES * HID); // gat output (bf16)
  ushort* h16   = tmp16 + (size_t)N_NODES * HID;           // inproj bf16
  ushort* xl16  = h16 + (size_t)N_NODES * HID;
  ushort* xr16  = xl16 + (size_t)N_NODES * HID;
  float* stats  = (float*)(xr16 + (size_t)N_NODES * HID);
  ushort* wpk   = (ushort*)(stats + NLAYERS * 256);
  ushort* wppk  = wpk + (size_t)NLAYERS * 4 * 256 * 32;
  int* off    = (int*)(wppk + 4 * 128 * 32);
  int* cursor = off + (N_NODES + 1);
  int* bsum   = cursor + N_NODES;
  uint* erec  = (uint*)(((uintptr_t)(bsum + 256) + 15) & ~(uintptr_t)15);

  const int NB = (N_NODES + 255) / 256;
  const int EB = (N_EDGES + 255) / 256;

  zero_kernel<<<NB, 256, 0, stream>>>(off, cursor, stats, erec);
  count_kernel<<<EB, 256, 0, stream>>>(dst, off);
  scan1_kernel<<<NB, 256, 0, stream>>>(off, bsum);
  scan2_kernel<<<1, 256, 0, stream>>>(bsum, NB);
  scan3_kernel<<<NB, 256, 0, stream>>>(off, bsum);
  scatter_kernel<<<EB, 256, 0, stream>>>(src, dst, ea, off, cursor, erec);
  wprep_kernel<<<(NLAYERS * 4 * 256 * 32 + 255) / 256, 256, 0, stream>>>(Wl, Wr, wpk);
  wprep_pol_kernel<<<(4 * 128 * 32 + 255) / 256, 256, 0, stream>>>(Wp1, wppk);
  inproj_kernel<<<N_NODES / 2, 256, 0, stream>>>(x, Win, b_in, hres, h16);

  const int MB = (N_NODES + 63) / 64;
  const int GATB = (N_NODES + 3) / 4;

  for (int l = 0; l < NLAYERS; l++) {
    if (l == 0) {
      gemm_mfma_kernel<256, 128, true, true, false, false, false><<<MB, 256, 0, stream>>>(
          h16, nullptr, nullptr, nullptr, nullptr, nullptr, nullptr,
          wpk, bl, br, xl16, xr16, N_NODES);
    } else if (l & 1) {
      int p = l - 1;
      gemm_mfma_kernel<256, 128, true, true, true, false, false><<<MB, 256, 0, stream>>>(
          nullptr, tmp16, stats + p * 256, gamma + p * HID, beta + p * HID, nullptr, nullptr,
          wpk + (size_t)l * 32768, bl + l * HID, br + l * HID, xl16, xr16, N_NODES);
    } else {
      int p = l - 1;
      gemm_mfma_kernel<256, 128, true, true, true, true, true><<<MB, 256, 0, stream>>>(
          nullptr, tmp16, stats + p * 256, gamma + p * HID, beta + p * HID, hres, hres,
          wpk + (size_t)l * 32768, bl + l * HID, br + l * HID, xl16, xr16, N_NODES);
    }
    gat_kernel<<<GATB, 256, 0, stream>>>(xl16, xr16, erec, off,
                                         We + (size_t)l * EDIM * HID, att + (size_t)l * HID,
                                         bo + (size_t)l * HID, tmp16);
    bnstats_kernel<<<256, 256, 0, stream>>>(tmp16, stats + l * 256);
  }

  // policy projections: BN of layer 7 fused (+residual, final h -> hres), bf16 out
  ushort* Ps = xl16;
  ushort* Pd = xr16;
  gemm_mfma_kernel<128, 64, false, true, true, true, true><<<MB, 256, 0, stream>>>(
      nullptr, tmp16, stats + 7 * 256, gamma + 7 * HID, beta + 7 * HID, hres, hres,
      wppk, nullptr, nullptr, Ps, Pd, N_NODES);
  policy_kernel<<<(N_EDGES + 15) / 16, 256, 0, stream>>>(Ps, Pd, src, dst, ea,
                                                         Wp1 + 256 * 64, bp1, Wp2, bp2, outp);
  poolvalue_kernel<<<N_GRAPHS, 128, 0, stream>>>(hres, batch, Wv1, bv1, Wv2, bv2, outv);
}

// Round 11
// 1240.102 us; speedup vs baseline: 1.9863x; 1.0448x over previous
//
#include <hip/hip_runtime.h>
#include <math.h>

#define N_NODES 50000
#define N_EDGES 500000
#define N_GRAPHS 2048
#define HID 128
#define EDIM 12
#define NLAYERS 8
#define EPS_BN 1e-5f
#define LOG2E 1.44269504088896340736f

typedef __attribute__((ext_vector_type(8))) short short8;
typedef __attribute__((ext_vector_type(4))) float f32x4;
typedef __attribute__((ext_vector_type(2))) float f32x2;
typedef unsigned int uint;
typedef unsigned short ushort;

__device__ inline ushort f2bf(float x) {
  unsigned u = __float_as_uint(x);
  u = (u + 0x7FFFu + ((u >> 16) & 1u)) >> 16;  // RNE
  return (ushort)u;
}
__device__ inline unsigned pk_bf16(float a, float b) {
  return (unsigned)f2bf(a) | ((unsigned)f2bf(b) << 16);
}
__device__ inline float bflo(uint q) { return __uint_as_float(q << 16); }
__device__ inline float bfhi(uint q) { return __uint_as_float(q & 0xFFFF0000u); }
__device__ inline f32x2 pfma(f32x2 a, f32x2 b, f32x2 c) {
  return __builtin_elementwise_fma(a, b, c);
}
// butterfly add, pure-VALU DPP (ctrl must be a literal)
template <int CTRL>
__device__ inline float dpp_add(float v) {
  int s = __builtin_amdgcn_update_dpp(0, __float_as_int(v), CTRL, 0xF, 0xF, true);
  return v + __int_as_float(s);
}
// 8-lane butterfly (head = 8 lanes x 4ch): xor1, xor2, mirror-within-8
#define RED8(v)               \
  v = dpp_add<0xB1>(v);       \
  v = dpp_add<0x4E>(v);       \
  v = dpp_add<0x141>(v);

// ---------------- CSR build ----------------
__global__ void zero_kernel(int* deg, int* cursor, float* stats, uint* erec) {
  int i = blockIdx.x * 256 + threadIdx.x;
  if (i < N_NODES) { deg[i] = 0; cursor[i] = 0; }
  if (i < NLAYERS * 256) stats[i] = 0.f;
  if (i < 32) erec[(size_t)N_EDGES * 8 + i] = 0u;  // 4 pad records (src=0)
}

__global__ void count_kernel(const int* __restrict__ dst, int* __restrict__ deg) {
  int e = blockIdx.x * 256 + threadIdx.x;
  if (e < N_EDGES) atomicAdd(&deg[dst[e]], 1);
}

__global__ void scan1_kernel(int* __restrict__ off, int* __restrict__ bsum) {
  __shared__ int s[256];
  int t = threadIdx.x; int n = blockIdx.x * 256 + t;
  int x = (n < N_NODES) ? off[n] : 0;
  s[t] = x; __syncthreads();
  for (int o = 1; o < 256; o <<= 1) {
    int v = (t >= o) ? s[t - o] : 0;
    __syncthreads(); s[t] += v; __syncthreads();
  }
  if (n < N_NODES) off[n] = s[t] - x;
  if (t == 255) bsum[blockIdx.x] = s[255];
}

__global__ void scan2_kernel(int* __restrict__ bsum, int nb) {
  __shared__ int s[256];
  int t = threadIdx.x;
  int x = (t < nb) ? bsum[t] : 0;
  s[t] = x; __syncthreads();
  for (int o = 1; o < 256; o <<= 1) {
    int v = (t >= o) ? s[t - o] : 0;
    __syncthreads(); s[t] += v; __syncthreads();
  }
  if (t < nb) bsum[t] = s[t] - x;
}

__global__ void scan3_kernel(int* __restrict__ off, const int* __restrict__ bsum) {
  int t = threadIdx.x; int n = blockIdx.x * 256 + t;
  if (n < N_NODES) off[n] += bsum[blockIdx.x];
  if (n == 0 && blockIdx.x == 0) off[N_NODES] = N_EDGES;
}

// erec[pos] = {src, pad, ea_bf16 x6} (8 dwords, 32B)
__global__ void scatter_kernel(const int* __restrict__ src, const int* __restrict__ dst,
                               const float* __restrict__ ea,
                               const int* __restrict__ off, int* __restrict__ cursor,
                               uint* __restrict__ erec) {
  int e = blockIdx.x * 256 + threadIdx.x;
  if (e < N_EDGES) {
    int d = dst[e];
    int p = atomicAdd(&cursor[d], 1);
    int pos = off[d] + p;
    const float* eap = &ea[(size_t)e * EDIM];
    float4 e0 = *(const float4*)eap;
    float4 e1 = *(const float4*)(eap + 4);
    float4 e2 = *(const float4*)(eap + 8);
    uint4 q0, q1;
    q0.x = (uint)src[e]; q0.y = 0u;
    q0.z = pk_bf16(e0.x, e0.y); q0.w = pk_bf16(e0.z, e0.w);
    q1.x = pk_bf16(e1.x, e1.y); q1.y = pk_bf16(e1.z, e1.w);
    q1.z = pk_bf16(e2.x, e2.y); q1.w = pk_bf16(e2.z, e2.w);
    uint* o = &erec[(size_t)pos * 8];
    *(uint4*)o = q0;
    *(uint4*)(o + 4) = q1;
  }
}

// ---------------- weight packing for MFMA fragments ----------------
__global__ void wprep_kernel(const float* __restrict__ Wl, const float* __restrict__ Wr,
                             ushort* __restrict__ wpk) {
  int idx = blockIdx.x * 256 + threadIdx.x;
  if (idx >= NLAYERS * 4 * 256 * 32) return;
  int kk = idx & 31;
  int cc = (idx >> 5) & 255;
  int kb = (idx >> 13) & 3;
  int layer = idx >> 15;
  int k = kb * 32 + kk;
  float v = (cc < 128) ? Wl[((size_t)layer * 128 + k) * 128 + cc]
                       : Wr[((size_t)layer * 128 + k) * 128 + (cc - 128)];
  wpk[idx] = f2bf(v);
}

__global__ void wprep_pol_kernel(const float* __restrict__ Wp1, ushort* __restrict__ wppk) {
  int idx = blockIdx.x * 256 + threadIdx.x;
  if (idx >= 4 * 128 * 32) return;
  int kk = idx & 31;
  int cc = (idx >> 5) & 127;
  int kb = idx >> 12;
  int k = kb * 32 + kk;
  float v = (cc < 64) ? Wp1[(size_t)k * 64 + cc] : Wp1[(size_t)(128 + k) * 64 + (cc - 64)];
  wppk[idx] = f2bf(v);
}

// ---------------- input projection (writes f32 hres + bf16 h16) ----------------
__global__ void inproj_kernel(const float* __restrict__ x, const float* __restrict__ Win,
                              const float* __restrict__ b_in, float* __restrict__ h,
                              ushort* __restrict__ h16) {
  __shared__ float xs[44];
  int t = threadIdx.x;
  int n0 = blockIdx.x * 2;
  if (t < 44) xs[t] = x[n0 * 22 + t];
  __syncthreads();
  int c = t & 127, half = t >> 7;
  int n = n0 + half;
  if (n < N_NODES) {
    float acc = b_in[c];
#pragma unroll
    for (int k = 0; k < 22; k++) acc = fmaf(xs[half * 22 + k], Win[k * HID + c], acc);
    float v = fmaxf(acc, 0.f);
    h[(size_t)n * HID + c] = v;
    h16[(size_t)n * HID + c] = f2bf(v);
  }
}

// ---------------- MFMA GEMM (optionally BN+residual+relu fused on input) --------
template <int NOUT, int SPLIT, bool BIAS, bool OUTBF16, bool BNFUSE, bool RESID, bool WRITEH>
__global__ __launch_bounds__(256) void gemm_mfma_kernel(
    const ushort* __restrict__ A16, const ushort* __restrict__ T16,
    const float* __restrict__ stats, const float* __restrict__ gamma,
    const float* __restrict__ beta, const float* __restrict__ res,
    float* __restrict__ hout,
    const ushort* __restrict__ Wpk, const float* __restrict__ b1,
    const float* __restrict__ b2, void* __restrict__ C1v, void* __restrict__ C2v,
    int nrows) {
  __shared__ ushort As[64][136];  // +8 pad
  int t = threadIdx.x;
  int brow = blockIdx.x * 64;
  if constexpr (!BNFUSE) {
#pragma unroll
    for (int i = 0; i < 4; i++) {
      int f = t + i * 256;
      int r = f >> 4, cg = (f & 15) * 8;
      int g = brow + r;
      uint4 v = make_uint4(0, 0, 0, 0);
      if (g < nrows) v = *(const uint4*)&A16[(size_t)g * HID + cg];
      *(uint4*)&As[r][cg] = v;
    }
  } else {
    int cg = (t & 31) * 4;
    int r0 = t >> 5;
    const float invN = 1.f / (float)N_NODES;
    float4 sm = *(const float4*)&stats[cg];
    float4 sq = *(const float4*)&stats[128 + cg];
    float4 gm = *(const float4*)&gamma[cg];
    float4 bt = *(const float4*)&beta[cg];
    float s4[4] = {sm.x, sm.y, sm.z, sm.w};
    float q4[4] = {sq.x, sq.y, sq.z, sq.w};
    float g4[4] = {gm.x, gm.y, gm.z, gm.w};
    float bb4[4] = {bt.x, bt.y, bt.z, bt.w};
    float scl[4], shf[4];
#pragma unroll
    for (int k = 0; k < 4; k++) {
      float mu = s4[k] * invN;
      float var = q4[k] * invN - mu * mu;
      float rs = rsqrtf(var + EPS_BN);
      scl[k] = g4[k] * rs;
      shf[k] = bb4[k] - mu * scl[k];
    }
#pragma unroll
    for (int rr = 0; rr < 8; rr++) {
      int r = r0 + rr * 8;
      int g = brow + r;
      uint2 tvu = make_uint2(0u, 0u);
      if (g < nrows) tvu = *(const uint2*)&T16[(size_t)g * HID + cg];
      float o0 = fmaf(bflo(tvu.x), scl[0], shf[0]);
      float o1 = fmaf(bfhi(tvu.x), scl[1], shf[1]);
      float o2 = fmaf(bflo(tvu.y), scl[2], shf[2]);
      float o3 = fmaf(bfhi(tvu.y), scl[3], shf[3]);
      if constexpr (RESID) {
        if (g < nrows) {
          float4 rv = *(const float4*)&res[(size_t)g * HID + cg];
          o0 += rv.x; o1 += rv.y; o2 += rv.z; o3 += rv.w;
        }
      }
      o0 = fmaxf(o0, 0.f); o1 = fmaxf(o1, 0.f);
      o2 = fmaxf(o2, 0.f); o3 = fmaxf(o3, 0.f);
      if constexpr (WRITEH) {
        if (g < nrows) {
          float4 ov = make_float4(o0, o1, o2, o3);
          *(float4*)&hout[(size_t)g * HID + cg] = ov;
        }
      }
      *(uint2*)&As[r][cg] = make_uint2(pk_bf16(o0, o1), pk_bf16(o2, o3));
    }
  }
  __syncthreads();
  int lane = t & 63, wave = t >> 6;
  int arow = wave * 16 + (lane & 15);
  int k8 = (lane >> 4) * 8;
  constexpr int NT = NOUT / 16;
  f32x4 acc[NT];
#pragma unroll
  for (int n = 0; n < NT; n++) acc[n] = (f32x4){0.f, 0.f, 0.f, 0.f};
#pragma unroll
  for (int kb = 0; kb < 4; kb++) {
    short8 a = *(const short8*)&As[arow][kb * 32 + k8];
#pragma unroll
    for (int n = 0; n < NT; n++) {
      int col = n * 16 + (lane & 15);
      short8 b = *(const short8*)&Wpk[((size_t)(kb * NOUT + col)) * 32 + k8];
      acc[n] = __builtin_amdgcn_mfma_f32_16x16x32_bf16(a, b, acc[n], 0, 0, 0);
    }
  }
  // C/D: col = lane&15, row = (lane>>4)*4 + j
  int rbase = brow + wave * 16 + (lane >> 4) * 4;
  int ccol = lane & 15;
#pragma unroll
  for (int n = 0; n < NT; n++) {
    int col = n * 16 + ccol;
    float bias = 0.f;
    if (BIAS) bias = (col < SPLIT) ? b1[col] : b2[col - SPLIT];
    int colw = (col < SPLIT) ? col : col - SPLIT;
#pragma unroll
    for (int j = 0; j < 4; j++) {
      int row = rbase + j;
      if (row < nrows) {
        float v = acc[n][j] + bias;
        if (OUTBF16) {
          ushort* dstp = (ushort*)((col < SPLIT) ? C1v : C2v);
          dstp[(size_t)row * SPLIT + colw] = f2bf(v);
        } else {
          float* dstp = (float*)((col < SPLIT) ? C1v : C2v);
          dstp[(size_t)row * SPLIT + colw] = v;
        }
      }
    }
  }
}

// ---------------- GATv2 aggregation ----------------
// 1 node/wave, 2 EDGES per wave: lanes 0-31 = even edges, lanes 32-63 = odd edges,
// 4 channels/lane. Independent online-softmax chain per half-wave, merged at end
// via shfl_xor(32). 8-lane DPP head-reduce. exp2-domain softmax. Pad-safe prefetch.
#define GAT_EDGE4(ra, rb, xw, OKEXPR)                                        \
  {                                                                          \
    f32x2 xa01 = (f32x2){bflo(xw.x), bfhi(xw.x)};                            \
    f32x2 xa23 = (f32x2){bflo(xw.y), bfhi(xw.y)};                            \
    f32x2 ep01 = xa01 + xr01;                                                \
    f32x2 ep23 = xa23 + xr23;                                                \
    uint q; float lo, hi;                                                    \
    q = ra.z; lo = bflo(q); hi = bfhi(q);                                    \
    ep01 = pfma((f32x2){lo, lo}, wk01[0], ep01);                             \
    ep23 = pfma((f32x2){lo, lo}, wk23[0], ep23);                             \
    ep01 = pfma((f32x2){hi, hi}, wk01[1], ep01);                             \
    ep23 = pfma((f32x2){hi, hi}, wk23[1], ep23);                             \
    q = ra.w; lo = bflo(q); hi = bfhi(q);                                    \
    ep01 = pfma((f32x2){lo, lo}, wk01[2], ep01);                             \
    ep23 = pfma((f32x2){lo, lo}, wk23[2], ep23);                             \
    ep01 = pfma((f32x2){hi, hi}, wk01[3], ep01);                             \
    ep23 = pfma((f32x2){hi, hi}, wk23[3], ep23);                             \
    q = rb.x; lo = bflo(q); hi = bfhi(q);                                    \
    ep01 = pfma((f32x2){lo, lo}, wk01[4], ep01);                             \
    ep23 = pfma((f32x2){lo, lo}, wk23[4], ep23);                             \
    ep01 = pfma((f32x2){hi, hi}, wk01[5], ep01);                             \
    ep23 = pfma((f32x2){hi, hi}, wk23[5], ep23);                             \
    q = rb.y; lo = bflo(q); hi = bfhi(q);                                    \
    ep01 = pfma((f32x2){lo, lo}, wk01[6], ep01);                             \
    ep23 = pfma((f32x2){lo, lo}, wk23[6], ep23);                             \
    ep01 = pfma((f32x2){hi, hi}, wk01[7], ep01);                             \
    ep23 = pfma((f32x2){hi, hi}, wk23[7], ep23);                             \
    q = rb.z; lo = bflo(q); hi = bfhi(q);                                    \
    ep01 = pfma((f32x2){lo, lo}, wk01[8], ep01);                             \
    ep23 = pfma((f32x2){lo, lo}, wk23[8], ep23);                             \
    ep01 = pfma((f32x2){hi, hi}, wk01[9], ep01);                             \
    ep23 = pfma((f32x2){hi, hi}, wk23[9], ep23);                             \
    q = rb.w; lo = bflo(q); hi = bfhi(q);                                    \
    ep01 = pfma((f32x2){lo, lo}, wk01[10], ep01);                            \
    ep23 = pfma((f32x2){lo, lo}, wk23[10], ep23);                            \
    ep01 = pfma((f32x2){hi, hi}, wk01[11], ep01);                            \
    ep23 = pfma((f32x2){hi, hi}, wk23[11], ep23);                            \
    f32x2 s01 = __builtin_elementwise_max(ep01, ep01 * (f32x2){0.2f, 0.2f}); \
    f32x2 s23 = __builtin_elementwise_max(ep23, ep23 * (f32x2){0.2f, 0.2f}); \
    float v = fmaf(s01.x, at4.x,                                             \
              fmaf(s01.y, at4.y, fmaf(s23.x, at4.z, s23.y * at4.w)));        \
    RED8(v)                                                                  \
    bool ok = (OKEXPR);                                                      \
    float dm = v - m;                                                        \
    float e = __builtin_amdgcn_exp2f(-fabsf(dm));                            \
    bool big = dm > 0.f;                                                     \
    float sc = (big && ok) ? e : 1.f;                                        \
    float p = ok ? (big ? 1.f : e) : 0.f;                                    \
    m = (ok && big) ? v : m;                                                 \
    d = fmaf(d, sc, p);                                                      \
    acc01 = pfma(acc01, (f32x2){sc, sc}, (f32x2){p, p} * xa01);              \
    acc23 = pfma(acc23, (f32x2){sc, sc}, (f32x2){p, p} * xa23);              \
  }

__global__ __launch_bounds__(256, 4) void gat_kernel(
    const ushort* __restrict__ xl16, const ushort* __restrict__ xr16,
    const uint* __restrict__ erec, const int* __restrict__ off,
    const float* __restrict__ Wel, const float* __restrict__ attl,
    const float* __restrict__ bol, ushort* __restrict__ out16) {
  int lane = threadIdx.x & 63;
  int node = blockIdx.x * 4 + (threadIdx.x >> 6);
  if (node >= N_NODES) return;
  int half = lane >> 5;          // 0: even edges, 1: odd edges
  int c0 = (lane & 31) * 4;      // 4 channels per lane (head = c0/32 spans 8 lanes)

  f32x2 wk01[12], wk23[12];
#pragma unroll
  for (int k = 0; k < 12; k++) {
    float4 w = *(const float4*)&Wel[k * HID + c0];
    wk01[k] = (f32x2){w.x, w.y};
    wk23[k] = (f32x2){w.z, w.w};
  }
  float4 at4 = *(const float4*)&attl[c0];
  at4.x *= LOG2E; at4.y *= LOG2E; at4.z *= LOG2E; at4.w *= LOG2E;
  uint2 xru = *(const uint2*)&xr16[((uint)node << 7) + c0];
  f32x2 xr01 = (f32x2){bflo(xru.x), bfhi(xru.x)};
  f32x2 xr23 = (f32x2){bflo(xru.y), bfhi(xru.y)};

  int is = off[node], deg = off[node + 1] - is;

  float m = -INFINITY, d = 0.f;
  f32x2 acc01 = (f32x2){0.f, 0.f};
  f32x2 acc23 = (f32x2){0.f, 0.f};

  if (deg > 0) {
    const uint* pe = erec + ((size_t)is + half) * 8;   // this half's first record
    uint4 Ra = *(const uint4*)pe, Rb = *(const uint4*)(pe + 4);
    uint2 xw = *(const uint2*)&xl16[(Ra.x << 7) + c0];
    int full = deg >> 1;
    for (int i = 0; i < full; i++) {
      const uint* pn = pe + 16;                         // next record for this half
      uint4 Na = *(const uint4*)pn, Nb = *(const uint4*)(pn + 4);
      uint2 xn = *(const uint2*)&xl16[(Na.x << 7) + c0];
      GAT_EDGE4(Ra, Rb, xw, true)
      Ra = Na; Rb = Nb; xw = xn; pe = pn;
    }
    if (deg & 1) GAT_EDGE4(Ra, Rb, xw, half == 0)
  }

  // merge the two half-wave chains (same channels live in lane l and l^32)
  float mo = __shfl_xor(m, 32);
  float dd = __shfl_xor(d, 32);
  f32x2 o01, o23;
  o01.x = __shfl_xor(acc01.x, 32); o01.y = __shfl_xor(acc01.y, 32);
  o23.x = __shfl_xor(acc23.x, 32); o23.y = __shfl_xor(acc23.y, 32);
  float mn = fmaxf(m, mo);
  float wS = (m > -INFINITY) ? __builtin_amdgcn_exp2f(m - mn) : 0.f;
  float wO = (mo > -INFINITY) ? __builtin_amdgcn_exp2f(mo - mn) : 0.f;
  float den = d * wS + dd * wO;
  f32x2 a01 = acc01 * (f32x2){wS, wS} + o01 * (f32x2){wO, wO};
  f32x2 a23 = acc23 * (f32x2){wS, wS} + o23 * (f32x2){wO, wO};
  float inv = 1.f / (den + 1e-16f);
  if (half == 0) {
    float4 bo = *(const float4*)&bol[c0];
    uint2 o;
    o.x = pk_bf16(fmaf(a01.x, inv, bo.x), fmaf(a01.y, inv, bo.y));
    o.y = pk_bf16(fmaf(a23.x, inv, bo.z), fmaf(a23.y, inv, bo.w));
    *(uint2*)&out16[((uint)node << 7) + c0] = o;
  }
}

// ---------------- BatchNorm stats (bf16 input) ----------------
__global__ void bnstats_kernel(const ushort* __restrict__ t16, float* __restrict__ sums) {
  int tid = threadIdx.x;
  int c2 = (tid & 63) * 2;     // channel pair
  int grp = tid >> 6;          // 0..3 row groups
  float s0 = 0.f, s1 = 0.f, q0 = 0.f, q1 = 0.f;
  for (int n = blockIdx.x * 4 + grp; n < N_NODES; n += 1024) {
    uint v = *(const uint*)&t16[((uint)n << 7) + c2];
    float a = bflo(v), b = bfhi(v);
    s0 += a; q0 = fmaf(a, a, q0);
    s1 += b; q1 = fmaf(b, b, q1);
  }
  __shared__ float ls[4][128], lq[4][128];
  *(float2*)&ls[grp][c2] = make_float2(s0, s1);
  *(float2*)&lq[grp][c2] = make_float2(q0, q1);
  __syncthreads();
  if (tid < 128) {
    float s = ls[0][tid] + ls[1][tid] + ls[2][tid] + ls[3][tid];
    atomicAdd(&sums[tid], s);
    float q = lq[0][tid] + lq[1][tid] + lq[2][tid] + lq[3][tid];
    atomicAdd(&sums[128 + tid], q);
  }
}

// ---------------- policy head (one edge per 16 lanes, grid-stride) ----------------
__global__ __launch_bounds__(256) void policy_kernel(
    const ushort* __restrict__ Ps, const ushort* __restrict__ Pd,
    const int* __restrict__ src, const int* __restrict__ dst,
    const float* __restrict__ edge_attr, const float* __restrict__ Wp1e,
    const float* __restrict__ bp1, const float* __restrict__ Wp2,
    const float* __restrict__ bp2, float* __restrict__ outp) {
  int j = threadIdx.x & 15;
  int gid = (blockIdx.x * 256 + threadIdx.x) >> 4;
  int ngroups = (gridDim.x * 256) >> 4;
  float4 we[12];
#pragma unroll
  for (int k = 0; k < 12; k++) we[k] = *(const float4*)&Wp1e[k * 64 + j * 4];
  float4 b4 = *(const float4*)&bp1[j * 4];
  float4 w2 = *(const float4*)&Wp2[j * 4];
  float bp2c = bp2[0];
  for (int e = gid; e < N_EDGES; e += ngroups) {
    int s = src[e], d = dst[e];
    const float* eap = &edge_attr[(size_t)e * EDIM];
    float4 e0 = *(const float4*)eap;
    float4 e1 = *(const float4*)(eap + 4);
    float4 e2 = *(const float4*)(eap + 8);
    uint2 psu = *(const uint2*)&Ps[(size_t)s * 64 + j * 4];
    uint2 pdu = *(const uint2*)&Pd[(size_t)d * 64 + j * 4];
    float eav[12] = {e0.x, e0.y, e0.z, e0.w, e1.x, e1.y, e1.z, e1.w, e2.x, e2.y, e2.z, e2.w};
    float hx = bflo(psu.x) + bflo(pdu.x) + b4.x;
    float hy = bfhi(psu.x) + bfhi(pdu.x) + b4.y;
    float hz = bflo(psu.y) + bflo(pdu.y) + b4.z;
    float hw = bfhi(psu.y) + bfhi(pdu.y) + b4.w;
#pragma unroll
    for (int k = 0; k < 12; k++) {
      hx = fmaf(eav[k], we[k].x, hx);
      hy = fmaf(eav[k], we[k].y, hy);
      hz = fmaf(eav[k], we[k].z, hz);
      hw = fmaf(eav[k], we[k].w, hw);
    }
    hx = fmaxf(hx, 0.f); hy = fmaxf(hy, 0.f); hz = fmaxf(hz, 0.f); hw = fmaxf(hw, 0.f);
    float v = fmaf(hx, w2.x, fmaf(hy, w2.y, fmaf(hz, w2.z, hw * w2.w)));
    v += __shfl_xor(v, 1);
    v += __shfl_xor(v, 2);
    v += __shfl_xor(v, 4);
    v += __shfl_xor(v, 8);
    if (j == 0) outp[e] = v + bp2c;
  }
}

// ---------------- pooled mean + value head ----------------
__device__ int lower_bound_dev(const int* a, int n, int key) {
  int lo = 0, hi = n;
  while (lo < hi) {
    int mid = (lo + hi) >> 1;
    if (a[mid] < key) lo = mid + 1; else hi = mid;
  }
  return lo;
}

__global__ void poolvalue_kernel(const float* __restrict__ h, const int* __restrict__ batch,
                                 const float* __restrict__ Wv1, const float* __restrict__ bv1,
                                 const float* __restrict__ Wv2, const float* __restrict__ bv2,
                                 float* __restrict__ outv) {
  __shared__ float pl[128];
  __shared__ float hd[64];
  __shared__ int range[2];
  int g = blockIdx.x, t = threadIdx.x;
  if (t == 0) {
    range[0] = lower_bound_dev(batch, N_NODES, g);
    range[1] = lower_bound_dev(batch, N_NODES, g + 1);
  }
  __syncthreads();
  int lo = range[0], hi = range[1];
  float s = 0.f;
  for (int n = lo; n < hi; n++) s += h[(size_t)n * HID + t];
  float cnt = (float)(hi - lo);
  pl[t] = s / fmaxf(cnt, 1.f);
  __syncthreads();
  if (t < 64) {
    float a = bv1[t];
    for (int c = 0; c < 128; c++) a = fmaf(pl[c], Wv1[c * 64 + t], a);
    hd[t] = fmaxf(a, 0.f);
  }
  __syncthreads();
  if (t < 3) {
    float a = bv2[t];
    for (int j = 0; j < 64; j++) a = fmaf(hd[j], Wv2[j * 3 + t], a);
    outv[g * 3 + t] = a;
  }
}

// ---------------- host ----------------
extern "C" void kernel_launch(void* const* d_in, const int* in_sizes, int n_in,
                              void* d_out, int out_size, void* d_ws, size_t ws_size,
                              hipStream_t stream) {
  (void)in_sizes; (void)n_in; (void)out_size; (void)ws_size;
  const float* x    = (const float*)d_in[0];
  const int*   src  = (const int*)d_in[1];
  const int*   dst  = (const int*)d_in[2];
  const int*   batch= (const int*)d_in[3];
  const float* ea   = (const float*)d_in[4];
  const float* Win  = (const float*)d_in[5];
  const float* b_in = (const float*)d_in[6];
  const float* Wl   = (const float*)d_in[7];
  const float* bl   = (const float*)d_in[8];
  const float* Wr   = (const float*)d_in[9];
  const float* br   = (const float*)d_in[10];
  const float* We   = (const float*)d_in[11];
  const float* att  = (const float*)d_in[12];
  const float* bo   = (const float*)d_in[13];
  const float* gamma= (const float*)d_in[14];
  const float* beta = (const float*)d_in[15];
  const float* Wv1  = (const float*)d_in[16];
  const float* bv1  = (const float*)d_in[17];
  const float* Wv2  = (const float*)d_in[18];
  const float* bv2  = (const float*)d_in[19];
  const float* Wp1  = (const float*)d_in[20];
  const float* bp1  = (const float*)d_in[21];
  const float* Wp2  = (const float*)d_in[22];
  const float* bp2  = (const float*)d_in[23];

  float* outv = (float*)d_out;                      // [G,3]
  float* outp = outv + (size_t)N_GRAPHS * 3;        // [E]

  float* hres   = (float*)d_ws;                           // residual / final h (f32)
  ushort* tmp16 = (ushort*)(hres + (size_t)N_NODES * HID); // gat output (bf16)
  ushort* h16   = tmp16 + (size_t)N_NODES * HID;           // inproj bf16
  ushort* xl16  = h16 + (size_t)N_NODES * HID;
  ushort* xr16  = xl16 + (size_t)N_NODES * HID;
  float* stats  = (float*)(xr16 + (size_t)N_NODES * HID);
  ushort* wpk   = (ushort*)(stats + NLAYERS * 256);
  ushort* wppk  = wpk + (size_t)NLAYERS * 4 * 256 * 32;
  int* off    = (int*)(wppk + 4 * 128 * 32);
  int* cursor = off + (N_NODES + 1);
  int* bsum   = cursor + N_NODES;
  uint* erec  = (uint*)(((uintptr_t)(bsum + 256) + 15) & ~(uintptr_t)15);

  const int NB = (N_NODES + 255) / 256;
  const int EB = (N_EDGES + 255) / 256;

  zero_kernel<<<NB, 256, 0, stream>>>(off, cursor, stats, erec);
  count_kernel<<<EB, 256, 0, stream>>>(dst, off);
  scan1_kernel<<<NB, 256, 0, stream>>>(off, bsum);
  scan2_kernel<<<1, 256, 0, stream>>>(bsum, NB);
  scan3_kernel<<<NB, 256, 0, stream>>>(off, bsum);
  scatter_kernel<<<EB, 256, 0, stream>>>(src, dst, ea, off, cursor, erec);
  wprep_kernel<<<(NLAYERS * 4 * 256 * 32 + 255) / 256, 256, 0, stream>>>(Wl, Wr, wpk);
  wprep_pol_kernel<<<(4 * 128 * 32 + 255) / 256, 256, 0, stream>>>(Wp1, wppk);
  inproj_kernel<<<N_NODES / 2, 256, 0, stream>>>(x, Win, b_in, hres, h16);

  const int MB = (N_NODES + 63) / 64;
  const int GATB = (N_NODES + 3) / 4;

  for (int l = 0; l < NLAYERS; l++) {
    if (l == 0) {
      gemm_mfma_kernel<256, 128, true, true, false, false, false><<<MB, 256, 0, stream>>>(
          h16, nullptr, nullptr, nullptr, nullptr, nullptr, nullptr,
          wpk, bl, br, xl16, xr16, N_NODES);
    } else if (l & 1) {
      int p = l - 1;
      gemm_mfma_kernel<256, 128, true, true, true, false, false><<<MB, 256, 0, stream>>>(
          nullptr, tmp16, stats + p * 256, gamma + p * HID, beta + p * HID, nullptr, nullptr,
          wpk + (size_t)l * 32768, bl + l * HID, br + l * HID, xl16, xr16, N_NODES);
    } else {
      int p = l - 1;
      gemm_mfma_kernel<256, 128, true, true, true, true, true><<<MB, 256, 0, stream>>>(
          nullptr, tmp16, stats + p * 256, gamma + p * HID, beta + p * HID, hres, hres,
          wpk + (size_t)l * 32768, bl + l * HID, br + l * HID, xl16, xr16, N_NODES);
    }
    gat_kernel<<<GATB, 256, 0, stream>>>(xl16, xr16, erec, off,
                                         We + (size_t)l * EDIM * HID, att + (size_t)l * HID,
                                         bo + (size_t)l * HID, tmp16);
    bnstats_kernel<<<256, 256, 0, stream>>>(tmp16, stats + l * 256);
  }

  // policy projections: BN of layer 7 fused (+residual, final h -> hres), bf16 out
  ushort* Ps = xl16;
  ushort* Pd = xr16;
  gemm_mfma_kernel<128, 64, false, true, true, true, true><<<MB, 256, 0, stream>>>(
      nullptr, tmp16, stats + 7 * 256, gamma + 7 * HID, beta + 7 * HID, hres, hres,
      wppk, nullptr, nullptr, Ps, Pd, N_NODES);
  policy_kernel<<<2048, 256, 0, stream>>>(Ps, Pd, src, dst, ea,
                                          Wp1 + 256 * 64, bp1, Wp2, bp2, outp);
  poolvalue_kernel<<<N_GRAPHS, 128, 0, stream>>>(hres, batch, Wv1, bv1, Wv2, bv2, outv);
}